// Round 1
// baseline (4973.008 us; speedup 1.0000x reference)
//
#include <hip/hip_runtime.h>
#include <stdint.h>

#define DEV static __device__ __forceinline__

typedef float f32x4 __attribute__((ext_vector_type(4)));
typedef int   i32x4 __attribute__((ext_vector_type(4)));

DEV float bf2f(unsigned short u){ return __uint_as_float(((unsigned int)u)<<16); }
DEV unsigned short f2bf(float f){ return (unsigned short)(__float_as_uint(f)>>16); } // exact for small ints

// ---------------- block reductions (256-thread blocks, 4 waves) ----------------
DEV float wredsum(float v){
#pragma unroll
  for (int o=32;o;o>>=1) v += __shfl_xor(v,o);
  return v;
}
DEV float wredmax(float v){
#pragma unroll
  for (int o=32;o;o>>=1) v = fmaxf(v,__shfl_xor(v,o));
  return v;
}
DEV float bredsum(float v, float* red){
  v = wredsum(v);
  if ((threadIdx.x&63)==0) red[threadIdx.x>>6] = v;
  __syncthreads();
  float r = red[0]+red[1]+red[2]+red[3];
  __syncthreads();
  return r;
}
DEV float bredmax(float v, float* red){
  v = wredmax(v);
  if ((threadIdx.x&63)==0) red[threadIdx.x>>6] = v;
  __syncthreads();
  float r = fmaxf(fmaxf(red[0],red[1]),fmaxf(red[2],red[3]));
  __syncthreads();
  return r;
}

// ---------------- misc ----------------
__global__ void fill_k(float* p, int n, float v){
  int i = blockIdx.x*256 + threadIdx.x;
  if (i < n) p[i] = v;
}

__global__ __launch_bounds__(256) void copy_init_k(const float* __restrict__ x,
                                                   float* __restrict__ h, float* __restrict__ ho){
  int i = blockIdx.x*256 + threadIdx.x;       // 1024 blocks -> covers 1048576 floats as float4
  float4 v = *(const float4*)(x + (size_t)i*4);
  *(float4*)(h  + (size_t)i*4) = v;
  *(float4*)(ho + (size_t)i*4) = v;
}

// ---------------- weight scale: stage 1 partial |w| sums ----------------
__global__ __launch_bounds__(256) void absmean_k(const float* __restrict__ src, long epm,
                                                 float* __restrict__ part, int baseIdx){
  __shared__ float red[4];
  int mat = blockIdx.x >> 8;
  int seg = blockIdx.x & 255;
  const float* p = src + (long)mat*epm;
  float s = 0.f;
  for (long i = (long)seg*256 + threadIdx.x; i < epm; i += 65536) s += fabsf(p[i]);
  s = bredsum(s, red);
  if (threadIdx.x==0) part[(long)(baseIdx+mat)*256 + seg] = s;
}

// stage 2: finalize all 18 scales + grouped copies
__global__ __launch_bounds__(256) void finalize_scales_k(const float* __restrict__ part,
                                                         float* __restrict__ scales){
  __shared__ float red[4];
  const long numel[18] = {1048576, 1048576,1048576, 1048576,1048576, 1048576,1048576,
                          1048576,1048576, 4194304,4194304, 4194304,4194304, 4194304,4194304,
                          32768, 32768, 1024};
  for (int m=0;m<18;m++){
    float v = part[(long)m*256 + threadIdx.x];
    v = bredsum(v, red);
    if (threadIdx.x==0) scales[m] = v/(float)numel[m] + 1e-8f;
  }
  if (threadIdx.x==0){
    for (int l=0;l<2;l++){
      scales[18+l*3+0] = scales[1+l];   // wq
      scales[18+l*3+1] = scales[3+l];   // wk
      scales[18+l*3+2] = scales[5+l];   // wv
      scales[24+l*2+0] = scales[9+l];   // wg
      scales[24+l*2+1] = scales[11+l];  // wu
    }
  }
}

// ternary quantize weights -> bf16 {-1,0,1}
__global__ __launch_bounds__(256) void quantw_k(const float* __restrict__ src,
                                                unsigned short* __restrict__ dst,
                                                const float* __restrict__ sptr, long n){
  float s = *sptr;
  long stride = (long)gridDim.x*256;
  for (long i = (long)blockIdx.x*256 + threadIdx.x; i < n; i += stride){
    float q = fminf(fmaxf(rintf(src[i]/s), -1.f), 1.f);
    dst[i] = f2bf(q);
  }
}

// ---------------- loop_delta for all 8 iterations: delta[i][b][j] ----------------
__global__ __launch_bounds__(1024) void delta_all_k(const float* __restrict__ temb,
                                                    const float* __restrict__ lpw,
                                                    const float* __restrict__ lp2w,
                                                    const float* __restrict__ lp2b,
                                                    float* __restrict__ delta){
  int tid = threadIdx.x;                 // 1024 = 8 it * 2 b * 64 j
  int i = tid >> 7, b = (tid >> 6) & 1, j = tid & 63;
  float frac = (float)i / 7.f;
  int jj = j & 31;
  float fr = expf(-logf(10000.f) * (float)jj * (1.f/32.f));
  float ang = frac * fr;
  float sig = (j < 32) ? sinf(ang) : cosf(ang);
  float p1 = 0.f, p2 = 0.f;
  for (int k=0;k<256;k++){
    float te = temb[b*256+k];
    p1 += te * lpw[j*256+k];
    p2 += te * lp2w[j*256+k];
  }
  delta[i*128 + b*64 + j] = sig*p1 + p2 + lp2b[j];
}

// ---------------- row quant (1024 wide), optional rmsnorm ----------------
template<bool RMS>
__global__ __launch_bounds__(256) void rowquant1k_k(const float* __restrict__ x,
                                                    const float* __restrict__ gamma,
                                                    unsigned short* __restrict__ xq,
                                                    float* __restrict__ rs){
  __shared__ float red[4];
  int m = blockIdx.x, t = threadIdx.x;
  float v[4];
  float4 f = *(const float4*)(x + (size_t)m*1024 + t*4);
  v[0]=f.x; v[1]=f.y; v[2]=f.z; v[3]=f.w;
  if (RMS){
    float ss = v[0]*v[0]+v[1]*v[1]+v[2]*v[2]+v[3]*v[3];
    ss = bredsum(ss, red);
    float r1 = rsqrtf(ss*(1.f/1024.f) + 1e-6f);
#pragma unroll
    for (int j=0;j<4;j++) v[j] = v[j]*r1*gamma[t*4+j];
  }
  float am = fmaxf(fmaxf(fabsf(v[0]),fabsf(v[1])),fmaxf(fabsf(v[2]),fabsf(v[3])));
  am = bredmax(am, red);
  float a = fmaxf(am, 1e-8f), inv = 127.f/a;
  ushort4 q;
  q.x = f2bf(fminf(fmaxf(rintf(v[0]*inv),-128.f),127.f));
  q.y = f2bf(fminf(fmaxf(rintf(v[1]*inv),-128.f),127.f));
  q.z = f2bf(fminf(fmaxf(rintf(v[2]*inv),-128.f),127.f));
  q.w = f2bf(fminf(fmaxf(rintf(v[3]*inv),-128.f),127.f));
  *(ushort4*)(xq + (size_t)m*1024 + t*4) = q;
  if (t==0) rs[m] = a/127.f;
}

// ---------------- fused: h_in = rmsnorm(h+delta, lnw); a_in quant with n1 ----------------
__global__ __launch_bounds__(256) void loopnorm_quant_k(const float* __restrict__ h,
                                                        const float* __restrict__ delta,
                                                        const float* __restrict__ lnw,
                                                        const float* __restrict__ n1,
                                                        float* __restrict__ hin,
                                                        unsigned short* __restrict__ xq,
                                                        float* __restrict__ rs){
  __shared__ float red[4];
  int m = blockIdx.x, t = threadIdx.x;
  int b = m >> 9;
  float v[4];
  float4 f = *(const float4*)(h + (size_t)m*1024 + t*4);
  v[0]=f.x; v[1]=f.y; v[2]=f.z; v[3]=f.w;
  if (t < 16){
#pragma unroll
    for (int j=0;j<4;j++) v[j] += delta[b*64 + t*4 + j];
  }
  float ss = v[0]*v[0]+v[1]*v[1]+v[2]*v[2]+v[3]*v[3];
  ss = bredsum(ss, red);
  float r1 = rsqrtf(ss*(1.f/1024.f) + 1e-6f);
  float w4[4];
#pragma unroll
  for (int j=0;j<4;j++) w4[j] = v[j]*r1*lnw[t*4+j];
  float4 of; of.x=w4[0]; of.y=w4[1]; of.z=w4[2]; of.w=w4[3];
  *(float4*)(hin + (size_t)m*1024 + t*4) = of;
  float s2 = w4[0]*w4[0]+w4[1]*w4[1]+w4[2]*w4[2]+w4[3]*w4[3];
  s2 = bredsum(s2, red);
  float r2 = rsqrtf(s2*(1.f/1024.f) + 1e-6f);
  float y[4];
#pragma unroll
  for (int j=0;j<4;j++) y[j] = w4[j]*r2*n1[t*4+j];
  float am = fmaxf(fmaxf(fabsf(y[0]),fabsf(y[1])),fmaxf(fabsf(y[2]),fabsf(y[3])));
  am = bredmax(am, red);
  float a = fmaxf(am, 1e-8f), inv = 127.f/a;
  ushort4 q;
  q.x = f2bf(fminf(fmaxf(rintf(y[0]*inv),-128.f),127.f));
  q.y = f2bf(fminf(fmaxf(rintf(y[1]*inv),-128.f),127.f));
  q.z = f2bf(fminf(fmaxf(rintf(y[2]*inv),-128.f),127.f));
  q.w = f2bf(fminf(fmaxf(rintf(y[3]*inv),-128.f),127.f));
  *(ushort4*)(xq + (size_t)m*1024 + t*4) = q;
  if (t==0) rs[m] = a/127.f;
}

// ---------------- silu(g)*u over F=4096, then row quant ----------------
__global__ __launch_bounds__(256) void silu_mul_quant_k(const float* __restrict__ gu,
                                                        unsigned short* __restrict__ xq,
                                                        float* __restrict__ rs){
  __shared__ float red[4];
  int m = blockIdx.x, t = threadIdx.x;
  const float* g = gu + (size_t)m*8192;
  const float* u = g + 4096;
  float v[16];
#pragma unroll
  for (int j=0;j<16;j+=4){
    float4 gg = *(const float4*)(g + t*16 + j);
    float4 uu = *(const float4*)(u + t*16 + j);
    v[j+0] = gg.x/(1.f+expf(-gg.x))*uu.x;
    v[j+1] = gg.y/(1.f+expf(-gg.y))*uu.y;
    v[j+2] = gg.z/(1.f+expf(-gg.z))*uu.z;
    v[j+3] = gg.w/(1.f+expf(-gg.w))*uu.w;
  }
  float am = 0.f;
#pragma unroll
  for (int j=0;j<16;j++) am = fmaxf(am, fabsf(v[j]));
  am = bredmax(am, red);
  float a = fmaxf(am, 1e-8f), inv = 127.f/a;
#pragma unroll
  for (int j=0;j<16;j+=4){
    ushort4 q;
    q.x = f2bf(fminf(fmaxf(rintf(v[j+0]*inv),-128.f),127.f));
    q.y = f2bf(fminf(fmaxf(rintf(v[j+1]*inv),-128.f),127.f));
    q.z = f2bf(fminf(fmaxf(rintf(v[j+2]*inv),-128.f),127.f));
    q.w = f2bf(fminf(fmaxf(rintf(v[j+3]*inv),-128.f),127.f));
    *(ushort4*)(xq + (size_t)m*4096 + t*16 + j) = q;
  }
  if (t==0) rs[m] = a/127.f;
}

// ---------------- recurrence: h = A_eff*h + Be + alpha*bo ; quant h ----------------
__global__ __launch_bounds__(256) void recur_quant_k(float* __restrict__ h,
                                                     const float* __restrict__ Be,
                                                     const float* __restrict__ bo,
                                                     const float* __restrict__ Araw,
                                                     const float* __restrict__ alpha, int it,
                                                     unsigned short* __restrict__ xq,
                                                     float* __restrict__ rs){
  __shared__ float red[4];
  int m = blockIdx.x, t = threadIdx.x;
  float al = alpha[it];
  size_t base = (size_t)m*1024 + t*4;
  float4 hh = *(const float4*)(h + base);
  float4 be = *(const float4*)(Be + base);
  float4 bb = *(const float4*)(bo + base);
  float4 ar = *(const float4*)(Araw + t*4);
  float v[4];
  v[0] = 0.99f*tanhf(ar.x)*hh.x + be.x + al*bb.x;
  v[1] = 0.99f*tanhf(ar.y)*hh.y + be.y + al*bb.y;
  v[2] = 0.99f*tanhf(ar.z)*hh.z + be.z + al*bb.z;
  v[3] = 0.99f*tanhf(ar.w)*hh.w + be.w + al*bb.w;
  float4 of; of.x=v[0]; of.y=v[1]; of.z=v[2]; of.w=v[3];
  *(float4*)(h + base) = of;
  float am = fmaxf(fmaxf(fabsf(v[0]),fabsf(v[1])),fmaxf(fabsf(v[2]),fabsf(v[3])));
  am = bredmax(am, red);
  float a = fmaxf(am, 1e-8f), inv = 127.f/a;
  ushort4 q;
  q.x = f2bf(fminf(fmaxf(rintf(v[0]*inv),-128.f),127.f));
  q.y = f2bf(fminf(fmaxf(rintf(v[1]*inv),-128.f),127.f));
  q.z = f2bf(fminf(fmaxf(rintf(v[2]*inv),-128.f),127.f));
  q.w = f2bf(fminf(fmaxf(rintf(v[3]*inv),-128.f),127.f));
  *(ushort4*)(xq + (size_t)m*1024 + t*4) = q;
  if (t==0) rs[m] = a/127.f;
}

// ---------------- MFMA GEMM: C[M=1024,N] = Aq @ Wq^T * rowsc * wsc (+res) ----------------
DEV f32x4 accfence(f32x4 c){ asm volatile("s_nop 7\n\ts_nop 7" : "+v"(c)); return c; }

template<int SSHIFT>
__global__ __launch_bounds__(256)
void gemm_bt(const unsigned short* __restrict__ A, const unsigned short* __restrict__ W,
             const float* __restrict__ rowsc, const float* __restrict__ wscv,
             const float* __restrict__ res, float* __restrict__ C, int N, int K)
{
  __shared__ __align__(16) unsigned short As[128*32];
  __shared__ __align__(16) unsigned short Bs[128*32];
  const int tid = threadIdx.x;
  const int lane = tid & 63, wvid = tid >> 6;
  const int wr = wvid >> 1, wc = wvid & 1;
  const int bm = blockIdx.y, bn = blockIdx.x;

  const int r0 = (wvid<<4) + (lane>>2);
  const int c8 = (lane&3)<<3;
  const unsigned short* gA = A + (size_t)(bm*128 + r0)*K + c8;
  const unsigned short* gB = W + (size_t)(bn*128 + r0)*K + c8;
  const size_t row64 = (size_t)64*K;
  unsigned short* lA = As + (wvid<<9);
  unsigned short* lB = Bs + (wvid<<9);

  f32x4 acc[4][4] = {};
  const int rA = (wr<<6) + (lane&15);
  const int rB = (wc<<6) + (lane&15);
  const int kg = (lane>>4)<<3;

  for (int kt = 0; kt < K; kt += 32){
    __syncthreads();
    __builtin_amdgcn_global_load_lds(gA,       lA,      16, 0, 0);
    __builtin_amdgcn_global_load_lds(gA+row64, lA+2048, 16, 0, 0);
    __builtin_amdgcn_global_load_lds(gB,       lB,      16, 0, 0);
    __builtin_amdgcn_global_load_lds(gB+row64, lB+2048, 16, 0, 0);
    gA += 32; gB += 32;
    __syncthreads();
    i32x4 a[4], b[4];
#pragma unroll
    for (int mi=0;mi<4;mi++) a[mi] = *(const i32x4*)(As + (rA + mi*16)*32 + kg);
#pragma unroll
    for (int ni=0;ni<4;ni++) b[ni] = *(const i32x4*)(Bs + (rB + ni*16)*32 + kg);
#pragma unroll
    for (int mi=0;mi<4;mi++)
#pragma unroll
      for (int ni=0;ni<4;ni++)
        asm("v_mfma_f32_16x16x32_bf16 %0, %1, %2, %0" : "+v"(acc[mi][ni]) : "v"(a[mi]), "v"(b[ni]));
  }
#pragma unroll
  for (int mi=0;mi<4;mi++)
#pragma unroll
    for (int ni=0;ni<4;ni++)
      acc[mi][ni] = accfence(acc[mi][ni]);

  const int rif = (lane>>4)<<2;
  const int cif = lane&15;
#pragma unroll
  for (int mi=0;mi<4;mi++){
#pragma unroll
    for (int r=0;r<4;r++){
      const int grow = bm*128 + (wr<<6) + mi*16 + rif + r;
      const float rsc = rowsc[grow];
#pragma unroll
      for (int ni=0;ni<4;ni++){
        const int gcol = bn*128 + (wc<<6) + ni*16 + cif;
        float vvv = acc[mi][ni][r] * rsc * wscv[gcol>>SSHIFT];
        const size_t off = (size_t)grow*N + gcol;
        if (res) vvv += res[off];
        C[off] = vvv;
      }
    }
  }
}

// ---------------- RoPE in-place on fused qkv buffer [1024][3072] ----------------
__global__ __launch_bounds__(256) void rope_k(float* __restrict__ qkv){
  int idx = blockIdx.x*256 + threadIdx.x;   // 1024 tok * 16 h * 32 d
  int d = idx & 31, hh = (idx>>5) & 15, tok = idx >> 9;
  int tpos = tok & 511;
  float inv = powf(10000.f, -(float)d * (1.f/32.f));
  float ang = (float)tpos * inv;
  float sv, cv; sincosf(ang, &sv, &cv);
  size_t base = (size_t)tok*3072 + hh*64 + d;
  float q1 = qkv[base], q2 = qkv[base+32];
  qkv[base]    = q1*cv - q2*sv;
  qkv[base+32] = q1*sv + q2*cv;
  float k1 = qkv[base+1024], k2 = qkv[base+1056];
  qkv[base+1024] = k1*cv - k2*sv;
  qkv[base+1056] = k1*sv + k2*cv;
}

// ---------------- flash-style f32 attention ----------------
__global__ __launch_bounds__(256) void attn_k(const float* __restrict__ qkv, float* __restrict__ o){
  constexpr int ST = 66;
  __shared__ float Qs[64*ST];
  __shared__ float Ks[64*ST];
  __shared__ float Vs[64*ST];
  __shared__ float Ps[64*ST];
  int tid = threadIdx.x;
  int qt = blockIdx.x & 7, bh = blockIdx.x >> 3;
  int b = bh >> 4, h = bh & 15;
  size_t qbase = ((size_t)(b*512 + qt*64))*3072 + h*64;

  for (int it = tid; it < 512; it += 256){
    int r = it >> 3, cc = (it & 7) * 8;
    const float* src = qkv + qbase + (size_t)r*3072 + cc;
    float4 v0 = *(const float4*)src, v1 = *(const float4*)(src+4);
    float* dst = Qs + r*ST + cc;
    *(float2*)(dst)   = make_float2(v0.x,v0.y);
    *(float2*)(dst+2) = make_float2(v0.z,v0.w);
    *(float2*)(dst+4) = make_float2(v1.x,v1.y);
    *(float2*)(dst+6) = make_float2(v1.z,v1.w);
  }

  float m_run[4] = {-1e30f,-1e30f,-1e30f,-1e30f};
  float l_run[4] = {0.f,0.f,0.f,0.f};
  float accO[4][4] = {};
  int tq = tid >> 4, tk = tid & 15;
  int q0 = tq*4, k0 = tk*4;

  for (int kt = 0; kt <= qt; ++kt){
    __syncthreads();
    size_t kbase = ((size_t)(b*512 + kt*64))*3072 + h*64;
    for (int it = tid; it < 512; it += 256){
      int r = it >> 3, cc = (it & 7) * 8;
      const float* sk = qkv + kbase + (size_t)r*3072 + 1024 + cc;
      const float* sv2 = qkv + kbase + (size_t)r*3072 + 2048 + cc;
      float4 a0 = *(const float4*)sk,  a1 = *(const float4*)(sk+4);
      float4 b0 = *(const float4*)sv2, b1 = *(const float4*)(sv2+4);
      float* dk = Ks + r*ST + cc;
      float* dv = Vs + r*ST + cc;
      *(float2*)(dk)   = make_float2(a0.x,a0.y);
      *(float2*)(dk+2) = make_float2(a0.z,a0.w);
      *(float2*)(dk+4) = make_float2(a1.x,a1.y);
      *(float2*)(dk+6) = make_float2(a1.z,a1.w);
      *(float2*)(dv)   = make_float2(b0.x,b0.y);
      *(float2*)(dv+2) = make_float2(b0.z,b0.w);
      *(float2*)(dv+4) = make_float2(b1.x,b1.y);
      *(float2*)(dv+6) = make_float2(b1.z,b1.w);
    }
    __syncthreads();

    float s[4][4] = {};
    for (int d=0; d<64; d+=2){
      float2 qv[4], kv[4];
#pragma unroll
      for (int x=0;x<4;x++) qv[x] = *(const float2*)(Qs + (q0+x)*ST + d);
#pragma unroll
      for (int x=0;x<4;x++) kv[x] = *(const float2*)(Ks + (k0+x)*ST + d);
#pragma unroll
      for (int qi=0;qi<4;qi++)
#pragma unroll
        for (int ki=0;ki<4;ki++)
          s[qi][ki] += qv[qi].x*kv[ki].x + qv[qi].y*kv[ki].y;
    }
    const bool diag = (kt == qt);
#pragma unroll
    for (int qi=0;qi<4;qi++){
#pragma unroll
      for (int ki=0;ki<4;ki++){
        float sv = s[qi][ki]*0.125f;
        if (diag && (k0+ki) > (q0+qi)) sv = -1.0e9f;
        s[qi][ki] = sv;
      }
      float m2 = fmaxf(fmaxf(s[qi][0],s[qi][1]), fmaxf(s[qi][2],s[qi][3]));
      m2 = fmaxf(m2, __shfl_xor(m2,1));
      m2 = fmaxf(m2, __shfl_xor(m2,2));
      m2 = fmaxf(m2, __shfl_xor(m2,4));
      m2 = fmaxf(m2, __shfl_xor(m2,8));
      float mn = fmaxf(m_run[qi], m2);
      float sf = expf(m_run[qi]-mn);
      m_run[qi] = mn;
      float p0 = 0.f;
#pragma unroll
      for (int ki=0;ki<4;ki++){
        float p = expf(s[qi][ki]-mn);
        Ps[(q0+qi)*ST + k0+ki] = p;
        p0 += p;
      }
      p0 += __shfl_xor(p0,1); p0 += __shfl_xor(p0,2);
      p0 += __shfl_xor(p0,4); p0 += __shfl_xor(p0,8);
      l_run[qi] = l_run[qi]*sf + p0;
#pragma unroll
      for (int di=0;di<4;di++) accO[qi][di] *= sf;
    }
    __syncthreads();
    for (int k=0;k<64;k++){
      float2 v01 = *(const float2*)(Vs + k*ST + k0);
      float2 v23 = *(const float2*)(Vs + k*ST + k0+2);
#pragma unroll
      for (int qi=0;qi<4;qi++){
        float p = Ps[(q0+qi)*ST + k];
        accO[qi][0] += p*v01.x; accO[qi][1] += p*v01.y;
        accO[qi][2] += p*v23.x; accO[qi][3] += p*v23.y;
      }
    }
  }
#pragma unroll
  for (int qi=0;qi<4;qi++){
    float invl = 1.f / l_run[qi];
#pragma unroll
    for (int di=0;di<4;di++)
      o[(size_t)(b*512 + qt*64 + q0+qi)*1024 + h*64 + k0+di] = accO[qi][di]*invl;
  }
}

// ---------------- LoRA down: t1[m][32] = xq_h @ ldq^T * rs * s_ld ----------------
__global__ __launch_bounds__(256) void lora_down_k(const unsigned short* __restrict__ xq,
                                                   const float* __restrict__ rs,
                                                   const unsigned short* __restrict__ ldq,
                                                   const float* __restrict__ sld,
                                                   float* __restrict__ t1){
  __shared__ float xrow[1024];
  __shared__ float part[256];
  int m = blockIdx.x, t = threadIdx.x;
  {
    ushort4 u = *(const ushort4*)(xq + (size_t)m*1024 + t*4);
    xrow[t*4+0]=bf2f(u.x); xrow[t*4+1]=bf2f(u.y); xrow[t*4+2]=bf2f(u.z); xrow[t*4+3]=bf2f(u.w);
  }
  __syncthreads();
  int r = t & 31, seg = t >> 5;
  const unsigned short* wrow = ldq + (size_t)r*1024 + seg*128;
  const float* xr = xrow + seg*128;
  float acc = 0.f;
  for (int k=0;k<128;k+=4){
    ushort4 w4 = *(const ushort4*)(wrow + k);
    acc += xr[k]*bf2f(w4.x) + xr[k+1]*bf2f(w4.y) + xr[k+2]*bf2f(w4.z) + xr[k+3]*bf2f(w4.w);
  }
  part[t] = acc;
  __syncthreads();
  if (t < 32){
    float s = 0.f;
    for (int sg=0; sg<8; sg++) s += part[sg*32 + t];
    t1[(size_t)m*32 + t] = s * rs[m] * (*sld);
  }
}

// ---------------- fused: topk+lora_up+h-update+act+sigmoid+h_out ----------------
__global__ __launch_bounds__(256) void finalize_k(const float* __restrict__ t1,
                                                  const unsigned short* __restrict__ luq,
                                                  const float* __restrict__ slu,
                                                  const unsigned short* __restrict__ actq,
                                                  const float* __restrict__ sact,
                                                  const float* __restrict__ ig, int it,
                                                  float* __restrict__ h, float* __restrict__ hout,
                                                  float* __restrict__ wsw){
  __shared__ float xs[32];
  __shared__ float red[4];
  __shared__ float sh_thr, sh_gs;
  int m = blockIdx.x, t = threadIdx.x;
  if (t < 32) xs[t] = t1[(size_t)m*32 + t];
  __syncthreads();
  float val = 0.f, av = 0.f, amax = 0.f;
  if (t < 32){
    val = xs[t]; av = fabsf(val);
    int rank = 0;
    for (int j=0;j<32;j++){
      float aj = fabsf(xs[j]);
      amax = fmaxf(amax, aj);
      if (aj > av || (aj == av && j < t)) rank++;
    }
    if (rank == 17) sh_thr = av;   // 18th largest (k = ceil(0.55*32) = 18)
  }
  __syncthreads();
  if (t < 32){
    float a = fmaxf(amax, 1e-8f);
    float q = 0.f;
    if (av >= sh_thr) q = fminf(fmaxf(rintf(val*(127.f/a)), -128.f), 127.f);
    xs[t] = q;
    if (t == 0) sh_gs = ig[it] * (*slu) * (a/127.f);
  }
  __syncthreads();
  float gs = sh_gs;
  float hn[4];
  int n0 = t*4;
#pragma unroll
  for (int ni=0;ni<4;ni++){
    const unsigned short* lr = luq + (size_t)(n0+ni)*32;
    float d = 0.f;
    for (int k=0;k<32;k+=4){
      ushort4 w4 = *(const ushort4*)(lr + k);
      d += xs[k]*bf2f(w4.x) + xs[k+1]*bf2f(w4.y) + xs[k+2]*bf2f(w4.z) + xs[k+3]*bf2f(w4.w);
    }
    hn[ni] = h[(size_t)m*1024 + n0+ni] + gs*d;
  }
  float am = fmaxf(fmaxf(fabsf(hn[0]),fabsf(hn[1])),fmaxf(fabsf(hn[2]),fabsf(hn[3])));
  am = bredmax(am, red);
  float a2 = fmaxf(am, 1e-8f), inv2 = 127.f/a2;
  float zp = 0.f;
#pragma unroll
  for (int ni=0;ni<4;ni++){
    float q = fminf(fmaxf(rintf(hn[ni]*inv2),-128.f),127.f);
    zp += q * bf2f(actq[n0+ni]);
  }
  zp = bredsum(zp, red);
  float z = zp * (a2/127.f) * (*sact);
  float wv = 1.f/(1.f+expf(-z));
#pragma unroll
  for (int ni=0;ni<4;ni++){
    size_t off = (size_t)m*1024 + n0+ni;
    float ho = hout[off];
    hout[off] = ho + wv*(hn[ni]-ho);
    h[off] = hn[ni];
  }
  if (t==0) wsw[it*1024 + m] = wv;
}

__global__ __launch_bounds__(256) void ponder_k(const float* __restrict__ wsw, float* __restrict__ out){
  __shared__ float red[4];
  float s = 0.f;
  for (int j=threadIdx.x; j<8192; j+=256) s += wsw[j];
  s = bredsum(s, red);
  if (threadIdx.x==0) out[0] = s*(1.f/8192.f);
}

// ================= host =================
extern "C" void kernel_launch(void* const* d_in, const int* in_sizes, int n_in,
                              void* d_out, int out_size, void* d_ws, size_t ws_size,
                              hipStream_t stream)
{
  (void)in_sizes; (void)n_in;
  const float* x     = (const float*)d_in[0];
  const float* e     = (const float*)d_in[1];
  const float* temb  = (const float*)d_in[2];
  const float* bn1   = (const float*)d_in[3];
  const float* bwq   = (const float*)d_in[4];
  const float* bwk   = (const float*)d_in[5];
  const float* bwv   = (const float*)d_in[6];
  const float* bwo   = (const float*)d_in[7];
  const float* bn2   = (const float*)d_in[8];
  const float* bwg   = (const float*)d_in[9];
  const float* bwu   = (const float*)d_in[10];
  const float* bwd   = (const float*)d_in[11];
  const float* Araw  = (const float*)d_in[12];
  const float* Bw    = (const float*)d_in[13];
  const float* ldw   = (const float*)d_in[14];
  const float* luw   = (const float*)d_in[15];
  const float* ig    = (const float*)d_in[16];
  const float* actw  = (const float*)d_in[17];
  const float* alph  = (const float*)d_in[18];
  const float* lpw   = (const float*)d_in[19];
  const float* lp2w  = (const float*)d_in[20];
  const float* lp2b  = (const float*)d_in[21];
  const float* lnw   = (const float*)d_in[22];
  // d_in[23] = n_loops (setup fixes it at 8)

  char* ws = (char*)d_ws;
  float* out = (float*)d_out;
  const size_t WS_NEEDED = 130351616ull;
  if (ws_size < WS_NEEDED){
    fill_k<<<(out_size+255)/256,256,0,stream>>>(out, out_size, 1.0e9f);
    return;
  }

  unsigned short* qw_qkv = (unsigned short*)(ws + 0);
  unsigned short* qw_wo  = (unsigned short*)(ws + 12582912);
  unsigned short* qw_gu  = (unsigned short*)(ws + 16777216);
  unsigned short* qw_wd  = (unsigned short*)(ws + 50331648);
  unsigned short* qw_bw  = (unsigned short*)(ws + 67108864);
  unsigned short* qw_ld  = (unsigned short*)(ws + 69206016);
  unsigned short* qw_lu  = (unsigned short*)(ws + 69271552);
  unsigned short* qw_act = (unsigned short*)(ws + 69337088);
  float* scales = (float*)(ws + 69339136);
  float* part   = (float*)(ws + 69339648);
  float* delta  = (float*)(ws + 69358080);
  float* hbuf   = (float*)(ws + 69362176);
  float* Bebuf  = (float*)(ws + 73556480);
  float* bufX   = (float*)(ws + 77750784);
  float* bufY   = (float*)(ws + 81945088);
  float* qkvb   = (float*)(ws + 86139392);
  float* obuf   = (float*)(ws + 86139392 + 12582912);
  float* gub    = (float*)(ws + 86139392);
  unsigned short* xq1k = (unsigned short*)(ws + 119693824);
  float* rs1k   = (float*)(ws + 121790976);
  unsigned short* xqm  = (unsigned short*)(ws + 121795072);
  float* rsm    = (float*)(ws + 130183680);
  float* t1     = (float*)(ws + 130187776);
  float* wsw    = (float*)(ws + 130318848);

  // ---- weight scales ----
  absmean_k<<<256,256,0,stream>>>(Bw,  1048576, part, 0);
  absmean_k<<<512,256,0,stream>>>(bwq, 1048576, part, 1);
  absmean_k<<<512,256,0,stream>>>(bwk, 1048576, part, 3);
  absmean_k<<<512,256,0,stream>>>(bwv, 1048576, part, 5);
  absmean_k<<<512,256,0,stream>>>(bwo, 1048576, part, 7);
  absmean_k<<<512,256,0,stream>>>(bwg, 4194304, part, 9);
  absmean_k<<<512,256,0,stream>>>(bwu, 4194304, part, 11);
  absmean_k<<<512,256,0,stream>>>(bwd, 4194304, part, 13);
  absmean_k<<<256,256,0,stream>>>(ldw, 32768, part, 15);
  absmean_k<<<256,256,0,stream>>>(luw, 32768, part, 16);
  absmean_k<<<256,256,0,stream>>>(actw, 1024, part, 17);
  finalize_scales_k<<<1,256,0,stream>>>(part, scales);

  // ---- quantize weights (ternary bf16) ----
  for (int l=0;l<2;l++){
    quantw_k<<<1024,256,0,stream>>>(bwq + (size_t)l*1048576, qw_qkv + (size_t)l*3145728,           scales+1+l, 1048576);
    quantw_k<<<1024,256,0,stream>>>(bwk + (size_t)l*1048576, qw_qkv + (size_t)l*3145728 + 1048576, scales+3+l, 1048576);
    quantw_k<<<1024,256,0,stream>>>(bwv + (size_t)l*1048576, qw_qkv + (size_t)l*3145728 + 2097152, scales+5+l, 1048576);
    quantw_k<<<1024,256,0,stream>>>(bwo + (size_t)l*1048576, qw_wo + (size_t)l*1048576, scales+7+l, 1048576);
    quantw_k<<<2048,256,0,stream>>>(bwg + (size_t)l*4194304, qw_gu + (size_t)l*8388608,           scales+9+l,  4194304);
    quantw_k<<<2048,256,0,stream>>>(bwu + (size_t)l*4194304, qw_gu + (size_t)l*8388608 + 4194304, scales+11+l, 4194304);
    quantw_k<<<2048,256,0,stream>>>(bwd + (size_t)l*4194304, qw_wd + (size_t)l*4194304, scales+13+l, 4194304);
  }
  quantw_k<<<1024,256,0,stream>>>(Bw,  qw_bw,  scales+0,  1048576);
  quantw_k<<<64,256,0,stream>>>(ldw, qw_ld, scales+15, 32768);
  quantw_k<<<64,256,0,stream>>>(luw, qw_lu, scales+16, 32768);
  quantw_k<<<4,256,0,stream>>>(actw, qw_act, scales+17, 1024);

  // ---- misc setup ----
  delta_all_k<<<1,1024,0,stream>>>(temb, lpw, lp2w, lp2b, delta);
  copy_init_k<<<1024,256,0,stream>>>(x, hbuf, out);

  // Be = bitlinear(e, B_w)
  rowquant1k_k<false><<<1024,256,0,stream>>>(e, nullptr, xq1k, rs1k);
  { dim3 g(8,8); gemm_bt<30><<<g,256,0,stream>>>(xq1k, qw_bw, rs1k, scales+0, nullptr, Bebuf, 1024, 1024); }

  // ---- main recurrent loop (n_loops = 8) ----
  for (int it=0; it<8; ++it){
    loopnorm_quant_k<<<1024,256,0,stream>>>(hbuf, delta + it*128, lnw, bn1, bufX, xq1k, rs1k);
    for (int l=0;l<2;l++){
      if (l==1) rowquant1k_k<true><<<1024,256,0,stream>>>(bufX, bn1 + 1024, xq1k, rs1k);
      { dim3 g(24,8); gemm_bt<10><<<g,256,0,stream>>>(xq1k, qw_qkv + (size_t)l*3145728, rs1k, scales+18+l*3, nullptr, qkvb, 3072, 1024); }
      rope_k<<<2048,256,0,stream>>>(qkvb);
      attn_k<<<256,256,0,stream>>>(qkvb, obuf);
      rowquant1k_k<false><<<1024,256,0,stream>>>(obuf, nullptr, xq1k, rs1k);
      { dim3 g(8,8);  gemm_bt<30><<<g,256,0,stream>>>(xq1k, qw_wo + (size_t)l*1048576, rs1k, scales+7+l, bufX, bufY, 1024, 1024); }
      rowquant1k_k<true><<<1024,256,0,stream>>>(bufY, bn2 + (size_t)l*1024, xq1k, rs1k);
      { dim3 g(64,8); gemm_bt<12><<<g,256,0,stream>>>(xq1k, qw_gu + (size_t)l*8388608, rs1k, scales+24+l*2, nullptr, gub, 8192, 1024); }
      silu_mul_quant_k<<<1024,256,0,stream>>>(gub, xqm, rsm);
      { dim3 g(8,8);  gemm_bt<30><<<g,256,0,stream>>>(xqm, qw_wd + (size_t)l*4194304, rsm, scales+13+l, bufY, bufX, 1024, 4096); }
    }
    recur_quant_k<<<1024,256,0,stream>>>(hbuf, Bebuf, bufX, Araw, alph, it, xq1k, rs1k);
    lora_down_k<<<1024,256,0,stream>>>(xq1k, rs1k, qw_ld, scales+15, t1);
    finalize_k<<<1024,256,0,stream>>>(t1, qw_lu, scales+16, qw_act, scales+17, ig, it, hbuf, out, wsw);
  }
  ponder_k<<<1,256,0,stream>>>(wsw, out + 1048576);
}

// Round 2
// 3919.519 us; speedup vs baseline: 1.2688x; 1.2688x over previous
//
#include <hip/hip_runtime.h>
#include <stdint.h>

#define DEV static __device__ __forceinline__

typedef float f32x4 __attribute__((ext_vector_type(4)));
typedef int   i32x4 __attribute__((ext_vector_type(4)));

DEV float bf2f(unsigned short u){ return __uint_as_float(((unsigned int)u)<<16); }
DEV unsigned short f2bf(float f){ return (unsigned short)(__float_as_uint(f)>>16); } // exact for small ints

// ---------------- block reductions (256-thread blocks, 4 waves) ----------------
DEV float wredsum(float v){
#pragma unroll
  for (int o=32;o;o>>=1) v += __shfl_xor(v,o);
  return v;
}
DEV float wredmax(float v){
#pragma unroll
  for (int o=32;o;o>>=1) v = fmaxf(v,__shfl_xor(v,o));
  return v;
}
DEV float bredsum(float v, float* red){
  v = wredsum(v);
  if ((threadIdx.x&63)==0) red[threadIdx.x>>6] = v;
  __syncthreads();
  float r = red[0]+red[1]+red[2]+red[3];
  __syncthreads();
  return r;
}
DEV float bredmax(float v, float* red){
  v = wredmax(v);
  if ((threadIdx.x&63)==0) red[threadIdx.x>>6] = v;
  __syncthreads();
  float r = fmaxf(fmaxf(red[0],red[1]),fmaxf(red[2],red[3]));
  __syncthreads();
  return r;
}

// ---------------- misc ----------------
__global__ void fill_k(float* p, int n, float v){
  int i = blockIdx.x*256 + threadIdx.x;
  if (i < n) p[i] = v;
}

__global__ __launch_bounds__(256) void copy_init_k(const float* __restrict__ x,
                                                   float* __restrict__ h, float* __restrict__ ho){
  int i = blockIdx.x*256 + threadIdx.x;
  float4 v = *(const float4*)(x + (size_t)i*4);
  *(float4*)(h  + (size_t)i*4) = v;
  *(float4*)(ho + (size_t)i*4) = v;
}

// ---------------- weight scale: stage 1 partial |w| sums (float4) ----------------
__global__ __launch_bounds__(256) void absmean_k(const float* __restrict__ src, long epm,
                                                 float* __restrict__ part, int baseIdx){
  __shared__ float red[4];
  int mat = blockIdx.x >> 8;
  int seg = blockIdx.x & 255;
  const float4* p = (const float4*)(src + (long)mat*epm);
  long n4 = epm >> 2;
  float s = 0.f;
  for (long i = (long)seg*256 + threadIdx.x; i < n4; i += 65536){
    float4 v = p[i];
    s += fabsf(v.x)+fabsf(v.y)+fabsf(v.z)+fabsf(v.w);
  }
  s = bredsum(s, red);
  if (threadIdx.x==0) part[(long)(baseIdx+mat)*256 + seg] = s;
}

// stage 2: finalize all 18 scales + grouped copies
__global__ __launch_bounds__(256) void finalize_scales_k(const float* __restrict__ part,
                                                         float* __restrict__ scales){
  __shared__ float red[4];
  const long numel[18] = {1048576, 1048576,1048576, 1048576,1048576, 1048576,1048576,
                          1048576,1048576, 4194304,4194304, 4194304,4194304, 4194304,4194304,
                          32768, 32768, 1024};
  for (int m=0;m<18;m++){
    float v = part[(long)m*256 + threadIdx.x];
    v = bredsum(v, red);
    if (threadIdx.x==0) scales[m] = v/(float)numel[m] + 1e-8f;
  }
  if (threadIdx.x==0){
    for (int l=0;l<2;l++){
      scales[18+l*3+0] = scales[1+l];   // wq
      scales[18+l*3+1] = scales[3+l];   // wk
      scales[18+l*3+2] = scales[5+l];   // wv
      scales[24+l*2+0] = scales[9+l];   // wg
      scales[24+l*2+1] = scales[11+l];  // wu
    }
  }
}

// ternary quantize weights -> bf16 {-1,0,1}   (float4 vectorized)
__global__ __launch_bounds__(256) void quantw_k(const float* __restrict__ src,
                                                unsigned short* __restrict__ dst,
                                                const float* __restrict__ sptr, long n){
  float s = *sptr;
  long n4 = n >> 2;
  long stride = (long)gridDim.x*256;
  for (long i = (long)blockIdx.x*256 + threadIdx.x; i < n4; i += stride){
    float4 v = ((const float4*)src)[i];
    ushort4 q;
    q.x = f2bf(fminf(fmaxf(rintf(v.x/s), -1.f), 1.f));
    q.y = f2bf(fminf(fmaxf(rintf(v.y/s), -1.f), 1.f));
    q.z = f2bf(fminf(fmaxf(rintf(v.z/s), -1.f), 1.f));
    q.w = f2bf(fminf(fmaxf(rintf(v.w/s), -1.f), 1.f));
    ((ushort4*)dst)[i] = q;
  }
}

// ---------------- loop_delta for all 8 iterations ----------------
__global__ __launch_bounds__(1024) void delta_all_k(const float* __restrict__ temb,
                                                    const float* __restrict__ lpw,
                                                    const float* __restrict__ lp2w,
                                                    const float* __restrict__ lp2b,
                                                    float* __restrict__ delta){
  int tid = threadIdx.x;
  int i = tid >> 7, b = (tid >> 6) & 1, j = tid & 63;
  float frac = (float)i / 7.f;
  int jj = j & 31;
  float fr = expf(-logf(10000.f) * (float)jj * (1.f/32.f));
  float ang = frac * fr;
  float sig = (j < 32) ? sinf(ang) : cosf(ang);
  float p1 = 0.f, p2 = 0.f;
  for (int k=0;k<256;k++){
    float te = temb[b*256+k];
    p1 += te * lpw[j*256+k];
    p2 += te * lp2w[j*256+k];
  }
  delta[i*128 + b*64 + j] = sig*p1 + p2 + lp2b[j];
}

// ---------------- RoPE cos/sin table: tab[(tpos*32+d)*2] = {cos,sin} ----------------
__global__ __launch_bounds__(256) void ropetab_k(float* __restrict__ tab){
  int i = blockIdx.x*256 + threadIdx.x;   // 512*32 = 16384
  int tpos = i >> 5, d = i & 31;
  float inv = powf(10000.f, -(float)d * (1.f/32.f));
  float sv, cv; sincosf((float)tpos * inv, &sv, &cv);
  tab[i*2]   = cv;
  tab[i*2+1] = sv;
}

// ---------------- row quant (1024 wide), optional rmsnorm ----------------
template<bool RMS>
__global__ __launch_bounds__(256) void rowquant1k_k(const float* __restrict__ x,
                                                    const float* __restrict__ gamma,
                                                    unsigned short* __restrict__ xq,
                                                    float* __restrict__ rs){
  __shared__ float red[4];
  int m = blockIdx.x, t = threadIdx.x;
  float v[4];
  float4 f = *(const float4*)(x + (size_t)m*1024 + t*4);
  v[0]=f.x; v[1]=f.y; v[2]=f.z; v[3]=f.w;
  if (RMS){
    float ss = v[0]*v[0]+v[1]*v[1]+v[2]*v[2]+v[3]*v[3];
    ss = bredsum(ss, red);
    float r1 = rsqrtf(ss*(1.f/1024.f) + 1e-6f);
#pragma unroll
    for (int j=0;j<4;j++) v[j] = v[j]*r1*gamma[t*4+j];
  }
  float am = fmaxf(fmaxf(fabsf(v[0]),fabsf(v[1])),fmaxf(fabsf(v[2]),fabsf(v[3])));
  am = bredmax(am, red);
  float a = fmaxf(am, 1e-8f), inv = 127.f/a;
  ushort4 q;
  q.x = f2bf(fminf(fmaxf(rintf(v[0]*inv),-128.f),127.f));
  q.y = f2bf(fminf(fmaxf(rintf(v[1]*inv),-128.f),127.f));
  q.z = f2bf(fminf(fmaxf(rintf(v[2]*inv),-128.f),127.f));
  q.w = f2bf(fminf(fmaxf(rintf(v[3]*inv),-128.f),127.f));
  *(ushort4*)(xq + (size_t)m*1024 + t*4) = q;
  if (t==0) rs[m] = a/127.f;
}

// ---------------- fused: h_in = rmsnorm(h+delta, lnw); a_in quant with n1 ----------------
__global__ __launch_bounds__(256) void loopnorm_quant_k(const float* __restrict__ h,
                                                        const float* __restrict__ delta,
                                                        const float* __restrict__ lnw,
                                                        const float* __restrict__ n1,
                                                        float* __restrict__ hin,
                                                        unsigned short* __restrict__ xq,
                                                        float* __restrict__ rs){
  __shared__ float red[4];
  int m = blockIdx.x, t = threadIdx.x;
  int b = m >> 9;
  float v[4];
  float4 f = *(const float4*)(h + (size_t)m*1024 + t*4);
  v[0]=f.x; v[1]=f.y; v[2]=f.z; v[3]=f.w;
  if (t < 16){
#pragma unroll
    for (int j=0;j<4;j++) v[j] += delta[b*64 + t*4 + j];
  }
  float ss = v[0]*v[0]+v[1]*v[1]+v[2]*v[2]+v[3]*v[3];
  ss = bredsum(ss, red);
  float r1 = rsqrtf(ss*(1.f/1024.f) + 1e-6f);
  float w4[4];
#pragma unroll
  for (int j=0;j<4;j++) w4[j] = v[j]*r1*lnw[t*4+j];
  float4 of; of.x=w4[0]; of.y=w4[1]; of.z=w4[2]; of.w=w4[3];
  *(float4*)(hin + (size_t)m*1024 + t*4) = of;
  float s2 = w4[0]*w4[0]+w4[1]*w4[1]+w4[2]*w4[2]+w4[3]*w4[3];
  s2 = bredsum(s2, red);
  float r2 = rsqrtf(s2*(1.f/1024.f) + 1e-6f);
  float y[4];
#pragma unroll
  for (int j=0;j<4;j++) y[j] = w4[j]*r2*n1[t*4+j];
  float am = fmaxf(fmaxf(fabsf(y[0]),fabsf(y[1])),fmaxf(fabsf(y[2]),fabsf(y[3])));
  am = bredmax(am, red);
  float a = fmaxf(am, 1e-8f), inv = 127.f/a;
  ushort4 q;
  q.x = f2bf(fminf(fmaxf(rintf(y[0]*inv),-128.f),127.f));
  q.y = f2bf(fminf(fmaxf(rintf(y[1]*inv),-128.f),127.f));
  q.z = f2bf(fminf(fmaxf(rintf(y[2]*inv),-128.f),127.f));
  q.w = f2bf(fminf(fmaxf(rintf(y[3]*inv),-128.f),127.f));
  *(ushort4*)(xq + (size_t)m*1024 + t*4) = q;
  if (t==0) rs[m] = a/127.f;
}

// ---------------- silu(g)*u over F=4096, then row quant ----------------
__global__ __launch_bounds__(256) void silu_mul_quant_k(const float* __restrict__ gu,
                                                        unsigned short* __restrict__ xq,
                                                        float* __restrict__ rs){
  __shared__ float red[4];
  int m = blockIdx.x, t = threadIdx.x;
  const float* g = gu + (size_t)m*8192;
  const float* u = g + 4096;
  float v[16];
#pragma unroll
  for (int j=0;j<16;j+=4){
    float4 gg = *(const float4*)(g + t*16 + j);
    float4 uu = *(const float4*)(u + t*16 + j);
    v[j+0] = gg.x/(1.f+expf(-gg.x))*uu.x;
    v[j+1] = gg.y/(1.f+expf(-gg.y))*uu.y;
    v[j+2] = gg.z/(1.f+expf(-gg.z))*uu.z;
    v[j+3] = gg.w/(1.f+expf(-gg.w))*uu.w;
  }
  float am = 0.f;
#pragma unroll
  for (int j=0;j<16;j++) am = fmaxf(am, fabsf(v[j]));
  am = bredmax(am, red);
  float a = fmaxf(am, 1e-8f), inv = 127.f/a;
#pragma unroll
  for (int j=0;j<16;j+=4){
    ushort4 q;
    q.x = f2bf(fminf(fmaxf(rintf(v[j+0]*inv),-128.f),127.f));
    q.y = f2bf(fminf(fmaxf(rintf(v[j+1]*inv),-128.f),127.f));
    q.z = f2bf(fminf(fmaxf(rintf(v[j+2]*inv),-128.f),127.f));
    q.w = f2bf(fminf(fmaxf(rintf(v[j+3]*inv),-128.f),127.f));
    *(ushort4*)(xq + (size_t)m*4096 + t*16 + j) = q;
  }
  if (t==0) rs[m] = a/127.f;
}

// ---------------- recurrence: h = A_eff*h + Be + alpha*bo ; quant h ----------------
__global__ __launch_bounds__(256) void recur_quant_k(float* __restrict__ h,
                                                     const float* __restrict__ Be,
                                                     const float* __restrict__ bo,
                                                     const float* __restrict__ Araw,
                                                     const float* __restrict__ alpha, int it,
                                                     unsigned short* __restrict__ xq,
                                                     float* __restrict__ rs){
  __shared__ float red[4];
  int m = blockIdx.x, t = threadIdx.x;
  float al = alpha[it];
  size_t base = (size_t)m*1024 + t*4;
  float4 hh = *(const float4*)(h + base);
  float4 be = *(const float4*)(Be + base);
  float4 bb = *(const float4*)(bo + base);
  float4 ar = *(const float4*)(Araw + t*4);
  float v[4];
  v[0] = 0.99f*tanhf(ar.x)*hh.x + be.x + al*bb.x;
  v[1] = 0.99f*tanhf(ar.y)*hh.y + be.y + al*bb.y;
  v[2] = 0.99f*tanhf(ar.z)*hh.z + be.z + al*bb.z;
  v[3] = 0.99f*tanhf(ar.w)*hh.w + be.w + al*bb.w;
  float4 of; of.x=v[0]; of.y=v[1]; of.z=v[2]; of.w=v[3];
  *(float4*)(h + base) = of;
  float am = fmaxf(fmaxf(fabsf(v[0]),fabsf(v[1])),fmaxf(fabsf(v[2]),fabsf(v[3])));
  am = bredmax(am, red);
  float a = fmaxf(am, 1e-8f), inv = 127.f/a;
  ushort4 q;
  q.x = f2bf(fminf(fmaxf(rintf(v[0]*inv),-128.f),127.f));
  q.y = f2bf(fminf(fmaxf(rintf(v[1]*inv),-128.f),127.f));
  q.z = f2bf(fminf(fmaxf(rintf(v[2]*inv),-128.f),127.f));
  q.w = f2bf(fminf(fmaxf(rintf(v[3]*inv),-128.f),127.f));
  *(ushort4*)(xq + (size_t)m*1024 + t*4) = q;
  if (t==0) rs[m] = a/127.f;
}

// ---------------- MFMA GEMM (pipelined, double-buffered, swizzled) ----------------
// C[M=1024,N] = Aq @ Wq^T * rowsc * wsc (+res)   or raw split-K partials.
DEV f32x4 accfence(f32x4 c){ asm volatile("s_nop 7\n\ts_nop 7" : "+v"(c)); return c; }

template<int SSHIFT, bool SPLITK, bool ROPE>
__global__ __launch_bounds__(256)
void gemm_bt(const unsigned short* __restrict__ A, const unsigned short* __restrict__ W,
             const float* __restrict__ rowsc, const float* __restrict__ wscv,
             const float* __restrict__ res, float* __restrict__ C, int N, int Kf, int Kc,
             const float* __restrict__ ropetab)
{
  __shared__ __align__(16) unsigned short As[2][128*32];
  __shared__ __align__(16) unsigned short Bs[2][128*32];
  const int tid = threadIdx.x;
  const int lane = tid & 63, wvid = tid >> 6;
  const int wr = wvid >> 1, wc = wvid & 1;
  const int bm = blockIdx.y, bn = blockIdx.x;

  // staging: each wave DMAs rows [wvid*16, wvid*16+16) and +64, 4 lanes/row x 16B.
  // XOR swizzle: physical 16B slot = logical slot ^ ((row>>1)&3); implemented by
  // pre-swizzling the GLOBAL source column (LDS dest stays linear for global_load_lds).
  const int r0 = (wvid<<4) + (lane>>2);
  const int sw = (((lane&3) ^ ((r0>>1)&3)) << 3);   // element offset of 8-elem chunk
  const long kstart = SPLITK ? (long)blockIdx.z * Kc : 0;
  const unsigned short* gA = A + (size_t)(bm*128 + r0)*Kf + kstart + sw;
  const unsigned short* gB = W + (size_t)(bn*128 + r0)*Kf + kstart + sw;
  const size_t row64 = (size_t)64*Kf;

#define STAGE(buf, koff) do { \
    __builtin_amdgcn_global_load_lds(gA + (koff),         &As[buf][(wvid<<9)],      16, 0, 0); \
    __builtin_amdgcn_global_load_lds(gA + (koff) + row64, &As[buf][(wvid<<9)+2048], 16, 0, 0); \
    __builtin_amdgcn_global_load_lds(gB + (koff),         &Bs[buf][(wvid<<9)],      16, 0, 0); \
    __builtin_amdgcn_global_load_lds(gB + (koff) + row64, &Bs[buf][(wvid<<9)+2048], 16, 0, 0); \
  } while(0)

  f32x4 acc[4][4] = {};
  const int rA = (wr<<6) + (lane&15);
  const int rB = (wc<<6) + (lane&15);
  // read-side swizzle: same XOR (row>>1)&3 — constant across mi/ni since 16 | stride
  const int psA = (((lane>>4) ^ (((lane&15)>>1)&3)) << 3);
  const int psB = psA;

  STAGE(0, 0);
  const int NT = Kc >> 5;
  int cur = 0;
  for (int kt = 0; kt < NT; ++kt){
    const int knext = (kt+1 < NT) ? ((kt+1)<<5) : 0;   // wrap: harmless reload of tile 0
    STAGE(cur^1, knext);
    asm volatile("s_waitcnt vmcnt(4)" ::: "memory");   // current tile's 4 DMAs done
    __builtin_amdgcn_s_barrier();
    asm volatile("" ::: "memory");
    i32x4 a[4], b[4];
    const unsigned short* Ab = As[cur];
    const unsigned short* Bb = Bs[cur];
#pragma unroll
    for (int mi=0;mi<4;mi++) a[mi] = *(const i32x4*)(Ab + (rA + mi*16)*32 + psA);
#pragma unroll
    for (int ni=0;ni<4;ni++) b[ni] = *(const i32x4*)(Bb + (rB + ni*16)*32 + psB);
#pragma unroll
    for (int mi=0;mi<4;mi++)
#pragma unroll
      for (int ni=0;ni<4;ni++)
        asm("v_mfma_f32_16x16x32_bf16 %0, %1, %2, %0" : "+v"(acc[mi][ni]) : "v"(a[mi]), "v"(b[ni]));
    asm volatile("s_waitcnt lgkmcnt(0)" ::: "memory"); // ds_reads landed before buffer reuse
    __builtin_amdgcn_s_barrier();
    cur ^= 1;
  }
#undef STAGE

#pragma unroll
  for (int mi=0;mi<4;mi++)
#pragma unroll
    for (int ni=0;ni<4;ni++)
      acc[mi][ni] = accfence(acc[mi][ni]);

  const int rif = (lane>>4)<<2;
  const int cif = lane&15;
  const int gcol0 = bn*128 + (wc<<6);

  if constexpr (SPLITK){
    float* P = C + ((size_t)blockIdx.z << 20);
#pragma unroll
    for (int mi=0;mi<4;mi++)
#pragma unroll
      for (int r=0;r<4;r++){
        const int grow = bm*128 + (wr<<6) + mi*16 + rif + r;
#pragma unroll
        for (int ni=0;ni<4;ni++)
          P[(size_t)grow*N + gcol0 + ni*16 + cif] = acc[mi][ni][r];
      }
    return;
  }

  if (ROPE && gcol0 < 2048){
    // this 64-col span is exactly one head; pair d <-> d+32 (ni in {0,1} <-> ni+2)
#pragma unroll
    for (int mi=0;mi<4;mi++){
#pragma unroll
      for (int r=0;r<4;r++){
        const int grow = bm*128 + (wr<<6) + mi*16 + rif + r;
        const float rsc = rowsc[grow];
        const int tpos = grow & 511;
#pragma unroll
        for (int np=0;np<2;np++){
          const int d = np*16 + cif;
          const float wsc = wscv[(gcol0 + d)>>SSHIFT];
          float2 cs = *(const float2*)(ropetab + ((tpos<<5) + d)*2);
          float x1 = acc[mi][np][r]   * rsc * wsc;
          float x2 = acc[mi][np+2][r] * rsc * wsc;
          C[(size_t)grow*N + gcol0 + d]      = x1*cs.x - x2*cs.y;
          C[(size_t)grow*N + gcol0 + 32 + d] = x1*cs.y + x2*cs.x;
        }
      }
    }
    return;
  }

#pragma unroll
  for (int mi=0;mi<4;mi++){
#pragma unroll
    for (int r=0;r<4;r++){
      const int grow = bm*128 + (wr<<6) + mi*16 + rif + r;
      const float rsc = rowsc[grow];
#pragma unroll
      for (int ni=0;ni<4;ni++){
        const int gcol = gcol0 + ni*16 + cif;
        float vvv = acc[mi][ni][r] * rsc * wscv[gcol>>SSHIFT];
        const size_t off = (size_t)grow*N + gcol;
        if (res) vvv += res[off];
        C[off] = vvv;
      }
    }
  }
}

// ---------------- split-K reduce (Z=4): C = res + (sum_z P)*rowsc*wsc ----------------
__global__ __launch_bounds__(256) void reduce4_k(const float* __restrict__ P,
                                                 const float* __restrict__ rowsc,
                                                 const float* __restrict__ wsc,
                                                 const float* __restrict__ res,
                                                 float* __restrict__ C){
  int m = blockIdx.x, t = threadIdx.x;
  float s0 = rowsc[m] * wsc[0];
  size_t off = (size_t)m*1024 + t*4;
  float4 a = *(const float4*)(P + off);
  float4 b = *(const float4*)(P + 1048576 + off);
  float4 c = *(const float4*)(P + 2097152 + off);
  float4 d = *(const float4*)(P + 3145728 + off);
  float4 r = *(const float4*)(res + off);
  float4 o;
  o.x = r.x + (a.x+b.x+c.x+d.x)*s0;
  o.y = r.y + (a.y+b.y+c.y+d.y)*s0;
  o.z = r.z + (a.z+b.z+c.z+d.z)*s0;
  o.w = r.w + (a.w+b.w+c.w+d.w)*s0;
  *(float4*)(C + off) = o;
}

// ---------------- flash-style f32 attention ----------------
__global__ __launch_bounds__(256) void attn_k(const float* __restrict__ qkv, float* __restrict__ o){
  constexpr int ST = 66;
  __shared__ float Qs[64*ST];
  __shared__ float Ks[64*ST];
  __shared__ float Vs[64*ST];
  __shared__ float Ps[64*ST];
  int tid = threadIdx.x;
  int qt = blockIdx.x & 7, bh = blockIdx.x >> 3;
  int b = bh >> 4, h = bh & 15;
  size_t qbase = ((size_t)(b*512 + qt*64))*3072 + h*64;

  for (int it = tid; it < 512; it += 256){
    int r = it >> 3, cc = (it & 7) * 8;
    const float* src = qkv + qbase + (size_t)r*3072 + cc;
    float4 v0 = *(const float4*)src, v1 = *(const float4*)(src+4);
    float* dst = Qs + r*ST + cc;
    *(float2*)(dst)   = make_float2(v0.x,v0.y);
    *(float2*)(dst+2) = make_float2(v0.z,v0.w);
    *(float2*)(dst+4) = make_float2(v1.x,v1.y);
    *(float2*)(dst+6) = make_float2(v1.z,v1.w);
  }

  float m_run[4] = {-1e30f,-1e30f,-1e30f,-1e30f};
  float l_run[4] = {0.f,0.f,0.f,0.f};
  float accO[4][4] = {};
  int tq = tid >> 4, tk = tid & 15;
  int q0 = tq*4, k0 = tk*4;

  for (int kt = 0; kt <= qt; ++kt){
    __syncthreads();
    size_t kbase = ((size_t)(b*512 + kt*64))*3072 + h*64;
    for (int it = tid; it < 512; it += 256){
      int r = it >> 3, cc = (it & 7) * 8;
      const float* sk = qkv + kbase + (size_t)r*3072 + 1024 + cc;
      const float* sv2 = qkv + kbase + (size_t)r*3072 + 2048 + cc;
      float4 a0 = *(const float4*)sk,  a1 = *(const float4*)(sk+4);
      float4 b0 = *(const float4*)sv2, b1 = *(const float4*)(sv2+4);
      float* dk = Ks + r*ST + cc;
      float* dv = Vs + r*ST + cc;
      *(float2*)(dk)   = make_float2(a0.x,a0.y);
      *(float2*)(dk+2) = make_float2(a0.z,a0.w);
      *(float2*)(dk+4) = make_float2(a1.x,a1.y);
      *(float2*)(dk+6) = make_float2(a1.z,a1.w);
      *(float2*)(dv)   = make_float2(b0.x,b0.y);
      *(float2*)(dv+2) = make_float2(b0.z,b0.w);
      *(float2*)(dv+4) = make_float2(b1.x,b1.y);
      *(float2*)(dv+6) = make_float2(b1.z,b1.w);
    }
    __syncthreads();

    float s[4][4] = {};
    for (int d=0; d<64; d+=2){
      float2 qv[4], kv[4];
#pragma unroll
      for (int x=0;x<4;x++) qv[x] = *(const float2*)(Qs + (q0+x)*ST + d);
#pragma unroll
      for (int x=0;x<4;x++) kv[x] = *(const float2*)(Ks + (k0+x)*ST + d);
#pragma unroll
      for (int qi=0;qi<4;qi++)
#pragma unroll
        for (int ki=0;ki<4;ki++)
          s[qi][ki] += qv[qi].x*kv[ki].x + qv[qi].y*kv[ki].y;
    }
    const bool diag = (kt == qt);
#pragma unroll
    for (int qi=0;qi<4;qi++){
#pragma unroll
      for (int ki=0;ki<4;ki++){
        float sv = s[qi][ki]*0.125f;
        if (diag && (k0+ki) > (q0+qi)) sv = -1.0e9f;
        s[qi][ki] = sv;
      }
      float m2 = fmaxf(fmaxf(s[qi][0],s[qi][1]), fmaxf(s[qi][2],s[qi][3]));
      m2 = fmaxf(m2, __shfl_xor(m2,1));
      m2 = fmaxf(m2, __shfl_xor(m2,2));
      m2 = fmaxf(m2, __shfl_xor(m2,4));
      m2 = fmaxf(m2, __shfl_xor(m2,8));
      float mn = fmaxf(m_run[qi], m2);
      float sf = expf(m_run[qi]-mn);
      m_run[qi] = mn;
      float p0 = 0.f;
#pragma unroll
      for (int ki=0;ki<4;ki++){
        float p = expf(s[qi][ki]-mn);
        Ps[(q0+qi)*ST + k0+ki] = p;
        p0 += p;
      }
      p0 += __shfl_xor(p0,1); p0 += __shfl_xor(p0,2);
      p0 += __shfl_xor(p0,4); p0 += __shfl_xor(p0,8);
      l_run[qi] = l_run[qi]*sf + p0;
#pragma unroll
      for (int di=0;di<4;di++) accO[qi][di] *= sf;
    }
    __syncthreads();
    for (int k=0;k<64;k++){
      float2 v01 = *(const float2*)(Vs + k*ST + k0);
      float2 v23 = *(const float2*)(Vs + k*ST + k0+2);
#pragma unroll
      for (int qi=0;qi<4;qi++){
        float p = Ps[(q0+qi)*ST + k];
        accO[qi][0] += p*v01.x; accO[qi][1] += p*v01.y;
        accO[qi][2] += p*v23.x; accO[qi][3] += p*v23.y;
      }
    }
  }
#pragma unroll
  for (int qi=0;qi<4;qi++){
    float invl = 1.f / l_run[qi];
#pragma unroll
    for (int di=0;di<4;di++)
      o[(size_t)(b*512 + qt*64 + q0+qi)*1024 + h*64 + k0+di] = accO[qi][di]*invl;
  }
}

// ---------------- LoRA down ----------------
__global__ __launch_bounds__(256) void lora_down_k(const unsigned short* __restrict__ xq,
                                                   const float* __restrict__ rs,
                                                   const unsigned short* __restrict__ ldq,
                                                   const float* __restrict__ sld,
                                                   float* __restrict__ t1){
  __shared__ float xrow[1024];
  __shared__ float part[256];
  int m = blockIdx.x, t = threadIdx.x;
  {
    ushort4 u = *(const ushort4*)(xq + (size_t)m*1024 + t*4);
    xrow[t*4+0]=bf2f(u.x); xrow[t*4+1]=bf2f(u.y); xrow[t*4+2]=bf2f(u.z); xrow[t*4+3]=bf2f(u.w);
  }
  __syncthreads();
  int r = t & 31, seg = t >> 5;
  const unsigned short* wrow = ldq + (size_t)r*1024 + seg*128;
  const float* xr = xrow + seg*128;
  float acc = 0.f;
  for (int k=0;k<128;k+=4){
    ushort4 w4 = *(const ushort4*)(wrow + k);
    acc += xr[k]*bf2f(w4.x) + xr[k+1]*bf2f(w4.y) + xr[k+2]*bf2f(w4.z) + xr[k+3]*bf2f(w4.w);
  }
  part[t] = acc;
  __syncthreads();
  if (t < 32){
    float s = 0.f;
    for (int sg=0; sg<8; sg++) s += part[sg*32 + t];
    t1[(size_t)m*32 + t] = s * rs[m] * (*sld);
  }
}

// ---------------- fused: topk+lora_up+h-update+act+sigmoid+h_out ----------------
__global__ __launch_bounds__(256) void finalize_k(const float* __restrict__ t1,
                                                  const unsigned short* __restrict__ luq,
                                                  const float* __restrict__ slu,
                                                  const unsigned short* __restrict__ actq,
                                                  const float* __restrict__ sact,
                                                  const float* __restrict__ ig, int it,
                                                  float* __restrict__ h, float* __restrict__ hout,
                                                  float* __restrict__ wsw){
  __shared__ float xs[32];
  __shared__ float red[4];
  __shared__ float sh_thr, sh_gs;
  int m = blockIdx.x, t = threadIdx.x;
  if (t < 32) xs[t] = t1[(size_t)m*32 + t];
  __syncthreads();
  float val = 0.f, av = 0.f, amax = 0.f;
  if (t < 32){
    val = xs[t]; av = fabsf(val);
    int rank = 0;
    for (int j=0;j<32;j++){
      float aj = fabsf(xs[j]);
      amax = fmaxf(amax, aj);
      if (aj > av || (aj == av && j < t)) rank++;
    }
    if (rank == 17) sh_thr = av;   // 18th largest (k = ceil(0.55*32) = 18)
  }
  __syncthreads();
  if (t < 32){
    float a = fmaxf(amax, 1e-8f);
    float q = 0.f;
    if (av >= sh_thr) q = fminf(fmaxf(rintf(val*(127.f/a)), -128.f), 127.f);
    xs[t] = q;
    if (t == 0) sh_gs = ig[it] * (*slu) * (a/127.f);
  }
  __syncthreads();
  float gs = sh_gs;
  float hn[4];
  int n0 = t*4;
#pragma unroll
  for (int ni=0;ni<4;ni++){
    const unsigned short* lr = luq + (size_t)(n0+ni)*32;
    float d = 0.f;
    for (int k=0;k<32;k+=4){
      ushort4 w4 = *(const ushort4*)(lr + k);
      d += xs[k]*bf2f(w4.x) + xs[k+1]*bf2f(w4.y) + xs[k+2]*bf2f(w4.z) + xs[k+3]*bf2f(w4.w);
    }
    hn[ni] = h[(size_t)m*1024 + n0+ni] + gs*d;
  }
  float am = fmaxf(fmaxf(fabsf(hn[0]),fabsf(hn[1])),fmaxf(fabsf(hn[2]),fabsf(hn[3])));
  am = bredmax(am, red);
  float a2 = fmaxf(am, 1e-8f), inv2 = 127.f/a2;
  float zp = 0.f;
#pragma unroll
  for (int ni=0;ni<4;ni++){
    float q = fminf(fmaxf(rintf(hn[ni]*inv2),-128.f),127.f);
    zp += q * bf2f(actq[n0+ni]);
  }
  zp = bredsum(zp, red);
  float z = zp * (a2/127.f) * (*sact);
  float wv = 1.f/(1.f+expf(-z));
#pragma unroll
  for (int ni=0;ni<4;ni++){
    size_t off = (size_t)m*1024 + n0+ni;
    float ho = hout[off];
    hout[off] = ho + wv*(hn[ni]-ho);
    h[off] = hn[ni];
  }
  if (t==0) wsw[it*1024 + m] = wv;
}

__global__ __launch_bounds__(256) void ponder_k(const float* __restrict__ wsw, float* __restrict__ out){
  __shared__ float red[4];
  float s = 0.f;
  for (int j=threadIdx.x; j<8192; j+=256) s += wsw[j];
  s = bredsum(s, red);
  if (threadIdx.x==0) out[0] = s*(1.f/8192.f);
}

// ================= host =================
extern "C" void kernel_launch(void* const* d_in, const int* in_sizes, int n_in,
                              void* d_out, int out_size, void* d_ws, size_t ws_size,
                              hipStream_t stream)
{
  (void)in_sizes; (void)n_in;
  const float* x     = (const float*)d_in[0];
  const float* e     = (const float*)d_in[1];
  const float* temb  = (const float*)d_in[2];
  const float* bn1   = (const float*)d_in[3];
  const float* bwq   = (const float*)d_in[4];
  const float* bwk   = (const float*)d_in[5];
  const float* bwv   = (const float*)d_in[6];
  const float* bwo   = (const float*)d_in[7];
  const float* bn2   = (const float*)d_in[8];
  const float* bwg   = (const float*)d_in[9];
  const float* bwu   = (const float*)d_in[10];
  const float* bwd   = (const float*)d_in[11];
  const float* Araw  = (const float*)d_in[12];
  const float* Bw    = (const float*)d_in[13];
  const float* ldw   = (const float*)d_in[14];
  const float* luw   = (const float*)d_in[15];
  const float* ig    = (const float*)d_in[16];
  const float* actw  = (const float*)d_in[17];
  const float* alph  = (const float*)d_in[18];
  const float* lpw   = (const float*)d_in[19];
  const float* lp2w  = (const float*)d_in[20];
  const float* lp2b  = (const float*)d_in[21];
  const float* lnw   = (const float*)d_in[22];

  char* ws = (char*)d_ws;
  float* out = (float*)d_out;
  const size_t WS_NEEDED = 130482688ull;
  if (ws_size < WS_NEEDED){
    fill_k<<<(out_size+255)/256,256,0,stream>>>(out, out_size, 1.0e9f);
    return;
  }

  unsigned short* qw_qkv = (unsigned short*)(ws + 0);
  unsigned short* qw_wo  = (unsigned short*)(ws + 12582912);
  unsigned short* qw_gu  = (unsigned short*)(ws + 16777216);
  unsigned short* qw_wd  = (unsigned short*)(ws + 50331648);
  unsigned short* qw_bw  = (unsigned short*)(ws + 67108864);
  unsigned short* qw_ld  = (unsigned short*)(ws + 69206016);
  unsigned short* qw_lu  = (unsigned short*)(ws + 69271552);
  unsigned short* qw_act = (unsigned short*)(ws + 69337088);
  float* scales = (float*)(ws + 69339136);
  float* part   = (float*)(ws + 69339648);
  float* delta  = (float*)(ws + 69358080);
  float* hbuf   = (float*)(ws + 69362176);
  float* Bebuf  = (float*)(ws + 73556480);
  float* bufX   = (float*)(ws + 77750784);
  float* bufY   = (float*)(ws + 81945088);
  float* qkvb   = (float*)(ws + 86139392);
  float* obuf   = (float*)(ws + 86139392 + 12582912);
  float* gub    = (float*)(ws + 86139392);            // 32MB scratch; also wd partials
  unsigned short* xq1k = (unsigned short*)(ws + 119693824);
  float* rs1k   = (float*)(ws + 121790976);
  unsigned short* xqm  = (unsigned short*)(ws + 121795072);
  float* rsm    = (float*)(ws + 130183680);
  float* t1     = (float*)(ws + 130187776);
  float* wsw    = (float*)(ws + 130318848);
  float* ropetab= (float*)(ws + 130351616);           // 128KB

  // ---- weight scales ----
  absmean_k<<<256,256,0,stream>>>(Bw,  1048576, part, 0);
  absmean_k<<<512,256,0,stream>>>(bwq, 1048576, part, 1);
  absmean_k<<<512,256,0,stream>>>(bwk, 1048576, part, 3);
  absmean_k<<<512,256,0,stream>>>(bwv, 1048576, part, 5);
  absmean_k<<<512,256,0,stream>>>(bwo, 1048576, part, 7);
  absmean_k<<<512,256,0,stream>>>(bwg, 4194304, part, 9);
  absmean_k<<<512,256,0,stream>>>(bwu, 4194304, part, 11);
  absmean_k<<<512,256,0,stream>>>(bwd, 4194304, part, 13);
  absmean_k<<<256,256,0,stream>>>(ldw, 32768, part, 15);
  absmean_k<<<256,256,0,stream>>>(luw, 32768, part, 16);
  absmean_k<<<256,256,0,stream>>>(actw, 1024, part, 17);
  finalize_scales_k<<<1,256,0,stream>>>(part, scales);

  // ---- quantize weights (ternary bf16) ----
  for (int l=0;l<2;l++){
    quantw_k<<<1024,256,0,stream>>>(bwq + (size_t)l*1048576, qw_qkv + (size_t)l*3145728,           scales+1+l, 1048576);
    quantw_k<<<1024,256,0,stream>>>(bwk + (size_t)l*1048576, qw_qkv + (size_t)l*3145728 + 1048576, scales+3+l, 1048576);
    quantw_k<<<1024,256,0,stream>>>(bwv + (size_t)l*1048576, qw_qkv + (size_t)l*3145728 + 2097152, scales+5+l, 1048576);
    quantw_k<<<1024,256,0,stream>>>(bwo + (size_t)l*1048576, qw_wo + (size_t)l*1048576, scales+7+l, 1048576);
    quantw_k<<<2048,256,0,stream>>>(bwg + (size_t)l*4194304, qw_gu + (size_t)l*8388608,           scales+9+l,  4194304);
    quantw_k<<<2048,256,0,stream>>>(bwu + (size_t)l*4194304, qw_gu + (size_t)l*8388608 + 4194304, scales+11+l, 4194304);
    quantw_k<<<2048,256,0,stream>>>(bwd + (size_t)l*4194304, qw_wd + (size_t)l*4194304, scales+13+l, 4194304);
  }
  quantw_k<<<1024,256,0,stream>>>(Bw,  qw_bw,  scales+0,  1048576);
  quantw_k<<<64,256,0,stream>>>(ldw, qw_ld, scales+15, 32768);
  quantw_k<<<64,256,0,stream>>>(luw, qw_lu, scales+16, 32768);
  quantw_k<<<4,256,0,stream>>>(actw, qw_act, scales+17, 1024);

  // ---- misc setup ----
  delta_all_k<<<1,1024,0,stream>>>(temb, lpw, lp2w, lp2b, delta);
  ropetab_k<<<64,256,0,stream>>>(ropetab);
  copy_init_k<<<1024,256,0,stream>>>(x, hbuf, out);

  // Be = bitlinear(e, B_w)
  rowquant1k_k<false><<<1024,256,0,stream>>>(e, nullptr, xq1k, rs1k);
  { dim3 g(8,8); gemm_bt<30,false,false><<<g,256,0,stream>>>(xq1k, qw_bw, rs1k, scales+0, nullptr, Bebuf, 1024, 1024, 1024, nullptr); }

  // ---- main recurrent loop (n_loops = 8) ----
  for (int it=0; it<8; ++it){
    loopnorm_quant_k<<<1024,256,0,stream>>>(hbuf, delta + it*128, lnw, bn1, bufX, xq1k, rs1k);
    for (int l=0;l<2;l++){
      if (l==1) rowquant1k_k<true><<<1024,256,0,stream>>>(bufX, bn1 + 1024, xq1k, rs1k);
      { dim3 g(24,8); gemm_bt<10,false,true><<<g,256,0,stream>>>(xq1k, qw_qkv + (size_t)l*3145728, rs1k, scales+18+l*3, nullptr, qkvb, 3072, 1024, 1024, ropetab); }
      attn_k<<<256,256,0,stream>>>(qkvb, obuf);
      rowquant1k_k<false><<<1024,256,0,stream>>>(obuf, nullptr, xq1k, rs1k);
      { dim3 g(8,8);  gemm_bt<30,false,false><<<g,256,0,stream>>>(xq1k, qw_wo + (size_t)l*1048576, rs1k, scales+7+l, bufX, bufY, 1024, 1024, 1024, nullptr); }
      rowquant1k_k<true><<<1024,256,0,stream>>>(bufY, bn2 + (size_t)l*1024, xq1k, rs1k);
      { dim3 g(64,8); gemm_bt<12,false,false><<<g,256,0,stream>>>(xq1k, qw_gu + (size_t)l*8388608, rs1k, scales+24+l*2, nullptr, gub, 8192, 1024, 1024, nullptr); }
      silu_mul_quant_k<<<1024,256,0,stream>>>(gub, xqm, rsm);
      { dim3 g(8,8,4); gemm_bt<0,true,false><<<g,256,0,stream>>>(xqm, qw_wd + (size_t)l*4194304, nullptr, nullptr, nullptr, gub, 1024, 4096, 1024, nullptr); }
      reduce4_k<<<1024,256,0,stream>>>(gub, rsm, scales+13+l, bufY, bufX);
    }
    recur_quant_k<<<1024,256,0,stream>>>(hbuf, Bebuf, bufX, Araw, alph, it, xq1k, rs1k);
    lora_down_k<<<1024,256,0,stream>>>(xq1k, rs1k, qw_ld, scales+15, t1);
    finalize_k<<<1024,256,0,stream>>>(t1, qw_lu, scales+16, qw_act, scales+17, ig, it, hbuf, out, wsw);
  }
  ponder_k<<<1,256,0,stream>>>(wsw, out + 1048576);
}

// Round 3
// 2875.432 us; speedup vs baseline: 1.7295x; 1.3631x over previous
//
#include <hip/hip_runtime.h>
#include <stdint.h>

#define DEV static __device__ __forceinline__

typedef float f32x4 __attribute__((ext_vector_type(4)));
typedef int   i32x4 __attribute__((ext_vector_type(4)));
typedef unsigned short u16x8 __attribute__((ext_vector_type(8)));

DEV float bf2f(unsigned short u){ return __uint_as_float(((unsigned int)u)<<16); }
DEV unsigned short f2bf(float f){ return (unsigned short)(__float_as_uint(f)>>16); } // exact for small ints
DEV unsigned short f2bfr(float f){ // round-to-nearest-even bf16
  unsigned int u = __float_as_uint(f);
  return (unsigned short)((u + 0x7FFF + ((u>>16)&1)) >> 16);
}

// ---------------- block reductions (256-thread blocks, 4 waves) ----------------
DEV float wredsum(float v){
#pragma unroll
  for (int o=32;o;o>>=1) v += __shfl_xor(v,o);
  return v;
}
DEV float wredmax(float v){
#pragma unroll
  for (int o=32;o;o>>=1) v = fmaxf(v,__shfl_xor(v,o));
  return v;
}
DEV float bredsum(float v, float* red){
  v = wredsum(v);
  if ((threadIdx.x&63)==0) red[threadIdx.x>>6] = v;
  __syncthreads();
  float r = red[0]+red[1]+red[2]+red[3];
  __syncthreads();
  return r;
}
DEV float bredmax(float v, float* red){
  v = wredmax(v);
  if ((threadIdx.x&63)==0) red[threadIdx.x>>6] = v;
  __syncthreads();
  float r = fmaxf(fmaxf(red[0],red[1]),fmaxf(red[2],red[3]));
  __syncthreads();
  return r;
}

// ---------------- misc ----------------
__global__ void fill_k(float* p, int n, float v){
  int i = blockIdx.x*256 + threadIdx.x;
  if (i < n) p[i] = v;
}

__global__ __launch_bounds__(256) void copy_init_k(const float* __restrict__ x,
                                                   float* __restrict__ h, float* __restrict__ ho){
  int i = blockIdx.x*256 + threadIdx.x;
  float4 v = *(const float4*)(x + (size_t)i*4);
  *(float4*)(h  + (size_t)i*4) = v;
  *(float4*)(ho + (size_t)i*4) = v;
}

// ---------------- weight scale: stage 1 partial |w| sums (float4) ----------------
__global__ __launch_bounds__(256) void absmean_k(const float* __restrict__ src, long epm,
                                                 float* __restrict__ part, int baseIdx){
  __shared__ float red[4];
  int mat = blockIdx.x >> 8;
  int seg = blockIdx.x & 255;
  const float4* p = (const float4*)(src + (long)mat*epm);
  long n4 = epm >> 2;
  float s = 0.f;
  for (long i = (long)seg*256 + threadIdx.x; i < n4; i += 65536){
    float4 v = p[i];
    s += fabsf(v.x)+fabsf(v.y)+fabsf(v.z)+fabsf(v.w);
  }
  s = bredsum(s, red);
  if (threadIdx.x==0) part[(long)(baseIdx+mat)*256 + seg] = s;
}

// stage 2: finalize all 18 scales + grouped copies
__global__ __launch_bounds__(256) void finalize_scales_k(const float* __restrict__ part,
                                                         float* __restrict__ scales){
  __shared__ float red[4];
  const long numel[18] = {1048576, 1048576,1048576, 1048576,1048576, 1048576,1048576,
                          1048576,1048576, 4194304,4194304, 4194304,4194304, 4194304,4194304,
                          32768, 32768, 1024};
  for (int m=0;m<18;m++){
    float v = part[(long)m*256 + threadIdx.x];
    v = bredsum(v, red);
    if (threadIdx.x==0) scales[m] = v/(float)numel[m] + 1e-8f;
  }
  if (threadIdx.x==0){
    for (int l=0;l<2;l++){
      scales[18+l*3+0] = scales[1+l];   // wq
      scales[18+l*3+1] = scales[3+l];   // wk
      scales[18+l*3+2] = scales[5+l];   // wv
      scales[24+l*2+0] = scales[9+l];   // wg
      scales[24+l*2+1] = scales[11+l];  // wu
    }
  }
}

// ternary quantize weights -> bf16 {-1,0,1}   (float4 vectorized)
__global__ __launch_bounds__(256) void quantw_k(const float* __restrict__ src,
                                                unsigned short* __restrict__ dst,
                                                const float* __restrict__ sptr, long n){
  float s = *sptr;
  long n4 = n >> 2;
  long stride = (long)gridDim.x*256;
  for (long i = (long)blockIdx.x*256 + threadIdx.x; i < n4; i += stride){
    float4 v = ((const float4*)src)[i];
    ushort4 q;
    q.x = f2bf(fminf(fmaxf(rintf(v.x/s), -1.f), 1.f));
    q.y = f2bf(fminf(fmaxf(rintf(v.y/s), -1.f), 1.f));
    q.z = f2bf(fminf(fmaxf(rintf(v.z/s), -1.f), 1.f));
    q.w = f2bf(fminf(fmaxf(rintf(v.w/s), -1.f), 1.f));
    ((ushort4*)dst)[i] = q;
  }
}

// ---------------- loop_delta for all 8 iterations ----------------
__global__ __launch_bounds__(1024) void delta_all_k(const float* __restrict__ temb,
                                                    const float* __restrict__ lpw,
                                                    const float* __restrict__ lp2w,
                                                    const float* __restrict__ lp2b,
                                                    float* __restrict__ delta){
  int tid = threadIdx.x;
  int i = tid >> 7, b = (tid >> 6) & 1, j = tid & 63;
  float frac = (float)i / 7.f;
  int jj = j & 31;
  float fr = expf(-logf(10000.f) * (float)jj * (1.f/32.f));
  float ang = frac * fr;
  float sig = (j < 32) ? sinf(ang) : cosf(ang);
  float p1 = 0.f, p2 = 0.f;
  for (int k=0;k<256;k++){
    float te = temb[b*256+k];
    p1 += te * lpw[j*256+k];
    p2 += te * lp2w[j*256+k];
  }
  delta[i*128 + b*64 + j] = sig*p1 + p2 + lp2b[j];
}

// ---------------- RoPE cos/sin table ----------------
__global__ __launch_bounds__(256) void ropetab_k(float* __restrict__ tab){
  int i = blockIdx.x*256 + threadIdx.x;   // 512*32 = 16384
  int tpos = i >> 5, d = i & 31;
  float inv = powf(10000.f, -(float)d * (1.f/32.f));
  float sv, cv; sincosf((float)tpos * inv, &sv, &cv);
  tab[i*2]   = cv;
  tab[i*2+1] = sv;
}

// ---------------- row quant (1024 wide), optional rmsnorm ----------------
template<bool RMS>
__global__ __launch_bounds__(256) void rowquant1k_k(const float* __restrict__ x,
                                                    const float* __restrict__ gamma,
                                                    unsigned short* __restrict__ xq,
                                                    float* __restrict__ rs){
  __shared__ float red[4];
  int m = blockIdx.x, t = threadIdx.x;
  float v[4];
  float4 f = *(const float4*)(x + (size_t)m*1024 + t*4);
  v[0]=f.x; v[1]=f.y; v[2]=f.z; v[3]=f.w;
  if (RMS){
    float ss = v[0]*v[0]+v[1]*v[1]+v[2]*v[2]+v[3]*v[3];
    ss = bredsum(ss, red);
    float r1 = rsqrtf(ss*(1.f/1024.f) + 1e-6f);
#pragma unroll
    for (int j=0;j<4;j++) v[j] = v[j]*r1*gamma[t*4+j];
  }
  float am = fmaxf(fmaxf(fabsf(v[0]),fabsf(v[1])),fmaxf(fabsf(v[2]),fabsf(v[3])));
  am = bredmax(am, red);
  float a = fmaxf(am, 1e-8f), inv = 127.f/a;
  ushort4 q;
  q.x = f2bf(fminf(fmaxf(rintf(v[0]*inv),-128.f),127.f));
  q.y = f2bf(fminf(fmaxf(rintf(v[1]*inv),-128.f),127.f));
  q.z = f2bf(fminf(fmaxf(rintf(v[2]*inv),-128.f),127.f));
  q.w = f2bf(fminf(fmaxf(rintf(v[3]*inv),-128.f),127.f));
  *(ushort4*)(xq + (size_t)m*1024 + t*4) = q;
  if (t==0) rs[m] = a/127.f;
}

// ---------------- fused: h_in = rmsnorm(h+delta, lnw); a_in quant with n1 ----------------
__global__ __launch_bounds__(256) void loopnorm_quant_k(const float* __restrict__ h,
                                                        const float* __restrict__ delta,
                                                        const float* __restrict__ lnw,
                                                        const float* __restrict__ n1,
                                                        float* __restrict__ hin,
                                                        unsigned short* __restrict__ xq,
                                                        float* __restrict__ rs){
  __shared__ float red[4];
  int m = blockIdx.x, t = threadIdx.x;
  int b = m >> 9;
  float v[4];
  float4 f = *(const float4*)(h + (size_t)m*1024 + t*4);
  v[0]=f.x; v[1]=f.y; v[2]=f.z; v[3]=f.w;
  if (t < 16){
#pragma unroll
    for (int j=0;j<4;j++) v[j] += delta[b*64 + t*4 + j];
  }
  float ss = v[0]*v[0]+v[1]*v[1]+v[2]*v[2]+v[3]*v[3];
  ss = bredsum(ss, red);
  float r1 = rsqrtf(ss*(1.f/1024.f) + 1e-6f);
  float w4[4];
#pragma unroll
  for (int j=0;j<4;j++) w4[j] = v[j]*r1*lnw[t*4+j];
  float4 of; of.x=w4[0]; of.y=w4[1]; of.z=w4[2]; of.w=w4[3];
  *(float4*)(hin + (size_t)m*1024 + t*4) = of;
  float s2 = w4[0]*w4[0]+w4[1]*w4[1]+w4[2]*w4[2]+w4[3]*w4[3];
  s2 = bredsum(s2, red);
  float r2 = rsqrtf(s2*(1.f/1024.f) + 1e-6f);
  float y[4];
#pragma unroll
  for (int j=0;j<4;j++) y[j] = w4[j]*r2*n1[t*4+j];
  float am = fmaxf(fmaxf(fabsf(y[0]),fabsf(y[1])),fmaxf(fabsf(y[2]),fabsf(y[3])));
  am = bredmax(am, red);
  float a = fmaxf(am, 1e-8f), inv = 127.f/a;
  ushort4 q;
  q.x = f2bf(fminf(fmaxf(rintf(y[0]*inv),-128.f),127.f));
  q.y = f2bf(fminf(fmaxf(rintf(y[1]*inv),-128.f),127.f));
  q.z = f2bf(fminf(fmaxf(rintf(y[2]*inv),-128.f),127.f));
  q.w = f2bf(fminf(fmaxf(rintf(y[3]*inv),-128.f),127.f));
  *(ushort4*)(xq + (size_t)m*1024 + t*4) = q;
  if (t==0) rs[m] = a/127.f;
}

// ---------------- silu(g)*u over F=4096, then row quant ----------------
__global__ __launch_bounds__(256) void silu_mul_quant_k(const float* __restrict__ gu,
                                                        unsigned short* __restrict__ xq,
                                                        float* __restrict__ rs){
  __shared__ float red[4];
  int m = blockIdx.x, t = threadIdx.x;
  const float* g = gu + (size_t)m*8192;
  const float* u = g + 4096;
  float v[16];
#pragma unroll
  for (int j=0;j<16;j+=4){
    float4 gg = *(const float4*)(g + t*16 + j);
    float4 uu = *(const float4*)(u + t*16 + j);
    v[j+0] = gg.x/(1.f+expf(-gg.x))*uu.x;
    v[j+1] = gg.y/(1.f+expf(-gg.y))*uu.y;
    v[j+2] = gg.z/(1.f+expf(-gg.z))*uu.z;
    v[j+3] = gg.w/(1.f+expf(-gg.w))*uu.w;
  }
  float am = 0.f;
#pragma unroll
  for (int j=0;j<16;j++) am = fmaxf(am, fabsf(v[j]));
  am = bredmax(am, red);
  float a = fmaxf(am, 1e-8f), inv = 127.f/a;
#pragma unroll
  for (int j=0;j<16;j+=4){
    ushort4 q;
    q.x = f2bf(fminf(fmaxf(rintf(v[j+0]*inv),-128.f),127.f));
    q.y = f2bf(fminf(fmaxf(rintf(v[j+1]*inv),-128.f),127.f));
    q.z = f2bf(fminf(fmaxf(rintf(v[j+2]*inv),-128.f),127.f));
    q.w = f2bf(fminf(fmaxf(rintf(v[j+3]*inv),-128.f),127.f));
    *(ushort4*)(xq + (size_t)m*4096 + t*16 + j) = q;
  }
  if (t==0) rs[m] = a/127.f;
}

// ---------------- recurrence: h = A_eff*h + Be + alpha*bo ; quant h ----------------
__global__ __launch_bounds__(256) void recur_quant_k(float* __restrict__ h,
                                                     const float* __restrict__ Be,
                                                     const float* __restrict__ bo,
                                                     const float* __restrict__ Araw,
                                                     const float* __restrict__ alpha, int it,
                                                     unsigned short* __restrict__ xq,
                                                     float* __restrict__ rs){
  __shared__ float red[4];
  int m = blockIdx.x, t = threadIdx.x;
  float al = alpha[it];
  size_t base = (size_t)m*1024 + t*4;
  float4 hh = *(const float4*)(h + base);
  float4 be = *(const float4*)(Be + base);
  float4 bb = *(const float4*)(bo + base);
  float4 ar = *(const float4*)(Araw + t*4);
  float v[4];
  v[0] = 0.99f*tanhf(ar.x)*hh.x + be.x + al*bb.x;
  v[1] = 0.99f*tanhf(ar.y)*hh.y + be.y + al*bb.y;
  v[2] = 0.99f*tanhf(ar.z)*hh.z + be.z + al*bb.z;
  v[3] = 0.99f*tanhf(ar.w)*hh.w + be.w + al*bb.w;
  float4 of; of.x=v[0]; of.y=v[1]; of.z=v[2]; of.w=v[3];
  *(float4*)(h + base) = of;
  float am = fmaxf(fmaxf(fabsf(v[0]),fabsf(v[1])),fmaxf(fabsf(v[2]),fabsf(v[3])));
  am = bredmax(am, red);
  float a = fmaxf(am, 1e-8f), inv = 127.f/a;
  ushort4 q;
  q.x = f2bf(fminf(fmaxf(rintf(v[0]*inv),-128.f),127.f));
  q.y = f2bf(fminf(fmaxf(rintf(v[1]*inv),-128.f),127.f));
  q.z = f2bf(fminf(fmaxf(rintf(v[2]*inv),-128.f),127.f));
  q.w = f2bf(fminf(fmaxf(rintf(v[3]*inv),-128.f),127.f));
  *(ushort4*)(xq + (size_t)m*1024 + t*4) = q;
  if (t==0) rs[m] = a/127.f;
}

// ---------------- MFMA GEMM (pipelined, double-buffered, swizzled) ----------------
DEV f32x4 accfence(f32x4 c){ asm volatile("s_nop 7\n\ts_nop 7" : "+v"(c)); return c; }

template<int SSHIFT, bool SPLITK, bool ROPE>
__global__ __launch_bounds__(256)
void gemm_bt(const unsigned short* __restrict__ A, const unsigned short* __restrict__ W,
             const float* __restrict__ rowsc, const float* __restrict__ wscv,
             const float* __restrict__ res, float* __restrict__ C, int N, int Kf, int Kc,
             const float* __restrict__ ropetab)
{
  __shared__ __align__(16) unsigned short As[2][128*32];
  __shared__ __align__(16) unsigned short Bs[2][128*32];
  const int tid = threadIdx.x;
  const int lane = tid & 63, wvid = tid >> 6;
  const int wr = wvid >> 1, wc = wvid & 1;
  const int bm = blockIdx.y, bn = blockIdx.x;

  const int r0 = (wvid<<4) + (lane>>2);
  const int sw = (((lane&3) ^ ((r0>>1)&3)) << 3);
  const long kstart = SPLITK ? (long)blockIdx.z * Kc : 0;
  const unsigned short* gA = A + (size_t)(bm*128 + r0)*Kf + kstart + sw;
  const unsigned short* gB = W + (size_t)(bn*128 + r0)*Kf + kstart + sw;
  const size_t row64 = (size_t)64*Kf;

#define STAGE(buf, koff) do { \
    __builtin_amdgcn_global_load_lds(gA + (koff),         &As[buf][(wvid<<9)],      16, 0, 0); \
    __builtin_amdgcn_global_load_lds(gA + (koff) + row64, &As[buf][(wvid<<9)+2048], 16, 0, 0); \
    __builtin_amdgcn_global_load_lds(gB + (koff),         &Bs[buf][(wvid<<9)],      16, 0, 0); \
    __builtin_amdgcn_global_load_lds(gB + (koff) + row64, &Bs[buf][(wvid<<9)+2048], 16, 0, 0); \
  } while(0)

  f32x4 acc[4][4] = {};
  const int rA = (wr<<6) + (lane&15);
  const int rB = (wc<<6) + (lane&15);
  const int psA = (((lane>>4) ^ (((lane&15)>>1)&3)) << 3);
  const int psB = psA;

  STAGE(0, 0);
  const int NT = Kc >> 5;
  int cur = 0;
  for (int kt = 0; kt < NT; ++kt){
    const int knext = (kt+1 < NT) ? ((kt+1)<<5) : 0;
    STAGE(cur^1, knext);
    asm volatile("s_waitcnt vmcnt(4)" ::: "memory");
    __builtin_amdgcn_s_barrier();
    asm volatile("" ::: "memory");
    i32x4 a[4], b[4];
    const unsigned short* Ab = As[cur];
    const unsigned short* Bb = Bs[cur];
#pragma unroll
    for (int mi=0;mi<4;mi++) a[mi] = *(const i32x4*)(Ab + (rA + mi*16)*32 + psA);
#pragma unroll
    for (int ni=0;ni<4;ni++) b[ni] = *(const i32x4*)(Bb + (rB + ni*16)*32 + psB);
#pragma unroll
    for (int mi=0;mi<4;mi++)
#pragma unroll
      for (int ni=0;ni<4;ni++)
        asm("v_mfma_f32_16x16x32_bf16 %0, %1, %2, %0" : "+v"(acc[mi][ni]) : "v"(a[mi]), "v"(b[ni]));
    asm volatile("s_waitcnt lgkmcnt(0)" ::: "memory");
    __builtin_amdgcn_s_barrier();
    cur ^= 1;
  }
#undef STAGE

#pragma unroll
  for (int mi=0;mi<4;mi++)
#pragma unroll
    for (int ni=0;ni<4;ni++)
      acc[mi][ni] = accfence(acc[mi][ni]);

  const int rif = (lane>>4)<<2;
  const int cif = lane&15;
  const int gcol0 = bn*128 + (wc<<6);

  if constexpr (SPLITK){
    float* P = C + ((size_t)blockIdx.z << 20);
#pragma unroll
    for (int mi=0;mi<4;mi++)
#pragma unroll
      for (int r=0;r<4;r++){
        const int grow = bm*128 + (wr<<6) + mi*16 + rif + r;
#pragma unroll
        for (int ni=0;ni<4;ni++)
          P[(size_t)grow*N + gcol0 + ni*16 + cif] = acc[mi][ni][r];
      }
    return;
  }

  if (ROPE && gcol0 < 2048){
#pragma unroll
    for (int mi=0;mi<4;mi++){
#pragma unroll
      for (int r=0;r<4;r++){
        const int grow = bm*128 + (wr<<6) + mi*16 + rif + r;
        const float rsc = rowsc[grow];
        const int tpos = grow & 511;
#pragma unroll
        for (int np=0;np<2;np++){
          const int d = np*16 + cif;
          const float wsc = wscv[(gcol0 + d)>>SSHIFT];
          float2 cs = *(const float2*)(ropetab + ((tpos<<5) + d)*2);
          float x1 = acc[mi][np][r]   * rsc * wsc;
          float x2 = acc[mi][np+2][r] * rsc * wsc;
          C[(size_t)grow*N + gcol0 + d]      = x1*cs.x - x2*cs.y;
          C[(size_t)grow*N + gcol0 + 32 + d] = x1*cs.y + x2*cs.x;
        }
      }
    }
    return;
  }

#pragma unroll
  for (int mi=0;mi<4;mi++){
#pragma unroll
    for (int r=0;r<4;r++){
      const int grow = bm*128 + (wr<<6) + mi*16 + rif + r;
      const float rsc = rowsc[grow];
#pragma unroll
      for (int ni=0;ni<4;ni++){
        const int gcol = gcol0 + ni*16 + cif;
        float vvv = acc[mi][ni][r] * rsc * wscv[gcol>>SSHIFT];
        const size_t off = (size_t)grow*N + gcol;
        if (res) vvv += res[off];
        C[off] = vvv;
      }
    }
  }
}

// ---------------- split-K reduce (Z=4): C = res + (sum_z P)*rowsc*wsc ----------------
__global__ __launch_bounds__(256) void reduce4_k(const float* __restrict__ P,
                                                 const float* __restrict__ rowsc,
                                                 const float* __restrict__ wsc,
                                                 const float* __restrict__ res,
                                                 float* __restrict__ C){
  int m = blockIdx.x, t = threadIdx.x;
  float s0 = rowsc[m] * wsc[0];
  size_t off = (size_t)m*1024 + t*4;
  float4 a = *(const float4*)(P + off);
  float4 b = *(const float4*)(P + 1048576 + off);
  float4 c = *(const float4*)(P + 2097152 + off);
  float4 d = *(const float4*)(P + 3145728 + off);
  float4 r = *(const float4*)(res + off);
  float4 o;
  o.x = r.x + (a.x+b.x+c.x+d.x)*s0;
  o.y = r.y + (a.y+b.y+c.y+d.y)*s0;
  o.z = r.z + (a.z+b.z+c.z+d.z)*s0;
  o.w = r.w + (a.w+b.w+c.w+d.w)*s0;
  *(float4*)(C + off) = o;
}

// ---------------- MFMA flash attention ----------------
// block = (b, h, qtile of 64). 4 waves x 16 q-rows. bf16 MFMA for QK^T and PV,
// f32 online softmax. LDS tiles XOR-swizzled: elem ^= (row&7)<<3.
DEV int swz64(int r, int c){ return r*64 + (c ^ ((r&7)<<3)); }
DEV u16x8 cvt8(float4 a, float4 b, float sc){
  u16x8 q;
  q[0]=f2bfr(a.x*sc); q[1]=f2bfr(a.y*sc); q[2]=f2bfr(a.z*sc); q[3]=f2bfr(a.w*sc);
  q[4]=f2bfr(b.x*sc); q[5]=f2bfr(b.y*sc); q[6]=f2bfr(b.z*sc); q[7]=f2bfr(b.w*sc);
  return q;
}

__global__ __launch_bounds__(256) void attn_mfma_k(const float* __restrict__ qkv,
                                                   float* __restrict__ o){
  __shared__ __align__(16) unsigned short Qs[4096];
  __shared__ __align__(16) unsigned short Ks[4096];
  __shared__ __align__(16) unsigned short Vt[4096];   // [d][k], swizzled on d
  __shared__ __align__(16) unsigned short Ps[4][1024];
  const int tid = threadIdx.x;
  const int lane = tid & 63, wv = tid >> 6;
  const int qt = blockIdx.x & 7, bh = blockIdx.x >> 3;
  const int b = bh >> 4, h = bh & 15;
  const size_t tokbase = (size_t)(b*512);
  const int l15 = lane & 15, lh = lane >> 4;

  { // stage Q (scaled by 1/sqrt(64)); wave w stages its own rows w*16..+15
    int r = tid >> 2, c0 = (tid & 3) << 4;
    const float* s = qkv + (tokbase + qt*64 + r)*3072 + h*64 + c0;
    float4 f0 = *(const float4*)s,     f1 = *(const float4*)(s+4);
    float4 f2 = *(const float4*)(s+8), f3 = *(const float4*)(s+12);
    *(u16x8*)(Qs + swz64(r, c0))   = cvt8(f0, f1, 0.125f);
    *(u16x8*)(Qs + swz64(r, c0+8)) = cvt8(f2, f3, 0.125f);
  }

  float m_run[4] = {-1e30f,-1e30f,-1e30f,-1e30f};
  float l_run[4] = {0.f,0.f,0.f,0.f};
  f32x4 accO[4] = {};

  for (int kt = 0; kt <= qt; ++kt){
    __syncthreads();
    { // stage K
      int r = tid >> 2, c0 = (tid & 3) << 4;
      const float* s = qkv + (tokbase + kt*64 + r)*3072 + 1024 + h*64 + c0;
      float4 f0 = *(const float4*)s,     f1 = *(const float4*)(s+4);
      float4 f2 = *(const float4*)(s+8), f3 = *(const float4*)(s+12);
      *(u16x8*)(Ks + swz64(r, c0))   = cvt8(f0, f1, 1.f);
      *(u16x8*)(Ks + swz64(r, c0+8)) = cvt8(f2, f3, 1.f);
    }
    { // stage V transposed: thread covers rows r0,r0+1 x cols cv..cv+8
      int r0 = (tid >> 3) << 1, cv = (tid & 7) << 3;
      const float* s0 = qkv + (tokbase + kt*64 + r0)*3072 + 2048 + h*64 + cv;
      const float* s1 = s0 + 3072;
      float4 a0 = *(const float4*)s0, a1 = *(const float4*)(s0+4);
      float4 b0 = *(const float4*)s1, b1 = *(const float4*)(s1+4);
      float va[8] = {a0.x,a0.y,a0.z,a0.w,a1.x,a1.y,a1.z,a1.w};
      float vb[8] = {b0.x,b0.y,b0.z,b0.w,b1.x,b1.y,b1.z,b1.w};
#pragma unroll
      for (int j=0;j<8;j++){
        int d = cv + j;
        unsigned int pk = (unsigned int)f2bfr(va[j]) | ((unsigned int)f2bfr(vb[j])<<16);
        *(unsigned int*)(Vt + swz64(d, r0)) = pk;
      }
    }
    __syncthreads();

    // QK^T -> s4[nt], rows (lh*4+r), cols nt*16+l15
    f32x4 s4[4] = {};
#pragma unroll
    for (int kc=0; kc<2; ++kc){
      i32x4 aq = *(const i32x4*)(Qs + swz64(wv*16 + l15, kc*32 + lh*8));
#pragma unroll
      for (int nt=0; nt<4; ++nt){
        i32x4 bk = *(const i32x4*)(Ks + swz64(nt*16 + l15, kc*32 + lh*8));
        asm("v_mfma_f32_16x16x32_bf16 %0, %1, %2, %0" : "+v"(s4[nt]) : "v"(aq), "v"(bk));
      }
    }
#pragma unroll
    for (int nt=0; nt<4; ++nt) s4[nt] = accfence(s4[nt]);

    const bool diag = (kt == qt);
    float sf[4];
#pragma unroll
    for (int r=0;r<4;r++){
      int rl = lh*4 + r;
      float mx = -1e30f;
#pragma unroll
      for (int nt=0; nt<4; ++nt){
        float v = s4[nt][r];
        if (diag && (nt*16 + l15) > (wv*16 + rl)) v = -1e30f;
        s4[nt][r] = v;
        mx = fmaxf(mx, v);
      }
      mx = fmaxf(mx, __shfl_xor(mx,1));
      mx = fmaxf(mx, __shfl_xor(mx,2));
      mx = fmaxf(mx, __shfl_xor(mx,4));
      mx = fmaxf(mx, __shfl_xor(mx,8));
      float mn = fmaxf(m_run[r], mx);
      sf[r] = __expf(m_run[r] - mn);
      m_run[r] = mn;
      float ps = 0.f;
#pragma unroll
      for (int nt=0; nt<4; ++nt){
        float p = __expf(s4[nt][r] - mn);
        ps += p;
        Ps[wv][swz64(rl, nt*16 + l15)] = f2bfr(p);
      }
      ps += __shfl_xor(ps,1); ps += __shfl_xor(ps,2);
      ps += __shfl_xor(ps,4); ps += __shfl_xor(ps,8);
      l_run[r] = l_run[r]*sf[r] + ps;
    }
#pragma unroll
    for (int dt=0; dt<4; ++dt){
#pragma unroll
      for (int r=0;r<4;r++) accO[dt][r] *= sf[r];
      accO[dt] = accfence(accO[dt]);   // VALU->MFMA SrcC hazard fence
    }
    // PV: A = P (rows l15), B = Vt
#pragma unroll
    for (int kc=0; kc<2; ++kc){
      i32x4 pa = *(const i32x4*)(Ps[wv] + swz64(l15, kc*32 + lh*8));
#pragma unroll
      for (int dt=0; dt<4; ++dt){
        i32x4 vb2 = *(const i32x4*)(Vt + swz64(dt*16 + l15, kc*32 + lh*8));
        asm("v_mfma_f32_16x16x32_bf16 %0, %1, %2, %0" : "+v"(accO[dt]) : "v"(pa), "v"(vb2));
      }
    }
  }
#pragma unroll
  for (int dt=0; dt<4; ++dt) accO[dt] = accfence(accO[dt]);
#pragma unroll
  for (int r=0;r<4;r++){
    float invl = 1.f / l_run[r];
    int row = qt*64 + wv*16 + lh*4 + r;
    float* op = o + (tokbase + row)*1024 + h*64 + l15;
#pragma unroll
    for (int dt=0; dt<4; ++dt)
      op[dt*16] = accO[dt][r] * invl;
  }
}

// ---------------- LoRA down ----------------
__global__ __launch_bounds__(256) void lora_down_k(const unsigned short* __restrict__ xq,
                                                   const float* __restrict__ rs,
                                                   const unsigned short* __restrict__ ldq,
                                                   const float* __restrict__ sld,
                                                   float* __restrict__ t1){
  __shared__ float xrow[1024];
  __shared__ float part[256];
  int m = blockIdx.x, t = threadIdx.x;
  {
    ushort4 u = *(const ushort4*)(xq + (size_t)m*1024 + t*4);
    xrow[t*4+0]=bf2f(u.x); xrow[t*4+1]=bf2f(u.y); xrow[t*4+2]=bf2f(u.z); xrow[t*4+3]=bf2f(u.w);
  }
  __syncthreads();
  int r = t & 31, seg = t >> 5;
  const unsigned short* wrow = ldq + (size_t)r*1024 + seg*128;
  const float* xr = xrow + seg*128;
  float acc = 0.f;
  for (int k=0;k<128;k+=4){
    ushort4 w4 = *(const ushort4*)(wrow + k);
    acc += xr[k]*bf2f(w4.x) + xr[k+1]*bf2f(w4.y) + xr[k+2]*bf2f(w4.z) + xr[k+3]*bf2f(w4.w);
  }
  part[t] = acc;
  __syncthreads();
  if (t < 32){
    float s = 0.f;
    for (int sg=0; sg<8; sg++) s += part[sg*32 + t];
    t1[(size_t)m*32 + t] = s * rs[m] * (*sld);
  }
}

// ---------------- fused: topk+lora_up+h-update+act+sigmoid+h_out ----------------
__global__ __launch_bounds__(256) void finalize_k(const float* __restrict__ t1,
                                                  const unsigned short* __restrict__ luq,
                                                  const float* __restrict__ slu,
                                                  const unsigned short* __restrict__ actq,
                                                  const float* __restrict__ sact,
                                                  const float* __restrict__ ig, int it,
                                                  float* __restrict__ h, float* __restrict__ hout,
                                                  float* __restrict__ wsw){
  __shared__ float xs[32];
  __shared__ float red[4];
  __shared__ float sh_thr, sh_gs;
  int m = blockIdx.x, t = threadIdx.x;
  if (t < 32) xs[t] = t1[(size_t)m*32 + t];
  __syncthreads();
  float val = 0.f, av = 0.f, amax = 0.f;
  if (t < 32){
    val = xs[t]; av = fabsf(val);
    int rank = 0;
    for (int j=0;j<32;j++){
      float aj = fabsf(xs[j]);
      amax = fmaxf(amax, aj);
      if (aj > av || (aj == av && j < t)) rank++;
    }
    if (rank == 17) sh_thr = av;   // 18th largest (k = ceil(0.55*32) = 18)
  }
  __syncthreads();
  if (t < 32){
    float a = fmaxf(amax, 1e-8f);
    float q = 0.f;
    if (av >= sh_thr) q = fminf(fmaxf(rintf(val*(127.f/a)), -128.f), 127.f);
    xs[t] = q;
    if (t == 0) sh_gs = ig[it] * (*slu) * (a/127.f);
  }
  __syncthreads();
  float gs = sh_gs;
  float hn[4];
  int n0 = t*4;
#pragma unroll
  for (int ni=0;ni<4;ni++){
    const unsigned short* lr = luq + (size_t)(n0+ni)*32;
    float d = 0.f;
    for (int k=0;k<32;k+=4){
      ushort4 w4 = *(const ushort4*)(lr + k);
      d += xs[k]*bf2f(w4.x) + xs[k+1]*bf2f(w4.y) + xs[k+2]*bf2f(w4.z) + xs[k+3]*bf2f(w4.w);
    }
    hn[ni] = h[(size_t)m*1024 + n0+ni] + gs*d;
  }
  float am = fmaxf(fmaxf(fabsf(hn[0]),fabsf(hn[1])),fmaxf(fabsf(hn[2]),fabsf(hn[3])));
  am = bredmax(am, red);
  float a2 = fmaxf(am, 1e-8f), inv2 = 127.f/a2;
  float zp = 0.f;
#pragma unroll
  for (int ni=0;ni<4;ni++){
    float q = fminf(fmaxf(rintf(hn[ni]*inv2),-128.f),127.f);
    zp += q * bf2f(actq[n0+ni]);
  }
  zp = bredsum(zp, red);
  float z = zp * (a2/127.f) * (*sact);
  float wv = 1.f/(1.f+expf(-z));
#pragma unroll
  for (int ni=0;ni<4;ni++){
    size_t off = (size_t)m*1024 + n0+ni;
    float ho = hout[off];
    hout[off] = ho + wv*(hn[ni]-ho);
    h[off] = hn[ni];
  }
  if (t==0) wsw[it*1024 + m] = wv;
}

__global__ __launch_bounds__(256) void ponder_k(const float* __restrict__ wsw, float* __restrict__ out){
  __shared__ float red[4];
  float s = 0.f;
  for (int j=threadIdx.x; j<8192; j+=256) s += wsw[j];
  s = bredsum(s, red);
  if (threadIdx.x==0) out[0] = s*(1.f/8192.f);
}

// ================= host =================
extern "C" void kernel_launch(void* const* d_in, const int* in_sizes, int n_in,
                              void* d_out, int out_size, void* d_ws, size_t ws_size,
                              hipStream_t stream)
{
  (void)in_sizes; (void)n_in;
  const float* x     = (const float*)d_in[0];
  const float* e     = (const float*)d_in[1];
  const float* temb  = (const float*)d_in[2];
  const float* bn1   = (const float*)d_in[3];
  const float* bwq   = (const float*)d_in[4];
  const float* bwk   = (const float*)d_in[5];
  const float* bwv   = (const float*)d_in[6];
  const float* bwo   = (const float*)d_in[7];
  const float* bn2   = (const float*)d_in[8];
  const float* bwg   = (const float*)d_in[9];
  const float* bwu   = (const float*)d_in[10];
  const float* bwd   = (const float*)d_in[11];
  const float* Araw  = (const float*)d_in[12];
  const float* Bw    = (const float*)d_in[13];
  const float* ldw   = (const float*)d_in[14];
  const float* luw   = (const float*)d_in[15];
  const float* ig    = (const float*)d_in[16];
  const float* actw  = (const float*)d_in[17];
  const float* alph  = (const float*)d_in[18];
  const float* lpw   = (const float*)d_in[19];
  const float* lp2w  = (const float*)d_in[20];
  const float* lp2b  = (const float*)d_in[21];
  const float* lnw   = (const float*)d_in[22];

  char* ws = (char*)d_ws;
  float* out = (float*)d_out;
  const size_t WS_NEEDED = 130482688ull;
  if (ws_size < WS_NEEDED){
    fill_k<<<(out_size+255)/256,256,0,stream>>>(out, out_size, 1.0e9f);
    return;
  }

  unsigned short* qw_qkv = (unsigned short*)(ws + 0);
  unsigned short* qw_wo  = (unsigned short*)(ws + 12582912);
  unsigned short* qw_gu  = (unsigned short*)(ws + 16777216);
  unsigned short* qw_wd  = (unsigned short*)(ws + 50331648);
  unsigned short* qw_bw  = (unsigned short*)(ws + 67108864);
  unsigned short* qw_ld  = (unsigned short*)(ws + 69206016);
  unsigned short* qw_lu  = (unsigned short*)(ws + 69271552);
  unsigned short* qw_act = (unsigned short*)(ws + 69337088);
  float* scales = (float*)(ws + 69339136);
  float* part   = (float*)(ws + 69339648);
  float* delta  = (float*)(ws + 69358080);
  float* hbuf   = (float*)(ws + 69362176);
  float* Bebuf  = (float*)(ws + 73556480);
  float* bufX   = (float*)(ws + 77750784);
  float* bufY   = (float*)(ws + 81945088);
  float* qkvb   = (float*)(ws + 86139392);
  float* obuf   = (float*)(ws + 86139392 + 12582912);
  float* gub    = (float*)(ws + 86139392);            // scratch: gu values / wd+wo partials
  unsigned short* xq1k = (unsigned short*)(ws + 119693824);
  float* rs1k   = (float*)(ws + 121790976);
  unsigned short* xqm  = (unsigned short*)(ws + 121795072);
  float* rsm    = (float*)(ws + 130183680);
  float* t1     = (float*)(ws + 130187776);
  float* wsw    = (float*)(ws + 130318848);
  float* ropetab= (float*)(ws + 130351616);           // 128KB

  // ---- weight scales ----
  absmean_k<<<256,256,0,stream>>>(Bw,  1048576, part, 0);
  absmean_k<<<512,256,0,stream>>>(bwq, 1048576, part, 1);
  absmean_k<<<512,256,0,stream>>>(bwk, 1048576, part, 3);
  absmean_k<<<512,256,0,stream>>>(bwv, 1048576, part, 5);
  absmean_k<<<512,256,0,stream>>>(bwo, 1048576, part, 7);
  absmean_k<<<512,256,0,stream>>>(bwg, 4194304, part, 9);
  absmean_k<<<512,256,0,stream>>>(bwu, 4194304, part, 11);
  absmean_k<<<512,256,0,stream>>>(bwd, 4194304, part, 13);
  absmean_k<<<256,256,0,stream>>>(ldw, 32768, part, 15);
  absmean_k<<<256,256,0,stream>>>(luw, 32768, part, 16);
  absmean_k<<<256,256,0,stream>>>(actw, 1024, part, 17);
  finalize_scales_k<<<1,256,0,stream>>>(part, scales);

  // ---- quantize weights (ternary bf16) ----
  for (int l=0;l<2;l++){
    quantw_k<<<1024,256,0,stream>>>(bwq + (size_t)l*1048576, qw_qkv + (size_t)l*3145728,           scales+1+l, 1048576);
    quantw_k<<<1024,256,0,stream>>>(bwk + (size_t)l*1048576, qw_qkv + (size_t)l*3145728 + 1048576, scales+3+l, 1048576);
    quantw_k<<<1024,256,0,stream>>>(bwv + (size_t)l*1048576, qw_qkv + (size_t)l*3145728 + 2097152, scales+5+l, 1048576);
    quantw_k<<<1024,256,0,stream>>>(bwo + (size_t)l*1048576, qw_wo + (size_t)l*1048576, scales+7+l, 1048576);
    quantw_k<<<2048,256,0,stream>>>(bwg + (size_t)l*4194304, qw_gu + (size_t)l*8388608,           scales+9+l,  4194304);
    quantw_k<<<2048,256,0,stream>>>(bwu + (size_t)l*4194304, qw_gu + (size_t)l*8388608 + 4194304, scales+11+l, 4194304);
    quantw_k<<<2048,256,0,stream>>>(bwd + (size_t)l*4194304, qw_wd + (size_t)l*4194304, scales+13+l, 4194304);
  }
  quantw_k<<<1024,256,0,stream>>>(Bw,  qw_bw,  scales+0,  1048576);
  quantw_k<<<64,256,0,stream>>>(ldw, qw_ld, scales+15, 32768);
  quantw_k<<<64,256,0,stream>>>(luw, qw_lu, scales+16, 32768);
  quantw_k<<<4,256,0,stream>>>(actw, qw_act, scales+17, 1024);

  // ---- misc setup ----
  delta_all_k<<<1,1024,0,stream>>>(temb, lpw, lp2w, lp2b, delta);
  ropetab_k<<<64,256,0,stream>>>(ropetab);
  copy_init_k<<<1024,256,0,stream>>>(x, hbuf, out);

  // Be = bitlinear(e, B_w)
  rowquant1k_k<false><<<1024,256,0,stream>>>(e, nullptr, xq1k, rs1k);
  { dim3 g(8,8); gemm_bt<30,false,false><<<g,256,0,stream>>>(xq1k, qw_bw, rs1k, scales+0, nullptr, Bebuf, 1024, 1024, 1024, nullptr); }

  // ---- main recurrent loop (n_loops = 8) ----
  for (int it=0; it<8; ++it){
    loopnorm_quant_k<<<1024,256,0,stream>>>(hbuf, delta + it*128, lnw, bn1, bufX, xq1k, rs1k);
    for (int l=0;l<2;l++){
      if (l==1) rowquant1k_k<true><<<1024,256,0,stream>>>(bufX, bn1 + 1024, xq1k, rs1k);
      { dim3 g(24,8); gemm_bt<10,false,true><<<g,256,0,stream>>>(xq1k, qw_qkv + (size_t)l*3145728, rs1k, scales+18+l*3, nullptr, qkvb, 3072, 1024, 1024, ropetab); }
      attn_mfma_k<<<256,256,0,stream>>>(qkvb, obuf);
      rowquant1k_k<false><<<1024,256,0,stream>>>(obuf, nullptr, xq1k, rs1k);
      { dim3 g(8,8,4); gemm_bt<0,true,false><<<g,256,0,stream>>>(xq1k, qw_wo + (size_t)l*1048576, nullptr, nullptr, nullptr, gub, 1024, 1024, 256, nullptr); }
      reduce4_k<<<1024,256,0,stream>>>(gub, rs1k, scales+7+l, bufX, bufY);
      rowquant1k_k<true><<<1024,256,0,stream>>>(bufY, bn2 + (size_t)l*1024, xq1k, rs1k);
      { dim3 g(64,8); gemm_bt<12,false,false><<<g,256,0,stream>>>(xq1k, qw_gu + (size_t)l*8388608, rs1k, scales+24+l*2, nullptr, gub, 8192, 1024, 1024, nullptr); }
      silu_mul_quant_k<<<1024,256,0,stream>>>(gub, xqm, rsm);
      { dim3 g(8,8,4); gemm_bt<0,true,false><<<g,256,0,stream>>>(xqm, qw_wd + (size_t)l*4194304, nullptr, nullptr, nullptr, gub, 1024, 4096, 1024, nullptr); }
      reduce4_k<<<1024,256,0,stream>>>(gub, rsm, scales+13+l, bufY, bufX);
    }
    recur_quant_k<<<1024,256,0,stream>>>(hbuf, Bebuf, bufX, Araw, alph, it, xq1k, rs1k);
    lora_down_k<<<1024,256,0,stream>>>(xq1k, rs1k, qw_ld, scales+15, t1);
    finalize_k<<<1024,256,0,stream>>>(t1, qw_lu, scales+16, qw_act, scales+17, ig, it, hbuf, out, wsw);
  }
  ponder_k<<<1,256,0,stream>>>(wsw, out + 1048576);
}

// Round 4
// 2572.979 us; speedup vs baseline: 1.9328x; 1.1175x over previous
//
#include <hip/hip_runtime.h>
#include <stdint.h>

#define DEV static __device__ __forceinline__

typedef float f32x4 __attribute__((ext_vector_type(4)));
typedef int   i32x4 __attribute__((ext_vector_type(4)));
typedef unsigned short u16x8 __attribute__((ext_vector_type(8)));

DEV float bf2f(unsigned short u){ return __uint_as_float(((unsigned int)u)<<16); }
DEV unsigned short f2bf(float f){ return (unsigned short)(__float_as_uint(f)>>16); } // exact for small ints
DEV unsigned short f2bfr(float f){ // round-to-nearest-even bf16
  unsigned int u = __float_as_uint(f);
  return (unsigned short)((u + 0x7FFF + ((u>>16)&1)) >> 16);
}

// ---------------- block reductions (256-thread blocks, 4 waves) ----------------
DEV float wredsum(float v){
#pragma unroll
  for (int o=32;o;o>>=1) v += __shfl_xor(v,o);
  return v;
}
DEV float wredmax(float v){
#pragma unroll
  for (int o=32;o;o>>=1) v = fmaxf(v,__shfl_xor(v,o));
  return v;
}
DEV float bredsum(float v, float* red){
  v = wredsum(v);
  if ((threadIdx.x&63)==0) red[threadIdx.x>>6] = v;
  __syncthreads();
  float r = red[0]+red[1]+red[2]+red[3];
  __syncthreads();
  return r;
}
DEV float bredmax(float v, float* red){
  v = wredmax(v);
  if ((threadIdx.x&63)==0) red[threadIdx.x>>6] = v;
  __syncthreads();
  float r = fmaxf(fmaxf(red[0],red[1]),fmaxf(red[2],red[3]));
  __syncthreads();
  return r;
}

// ---------------- misc ----------------
__global__ void fill_k(float* p, int n, float v){
  int i = blockIdx.x*256 + threadIdx.x;
  if (i < n) p[i] = v;
}

__global__ __launch_bounds__(256) void copy_init_k(const float* __restrict__ x,
                                                   float* __restrict__ h, float* __restrict__ ho){
  int i = blockIdx.x*256 + threadIdx.x;
  float4 v = *(const float4*)(x + (size_t)i*4);
  *(float4*)(h  + (size_t)i*4) = v;
  *(float4*)(ho + (size_t)i*4) = v;
  if (blockIdx.x==0 && threadIdx.x==0) ho[1048576] = 0.f;   // ponder accumulator
}

// ---------------- fused setup: 18 weight matrices ----------------
// order: 0:Bw 1:wq0 2:wq1 3:wk0 4:wk1 5:wv0 6:wv1 7:wo0 8:wo1
//        9:wg0 10:wg1 11:wu0 12:wu1 13:wd0 14:wd1 15:ld 16:lu 17:act
struct WSetup {
  const float* src[18];
  unsigned short* dst[18];
};
DEV long n4of(int mat){ return mat<9 ? 262144 : (mat<15 ? 1048576 : (mat<17 ? 8192 : 256)); }

__global__ __launch_bounds__(256) void absmean_all_k(WSetup wsu, float* __restrict__ part){
  __shared__ float red[4];
  int mat = blockIdx.x >> 8;
  int seg = blockIdx.x & 255;
  long n4 = n4of(mat);
  const float4* p = (const float4*)wsu.src[mat];
  float s = 0.f;
  for (long i = (long)seg*256 + threadIdx.x; i < n4; i += 65536){
    float4 v = p[i];
    s += fabsf(v.x)+fabsf(v.y)+fabsf(v.z)+fabsf(v.w);
  }
  s = bredsum(s, red);
  if (threadIdx.x==0) part[(long)mat*256 + seg] = s;
}

__global__ __launch_bounds__(256) void finalize_scales_k(const float* __restrict__ part,
                                                         float* __restrict__ scales){
  __shared__ float red[4];
  const long numel[18] = {1048576, 1048576,1048576, 1048576,1048576, 1048576,1048576,
                          1048576,1048576, 4194304,4194304, 4194304,4194304, 4194304,4194304,
                          32768, 32768, 1024};
  for (int m=0;m<18;m++){
    float v = part[(long)m*256 + threadIdx.x];
    v = bredsum(v, red);
    if (threadIdx.x==0) scales[m] = v/(float)numel[m] + 1e-8f;
  }
  if (threadIdx.x==0){
    for (int l=0;l<2;l++){
      scales[18+l*3+0] = scales[1+l];   // wq
      scales[18+l*3+1] = scales[3+l];   // wk
      scales[18+l*3+2] = scales[5+l];   // wv
      scales[24+l*2+0] = scales[9+l];   // wg
      scales[24+l*2+1] = scales[11+l];  // wu
    }
  }
}

// one kernel quantizes all 18 matrices; block -> (mat, seg of 1024 float4s)
__global__ __launch_bounds__(256) void quantw_all_k(WSetup wsu, const float* __restrict__ scales){
  int bid = blockIdx.x;
  int mat = 0, c = 0;
  for (;;){
    int nb = mat<9 ? 256 : (mat<15 ? 1024 : (mat<17 ? 8 : 1));
    if (bid < c + nb) break;
    c += nb; mat++;
  }
  long seg = bid - c;
  long n4 = n4of(mat);
  float s = scales[mat];
  const float4* src = (const float4*)wsu.src[mat];
  ushort4* dst = (ushort4*)wsu.dst[mat];
  long base = seg*1024;
#pragma unroll
  for (int k=0;k<4;k++){
    long i = base + k*256 + threadIdx.x;
    if (i < n4){
      float4 v = src[i];
      ushort4 q;
      q.x = f2bf(fminf(fmaxf(rintf(v.x/s), -1.f), 1.f));
      q.y = f2bf(fminf(fmaxf(rintf(v.y/s), -1.f), 1.f));
      q.z = f2bf(fminf(fmaxf(rintf(v.z/s), -1.f), 1.f));
      q.w = f2bf(fminf(fmaxf(rintf(v.w/s), -1.f), 1.f));
      dst[i] = q;
    }
  }
}

// ---------------- loop_delta: parallel dots, all 8 iterations ----------------
__global__ __launch_bounds__(256) void delta2_k(const float* __restrict__ temb,
                                                const float* __restrict__ lpw,
                                                const float* __restrict__ lp2w,
                                                const float* __restrict__ lp2b,
                                                float* __restrict__ delta){
  __shared__ float red[4];
  int blk = blockIdx.x;            // 128 = 2 b * 64 j
  int b = blk >> 6, j = blk & 63;
  int t = threadIdx.x;
  float te = temb[b*256 + t];
  float p1 = bredsum(te * lpw[j*256 + t], red);
  float p2 = bredsum(te * lp2w[j*256 + t], red);
  if (t < 8){
    int i = t;
    float frac = (float)i / 7.f;
    int jj = j & 31;
    float fr = expf(-logf(10000.f) * (float)jj * (1.f/32.f));
    float ang = frac * fr;
    float sig = (j < 32) ? sinf(ang) : cosf(ang);
    delta[i*128 + b*64 + j] = sig*p1 + p2 + lp2b[j];
  }
}

// ---------------- RoPE cos/sin table ----------------
__global__ __launch_bounds__(256) void ropetab_k(float* __restrict__ tab){
  int i = blockIdx.x*256 + threadIdx.x;   // 512*32 = 16384
  int tpos = i >> 5, d = i & 31;
  float inv = powf(10000.f, -(float)d * (1.f/32.f));
  float sv, cv; sincosf((float)tpos * inv, &sv, &cv);
  tab[i*2]   = cv;
  tab[i*2+1] = sv;
}

// ---------------- row quant (1024 wide), optional rmsnorm ----------------
template<bool RMS>
__global__ __launch_bounds__(256) void rowquant1k_k(const float* __restrict__ x,
                                                    const float* __restrict__ gamma,
                                                    unsigned short* __restrict__ xq,
                                                    float* __restrict__ rs){
  __shared__ float red[4];
  int m = blockIdx.x, t = threadIdx.x;
  float v[4];
  float4 f = *(const float4*)(x + (size_t)m*1024 + t*4);
  v[0]=f.x; v[1]=f.y; v[2]=f.z; v[3]=f.w;
  if (RMS){
    float ss = v[0]*v[0]+v[1]*v[1]+v[2]*v[2]+v[3]*v[3];
    ss = bredsum(ss, red);
    float r1 = rsqrtf(ss*(1.f/1024.f) + 1e-6f);
#pragma unroll
    for (int j=0;j<4;j++) v[j] = v[j]*r1*gamma[t*4+j];
  }
  float am = fmaxf(fmaxf(fabsf(v[0]),fabsf(v[1])),fmaxf(fabsf(v[2]),fabsf(v[3])));
  am = bredmax(am, red);
  float a = fmaxf(am, 1e-8f), inv = 127.f/a;
  ushort4 q;
  q.x = f2bf(fminf(fmaxf(rintf(v[0]*inv),-128.f),127.f));
  q.y = f2bf(fminf(fmaxf(rintf(v[1]*inv),-128.f),127.f));
  q.z = f2bf(fminf(fmaxf(rintf(v[2]*inv),-128.f),127.f));
  q.w = f2bf(fminf(fmaxf(rintf(v[3]*inv),-128.f),127.f));
  *(ushort4*)(xq + (size_t)m*1024 + t*4) = q;
  if (t==0) rs[m] = a/127.f;
}

// ---------------- fused: h_in = rmsnorm(h+delta, lnw); a_in quant with n1 ----------------
__global__ __launch_bounds__(256) void loopnorm_quant_k(const float* __restrict__ h,
                                                        const float* __restrict__ delta,
                                                        const float* __restrict__ lnw,
                                                        const float* __restrict__ n1,
                                                        float* __restrict__ hin,
                                                        unsigned short* __restrict__ xq,
                                                        float* __restrict__ rs){
  __shared__ float red[4];
  int m = blockIdx.x, t = threadIdx.x;
  int b = m >> 9;
  float v[4];
  float4 f = *(const float4*)(h + (size_t)m*1024 + t*4);
  v[0]=f.x; v[1]=f.y; v[2]=f.z; v[3]=f.w;
  if (t < 16){
#pragma unroll
    for (int j=0;j<4;j++) v[j] += delta[b*64 + t*4 + j];
  }
  float ss = v[0]*v[0]+v[1]*v[1]+v[2]*v[2]+v[3]*v[3];
  ss = bredsum(ss, red);
  float r1 = rsqrtf(ss*(1.f/1024.f) + 1e-6f);
  float w4[4];
#pragma unroll
  for (int j=0;j<4;j++) w4[j] = v[j]*r1*lnw[t*4+j];
  float4 of; of.x=w4[0]; of.y=w4[1]; of.z=w4[2]; of.w=w4[3];
  *(float4*)(hin + (size_t)m*1024 + t*4) = of;
  float s2 = w4[0]*w4[0]+w4[1]*w4[1]+w4[2]*w4[2]+w4[3]*w4[3];
  s2 = bredsum(s2, red);
  float r2 = rsqrtf(s2*(1.f/1024.f) + 1e-6f);
  float y[4];
#pragma unroll
  for (int j=0;j<4;j++) y[j] = w4[j]*r2*n1[t*4+j];
  float am = fmaxf(fmaxf(fabsf(y[0]),fabsf(y[1])),fmaxf(fabsf(y[2]),fabsf(y[3])));
  am = bredmax(am, red);
  float a = fmaxf(am, 1e-8f), inv = 127.f/a;
  ushort4 q;
  q.x = f2bf(fminf(fmaxf(rintf(y[0]*inv),-128.f),127.f));
  q.y = f2bf(fminf(fmaxf(rintf(y[1]*inv),-128.f),127.f));
  q.z = f2bf(fminf(fmaxf(rintf(y[2]*inv),-128.f),127.f));
  q.w = f2bf(fminf(fmaxf(rintf(y[3]*inv),-128.f),127.f));
  *(ushort4*)(xq + (size_t)m*1024 + t*4) = q;
  if (t==0) rs[m] = a/127.f;
}

// ---------------- silu(g)*u over F=4096, then row quant ----------------
__global__ __launch_bounds__(256) void silu_mul_quant_k(const float* __restrict__ gu,
                                                        unsigned short* __restrict__ xq,
                                                        float* __restrict__ rs){
  __shared__ float red[4];
  int m = blockIdx.x, t = threadIdx.x;
  const float* g = gu + (size_t)m*8192;
  const float* u = g + 4096;
  float v[16];
#pragma unroll
  for (int j=0;j<16;j+=4){
    float4 gg = *(const float4*)(g + t*16 + j);
    float4 uu = *(const float4*)(u + t*16 + j);
    v[j+0] = gg.x/(1.f+expf(-gg.x))*uu.x;
    v[j+1] = gg.y/(1.f+expf(-gg.y))*uu.y;
    v[j+2] = gg.z/(1.f+expf(-gg.z))*uu.z;
    v[j+3] = gg.w/(1.f+expf(-gg.w))*uu.w;
  }
  float am = 0.f;
#pragma unroll
  for (int j=0;j<16;j++) am = fmaxf(am, fabsf(v[j]));
  am = bredmax(am, red);
  float a = fmaxf(am, 1e-8f), inv = 127.f/a;
#pragma unroll
  for (int j=0;j<16;j+=4){
    ushort4 q;
    q.x = f2bf(fminf(fmaxf(rintf(v[j+0]*inv),-128.f),127.f));
    q.y = f2bf(fminf(fmaxf(rintf(v[j+1]*inv),-128.f),127.f));
    q.z = f2bf(fminf(fmaxf(rintf(v[j+2]*inv),-128.f),127.f));
    q.w = f2bf(fminf(fmaxf(rintf(v[j+3]*inv),-128.f),127.f));
    *(ushort4*)(xq + (size_t)m*4096 + t*16 + j) = q;
  }
  if (t==0) rs[m] = a/127.f;
}

// ---------------- MFMA GEMM (pipelined, double-buffered, swizzled) ----------------
DEV f32x4 accfence(f32x4 c){ asm volatile("s_nop 7\n\ts_nop 7" : "+v"(c)); return c; }

template<int SSHIFT, bool SPLITK>
__global__ __launch_bounds__(256)
void gemm_bt(const unsigned short* __restrict__ A, const unsigned short* __restrict__ W,
             const float* __restrict__ rowsc, const float* __restrict__ wscv,
             const float* __restrict__ res, float* __restrict__ C, int N, int Kf, int Kc)
{
  __shared__ __align__(16) unsigned short As[2][128*32];
  __shared__ __align__(16) unsigned short Bs[2][128*32];
  const int tid = threadIdx.x;
  const int lane = tid & 63, wvid = tid >> 6;
  const int wr = wvid >> 1, wc = wvid & 1;
  const int bm = blockIdx.y, bn = blockIdx.x;

  const int r0 = (wvid<<4) + (lane>>2);
  const int sw = (((lane&3) ^ ((r0>>1)&3)) << 3);
  const long kstart = SPLITK ? (long)blockIdx.z * Kc : 0;
  const unsigned short* gA = A + (size_t)(bm*128 + r0)*Kf + kstart + sw;
  const unsigned short* gB = W + (size_t)(bn*128 + r0)*Kf + kstart + sw;
  const size_t row64 = (size_t)64*Kf;

#define STAGE(buf, koff) do { \
    __builtin_amdgcn_global_load_lds(gA + (koff),         &As[buf][(wvid<<9)],      16, 0, 0); \
    __builtin_amdgcn_global_load_lds(gA + (koff) + row64, &As[buf][(wvid<<9)+2048], 16, 0, 0); \
    __builtin_amdgcn_global_load_lds(gB + (koff),         &Bs[buf][(wvid<<9)],      16, 0, 0); \
    __builtin_amdgcn_global_load_lds(gB + (koff) + row64, &Bs[buf][(wvid<<9)+2048], 16, 0, 0); \
  } while(0)

  f32x4 acc[4][4] = {};
  const int rA = (wr<<6) + (lane&15);
  const int rB = (wc<<6) + (lane&15);
  const int psA = (((lane>>4) ^ (((lane&15)>>1)&3)) << 3);
  const int psB = psA;

  STAGE(0, 0);
  const int NT = Kc >> 5;
  int cur = 0;
  for (int kt = 0; kt < NT; ++kt){
    const int knext = (kt+1 < NT) ? ((kt+1)<<5) : 0;
    STAGE(cur^1, knext);
    asm volatile("s_waitcnt vmcnt(4)" ::: "memory");
    __builtin_amdgcn_s_barrier();
    asm volatile("" ::: "memory");
    i32x4 a[4], b[4];
    const unsigned short* Ab = As[cur];
    const unsigned short* Bb = Bs[cur];
#pragma unroll
    for (int mi=0;mi<4;mi++) a[mi] = *(const i32x4*)(Ab + (rA + mi*16)*32 + psA);
#pragma unroll
    for (int ni=0;ni<4;ni++) b[ni] = *(const i32x4*)(Bb + (rB + ni*16)*32 + psB);
#pragma unroll
    for (int mi=0;mi<4;mi++)
#pragma unroll
      for (int ni=0;ni<4;ni++)
        asm("v_mfma_f32_16x16x32_bf16 %0, %1, %2, %0" : "+v"(acc[mi][ni]) : "v"(a[mi]), "v"(b[ni]));
    asm volatile("s_waitcnt lgkmcnt(0)" ::: "memory");
    __builtin_amdgcn_s_barrier();
    cur ^= 1;
  }
#undef STAGE

#pragma unroll
  for (int mi=0;mi<4;mi++)
#pragma unroll
    for (int ni=0;ni<4;ni++)
      acc[mi][ni] = accfence(acc[mi][ni]);

  const int rif = (lane>>4)<<2;
  const int cif = lane&15;
  const int gcol0 = bn*128 + (wc<<6);

  if constexpr (SPLITK){
    float* P = C + (size_t)blockIdx.z * ((size_t)N << 10);
#pragma unroll
    for (int mi=0;mi<4;mi++)
#pragma unroll
      for (int r=0;r<4;r++){
        const int grow = bm*128 + (wr<<6) + mi*16 + rif + r;
#pragma unroll
        for (int ni=0;ni<4;ni++)
          P[(size_t)grow*N + gcol0 + ni*16 + cif] = acc[mi][ni][r];
      }
    return;
  }

#pragma unroll
  for (int mi=0;mi<4;mi++){
#pragma unroll
    for (int r=0;r<4;r++){
      const int grow = bm*128 + (wr<<6) + mi*16 + rif + r;
      const float rsc = rowsc[grow];
#pragma unroll
      for (int ni=0;ni<4;ni++){
        const int gcol = gcol0 + ni*16 + cif;
        float vvv = acc[mi][ni][r] * rsc * wscv[gcol>>SSHIFT];
        const size_t off = (size_t)grow*N + gcol;
        if (res) vvv += res[off];
        C[off] = vvv;
      }
    }
  }
}

// ---------------- split-K(2) reduce + scales + RoPE -> qkvb (in-place alias of P z=0 ok) ----------------
__global__ __launch_bounds__(256) void rope_reduce_k(const float* P,
                                                     const float* __restrict__ rowsc,
                                                     const float* __restrict__ wscv,
                                                     const float* __restrict__ tab,
                                                     float* C){
  int m = blockIdx.x, t = threadIdx.x;
  const float rsc = rowsc[m];
  const int tpos = m & 511;
  const size_t base = (size_t)m*3072;
  const float* P1 = P + 3145728;
  // rotation pairs (q and k): thread handles pairs p0..p0+3 (same head)
  int p0 = t*4;
  int hh = p0 >> 5, d = p0 & 31;
  int c1 = hh*64 + d;
  float wsc = wscv[c1>>10] * rsc;
  float4 xa0 = *(const float4*)(P  + base + c1);
  float4 xa1 = *(const float4*)(P1 + base + c1);
  float4 xb0 = *(const float4*)(P  + base + c1 + 32);
  float4 xb1 = *(const float4*)(P1 + base + c1 + 32);
  float4 cs01 = *(const float4*)(tab + ((size_t)tpos*32 + d)*2);
  float4 cs23 = *(const float4*)(tab + ((size_t)tpos*32 + d)*2 + 4);
  // v columns
  int cv = 2048 + t*4;
  float4 va = *(const float4*)(P  + base + cv);
  float4 vb = *(const float4*)(P1 + base + cv);
  float wv2 = wscv[2] * rsc;

  float x1[4] = {(xa0.x+xa1.x)*wsc, (xa0.y+xa1.y)*wsc, (xa0.z+xa1.z)*wsc, (xa0.w+xa1.w)*wsc};
  float x2[4] = {(xb0.x+xb1.x)*wsc, (xb0.y+xb1.y)*wsc, (xb0.z+xb1.z)*wsc, (xb0.w+xb1.w)*wsc};
  float cc[4] = {cs01.x, cs01.z, cs23.x, cs23.z};
  float ss[4] = {cs01.y, cs01.w, cs23.y, cs23.w};
  float4 o1, o2, ov;
  o1.x = x1[0]*cc[0] - x2[0]*ss[0];  o2.x = x1[0]*ss[0] + x2[0]*cc[0];
  o1.y = x1[1]*cc[1] - x2[1]*ss[1];  o2.y = x1[1]*ss[1] + x2[1]*cc[1];
  o1.z = x1[2]*cc[2] - x2[2]*ss[2];  o2.z = x1[2]*ss[2] + x2[2]*cc[2];
  o1.w = x1[3]*cc[3] - x2[3]*ss[3];  o2.w = x1[3]*ss[3] + x2[3]*cc[3];
  ov.x = (va.x+vb.x)*wv2; ov.y = (va.y+vb.y)*wv2; ov.z = (va.z+vb.z)*wv2; ov.w = (va.w+vb.w)*wv2;
  *(float4*)(C + base + c1)      = o1;
  *(float4*)(C + base + c1 + 32) = o2;
  *(float4*)(C + base + cv)      = ov;
}

// ---------------- split-K(4) reduce: C = (res?) + (sum P)*rowsc*wsc ----------------
__global__ __launch_bounds__(256) void reduce4_k(const float* __restrict__ P,
                                                 const float* __restrict__ rowsc,
                                                 const float* __restrict__ wsc,
                                                 const float* __restrict__ res,
                                                 float* __restrict__ C){
  int m = blockIdx.x, t = threadIdx.x;
  float s0 = rowsc[m] * wsc[0];
  size_t off = (size_t)m*1024 + t*4;
  float4 a = *(const float4*)(P + off);
  float4 b = *(const float4*)(P + 1048576 + off);
  float4 c = *(const float4*)(P + 2097152 + off);
  float4 d = *(const float4*)(P + 3145728 + off);
  float4 o;
  o.x = (a.x+b.x+c.x+d.x)*s0;
  o.y = (a.y+b.y+c.y+d.y)*s0;
  o.z = (a.z+b.z+c.z+d.z)*s0;
  o.w = (a.w+b.w+c.w+d.w)*s0;
  if (res){
    float4 r = *(const float4*)(res + off);
    o.x += r.x; o.y += r.y; o.z += r.z; o.w += r.w;
  }
  *(float4*)(C + off) = o;
}

// ---------------- fused: split-K(4) reduce + residual + rmsnorm + quant ----------------
// NOTE: rowsc may alias rs (reads complete before first barrier; write after).
__global__ __launch_bounds__(256) void redq_norm_k(const float* __restrict__ P,
                                                   const float* rowsc,
                                                   const float* __restrict__ wsc,
                                                   const float* __restrict__ res,
                                                   const float* __restrict__ gamma,
                                                   float* __restrict__ Cout,
                                                   unsigned short* __restrict__ xq,
                                                   float* rs){
  __shared__ float red[4];
  int m = blockIdx.x, t = threadIdx.x;
  float s0 = rowsc[m] * wsc[0];
  size_t off = (size_t)m*1024 + t*4;
  float4 a = *(const float4*)(P + off);
  float4 b = *(const float4*)(P + 1048576 + off);
  float4 c = *(const float4*)(P + 2097152 + off);
  float4 d = *(const float4*)(P + 3145728 + off);
  float4 r4 = *(const float4*)(res + off);
  float v[4];
  v[0] = r4.x + (a.x+b.x+c.x+d.x)*s0;
  v[1] = r4.y + (a.y+b.y+c.y+d.y)*s0;
  v[2] = r4.z + (a.z+b.z+c.z+d.z)*s0;
  v[3] = r4.w + (a.w+b.w+c.w+d.w)*s0;
  float4 of; of.x=v[0]; of.y=v[1]; of.z=v[2]; of.w=v[3];
  *(float4*)(Cout + off) = of;
  float ss = v[0]*v[0]+v[1]*v[1]+v[2]*v[2]+v[3]*v[3];
  ss = bredsum(ss, red);
  float r1 = rsqrtf(ss*(1.f/1024.f) + 1e-6f);
  float y[4];
#pragma unroll
  for (int j=0;j<4;j++) y[j] = v[j]*r1*gamma[t*4+j];
  float am = fmaxf(fmaxf(fabsf(y[0]),fabsf(y[1])),fmaxf(fabsf(y[2]),fabsf(y[3])));
  am = bredmax(am, red);
  float aq = fmaxf(am, 1e-8f), inv = 127.f/aq;
  ushort4 q;
  q.x = f2bf(fminf(fmaxf(rintf(y[0]*inv),-128.f),127.f));
  q.y = f2bf(fminf(fmaxf(rintf(y[1]*inv),-128.f),127.f));
  q.z = f2bf(fminf(fmaxf(rintf(y[2]*inv),-128.f),127.f));
  q.w = f2bf(fminf(fmaxf(rintf(y[3]*inv),-128.f),127.f));
  *(ushort4*)(xq + (size_t)m*1024 + t*4) = q;
  if (t==0) rs[m] = aq/127.f;
}

// ---------------- fused tail (l=1 wd): reduce + recurrence + quant + loraDown
//                  + topk + loraUp + act-sigmoid + h_out blend + ponder ----------------
__global__ __launch_bounds__(256) void redfin_k(const float* __restrict__ P,
                                                const float* __restrict__ rowsc,
                                                const float* __restrict__ wsc,
                                                const float* __restrict__ res,
                                                float* __restrict__ h,
                                                const float* __restrict__ Be,
                                                const float* __restrict__ Araw,
                                                const float* __restrict__ alpha, int it,
                                                const unsigned short* __restrict__ ldq,
                                                const float* __restrict__ sld,
                                                const unsigned short* __restrict__ luq,
                                                const float* __restrict__ slu,
                                                const unsigned short* __restrict__ actq,
                                                const float* __restrict__ sact,
                                                const float* __restrict__ ig,
                                                float* __restrict__ hout,
                                                float* __restrict__ ponder){
  __shared__ float red[4];
  __shared__ float xrow[1024];
  __shared__ float part[256];
  __shared__ float xs[32];
  __shared__ float sh_thr, sh_gs;
  int m = blockIdx.x, t = threadIdx.x;
  float al = alpha[it];
  float s0 = rowsc[m] * wsc[0];
  size_t off = (size_t)m*1024 + t*4;
  float4 a = *(const float4*)(P + off);
  float4 b = *(const float4*)(P + 1048576 + off);
  float4 c = *(const float4*)(P + 2097152 + off);
  float4 d = *(const float4*)(P + 3145728 + off);
  float4 r4 = *(const float4*)(res + off);
  float4 hh = *(const float4*)(h + off);
  float4 be = *(const float4*)(Be + off);
  float4 ar = *(const float4*)(Araw + t*4);
  float v[4];
  v[0] = 0.99f*tanhf(ar.x)*hh.x + be.x + al*(r4.x + (a.x+b.x+c.x+d.x)*s0);
  v[1] = 0.99f*tanhf(ar.y)*hh.y + be.y + al*(r4.y + (a.y+b.y+c.y+d.y)*s0);
  v[2] = 0.99f*tanhf(ar.z)*hh.z + be.z + al*(r4.z + (a.z+b.z+c.z+d.z)*s0);
  v[3] = 0.99f*tanhf(ar.w)*hh.w + be.w + al*(r4.w + (a.w+b.w+c.w+d.w)*s0);
  // quantize h (int8 values as floats, into LDS)
  float am = fmaxf(fmaxf(fabsf(v[0]),fabsf(v[1])),fmaxf(fabsf(v[2]),fabsf(v[3])));
  am = bredmax(am, red);
  float aq = fmaxf(am, 1e-8f), inv = 127.f/aq;
#pragma unroll
  for (int j=0;j<4;j++) xrow[t*4+j] = fminf(fmaxf(rintf(v[j]*inv),-128.f),127.f);
  float rsv = aq/127.f;
  __syncthreads();
  // lora down: 32 dots of 1024; t = (seg<<5)|r
  {
    int r = t & 31, seg = t >> 5;
    const unsigned short* wrow = ldq + (size_t)r*1024 + seg*128;
    const float* xr = xrow + seg*128;
    float acc = 0.f;
    for (int k=0;k<128;k+=4){
      ushort4 w4 = *(const ushort4*)(wrow + k);
      acc += xr[k]*bf2f(w4.x) + xr[k+1]*bf2f(w4.y) + xr[k+2]*bf2f(w4.z) + xr[k+3]*bf2f(w4.w);
    }
    part[t] = acc;
  }
  __syncthreads();
  if (t < 32){
    float s = 0.f;
    for (int sg=0; sg<8; sg++) s += part[sg*32 + t];
    xs[t] = s * rsv * (*sld);
  }
  __syncthreads();
  // topk threshold (k=18) + act quant of t1
  float val = 0.f, av = 0.f, amax = 0.f;
  if (t < 32){
    val = xs[t]; av = fabsf(val);
    int rank = 0;
    for (int j=0;j<32;j++){
      float aj = fabsf(xs[j]);
      amax = fmaxf(amax, aj);
      if (aj > av || (aj == av && j < t)) rank++;
    }
    if (rank == 17) sh_thr = av;
  }
  __syncthreads();
  if (t < 32){
    float a2 = fmaxf(amax, 1e-8f);
    float q = 0.f;
    if (av >= sh_thr) q = fminf(fmaxf(rintf(val*(127.f/a2)), -128.f), 127.f);
    xs[t] = q;
    if (t == 0) sh_gs = ig[it] * (*slu) * (a2/127.f);
  }
  __syncthreads();
  float gs = sh_gs;
  float hn[4];
  int n0 = t*4;
#pragma unroll
  for (int ni=0;ni<4;ni++){
    const unsigned short* lr = luq + (size_t)(n0+ni)*32;
    float dd = 0.f;
    for (int k=0;k<32;k+=4){
      ushort4 w4 = *(const ushort4*)(lr + k);
      dd += xs[k]*bf2f(w4.x) + xs[k+1]*bf2f(w4.y) + xs[k+2]*bf2f(w4.z) + xs[k+3]*bf2f(w4.w);
    }
    hn[ni] = v[ni] + gs*dd;
  }
  float am2 = fmaxf(fmaxf(fabsf(hn[0]),fabsf(hn[1])),fmaxf(fabsf(hn[2]),fabsf(hn[3])));
  am2 = bredmax(am2, red);
  float a2 = fmaxf(am2, 1e-8f), inv2 = 127.f/a2;
  float zp = 0.f;
#pragma unroll
  for (int ni=0;ni<4;ni++){
    float q = fminf(fmaxf(rintf(hn[ni]*inv2),-128.f),127.f);
    zp += q * bf2f(actq[n0+ni]);
  }
  zp = bredsum(zp, red);
  float z = zp * (a2/127.f) * (*sact);
  float wv = 1.f/(1.f+expf(-z));
#pragma unroll
  for (int ni=0;ni<4;ni++){
    size_t o2 = (size_t)m*1024 + n0+ni;
    float ho = hout[o2];
    hout[o2] = ho + wv*(hn[ni]-ho);
    h[o2] = hn[ni];
  }
  if (t==0) atomicAdd(ponder, wv * (1.f/8192.f));
}

// ---------------- MFMA flash attention ----------------
DEV int swz64(int r, int c){ return r*64 + (c ^ ((r&7)<<3)); }
DEV u16x8 cvt8(float4 a, float4 b, float sc){
  u16x8 q;
  q[0]=f2bfr(a.x*sc); q[1]=f2bfr(a.y*sc); q[2]=f2bfr(a.z*sc); q[3]=f2bfr(a.w*sc);
  q[4]=f2bfr(b.x*sc); q[5]=f2bfr(b.y*sc); q[6]=f2bfr(b.z*sc); q[7]=f2bfr(b.w*sc);
  return q;
}

__global__ __launch_bounds__(256) void attn_mfma_k(const float* __restrict__ qkv,
                                                   float* __restrict__ o){
  __shared__ __align__(16) unsigned short Qs[4096];
  __shared__ __align__(16) unsigned short Ks[4096];
  __shared__ __align__(16) unsigned short Vt[4096];   // [d][k], swizzled on d
  __shared__ __align__(16) unsigned short Ps[4][1024];
  const int tid = threadIdx.x;
  const int lane = tid & 63, wv = tid >> 6;
  const int qt = blockIdx.x & 7, bh = blockIdx.x >> 3;
  const int b = bh >> 4, h = bh & 15;
  const size_t tokbase = (size_t)(b*512);
  const int l15 = lane & 15, lh = lane >> 4;

  { // stage Q (scaled by 1/sqrt(64))
    int r = tid >> 2, c0 = (tid & 3) << 4;
    const float* s = qkv + (tokbase + qt*64 + r)*3072 + h*64 + c0;
    float4 f0 = *(const float4*)s,     f1 = *(const float4*)(s+4);
    float4 f2 = *(const float4*)(s+8), f3 = *(const float4*)(s+12);
    *(u16x8*)(Qs + swz64(r, c0))   = cvt8(f0, f1, 0.125f);
    *(u16x8*)(Qs + swz64(r, c0+8)) = cvt8(f2, f3, 0.125f);
  }

  float m_run[4] = {-1e30f,-1e30f,-1e30f,-1e30f};
  float l_run[4] = {0.f,0.f,0.f,0.f};
  f32x4 accO[4] = {};

  for (int kt = 0; kt <= qt; ++kt){
    __syncthreads();
    { // stage K
      int r = tid >> 2, c0 = (tid & 3) << 4;
      const float* s = qkv + (tokbase + kt*64 + r)*3072 + 1024 + h*64 + c0;
      float4 f0 = *(const float4*)s,     f1 = *(const float4*)(s+4);
      float4 f2 = *(const float4*)(s+8), f3 = *(const float4*)(s+12);
      *(u16x8*)(Ks + swz64(r, c0))   = cvt8(f0, f1, 1.f);
      *(u16x8*)(Ks + swz64(r, c0+8)) = cvt8(f2, f3, 1.f);
    }
    { // stage V transposed
      int r0 = (tid >> 3) << 1, cv = (tid & 7) << 3;
      const float* s0 = qkv + (tokbase + kt*64 + r0)*3072 + 2048 + h*64 + cv;
      const float* s1 = s0 + 3072;
      float4 a0 = *(const float4*)s0, a1 = *(const float4*)(s0+4);
      float4 b0 = *(const float4*)s1, b1 = *(const float4*)(s1+4);
      float va[8] = {a0.x,a0.y,a0.z,a0.w,a1.x,a1.y,a1.z,a1.w};
      float vb[8] = {b0.x,b0.y,b0.z,b0.w,b1.x,b1.y,b1.z,b1.w};
#pragma unroll
      for (int j=0;j<8;j++){
        int d = cv + j;
        unsigned int pk = (unsigned int)f2bfr(va[j]) | ((unsigned int)f2bfr(vb[j])<<16);
        *(unsigned int*)(Vt + swz64(d, r0)) = pk;
      }
    }
    __syncthreads();

    f32x4 s4[4] = {};
#pragma unroll
    for (int kc=0; kc<2; ++kc){
      i32x4 aq = *(const i32x4*)(Qs + swz64(wv*16 + l15, kc*32 + lh*8));
#pragma unroll
      for (int nt=0; nt<4; ++nt){
        i32x4 bk = *(const i32x4*)(Ks + swz64(nt*16 + l15, kc*32 + lh*8));
        asm("v_mfma_f32_16x16x32_bf16 %0, %1, %2, %0" : "+v"(s4[nt]) : "v"(aq), "v"(bk));
      }
    }
#pragma unroll
    for (int nt=0; nt<4; ++nt) s4[nt] = accfence(s4[nt]);

    const bool diag = (kt == qt);
    float sf[4];
#pragma unroll
    for (int r=0;r<4;r++){
      int rl = lh*4 + r;
      float mx = -1e30f;
#pragma unroll
      for (int nt=0; nt<4; ++nt){
        float v = s4[nt][r];
        if (diag && (nt*16 + l15) > (wv*16 + rl)) v = -1e30f;
        s4[nt][r] = v;
        mx = fmaxf(mx, v);
      }
      mx = fmaxf(mx, __shfl_xor(mx,1));
      mx = fmaxf(mx, __shfl_xor(mx,2));
      mx = fmaxf(mx, __shfl_xor(mx,4));
      mx = fmaxf(mx, __shfl_xor(mx,8));
      float mn = fmaxf(m_run[r], mx);
      sf[r] = __expf(m_run[r] - mn);
      m_run[r] = mn;
      float ps = 0.f;
#pragma unroll
      for (int nt=0; nt<4; ++nt){
        float p = __expf(s4[nt][r] - mn);
        ps += p;
        Ps[wv][swz64(rl, nt*16 + l15)] = f2bfr(p);
      }
      ps += __shfl_xor(ps,1); ps += __shfl_xor(ps,2);
      ps += __shfl_xor(ps,4); ps += __shfl_xor(ps,8);
      l_run[r] = l_run[r]*sf[r] + ps;
    }
#pragma unroll
    for (int dt=0; dt<4; ++dt){
#pragma unroll
      for (int r=0;r<4;r++) accO[dt][r] *= sf[r];
      accO[dt] = accfence(accO[dt]);
    }
#pragma unroll
    for (int kc=0; kc<2; ++kc){
      i32x4 pa = *(const i32x4*)(Ps[wv] + swz64(l15, kc*32 + lh*8));
#pragma unroll
      for (int dt=0; dt<4; ++dt){
        i32x4 vb2 = *(const i32x4*)(Vt + swz64(dt*16 + l15, kc*32 + lh*8));
        asm("v_mfma_f32_16x16x32_bf16 %0, %1, %2, %0" : "+v"(accO[dt]) : "v"(pa), "v"(vb2));
      }
    }
  }
#pragma unroll
  for (int dt=0; dt<4; ++dt) accO[dt] = accfence(accO[dt]);
#pragma unroll
  for (int r=0;r<4;r++){
    float invl = 1.f / l_run[r];
    int row = qt*64 + wv*16 + lh*4 + r;
    float* op = o + (tokbase + row)*1024 + h*64 + l15;
#pragma unroll
    for (int dt=0; dt<4; ++dt)
      op[dt*16] = accO[dt][r] * invl;
  }
}

// ================= host =================
extern "C" void kernel_launch(void* const* d_in, const int* in_sizes, int n_in,
                              void* d_out, int out_size, void* d_ws, size_t ws_size,
                              hipStream_t stream)
{
  (void)in_sizes; (void)n_in;
  const float* x     = (const float*)d_in[0];
  const float* e     = (const float*)d_in[1];
  const float* temb  = (const float*)d_in[2];
  const float* bn1   = (const float*)d_in[3];
  const float* bwq   = (const float*)d_in[4];
  const float* bwk   = (const float*)d_in[5];
  const float* bwv   = (const float*)d_in[6];
  const float* bwo   = (const float*)d_in[7];
  const float* bn2   = (const float*)d_in[8];
  const float* bwg   = (const float*)d_in[9];
  const float* bwu   = (const float*)d_in[10];
  const float* bwd   = (const float*)d_in[11];
  const float* Araw  = (const float*)d_in[12];
  const float* Bw    = (const float*)d_in[13];
  const float* ldw   = (const float*)d_in[14];
  const float* luw   = (const float*)d_in[15];
  const float* ig    = (const float*)d_in[16];
  const float* actw  = (const float*)d_in[17];
  const float* alph  = (const float*)d_in[18];
  const float* lpw   = (const float*)d_in[19];
  const float* lp2w  = (const float*)d_in[20];
  const float* lp2b  = (const float*)d_in[21];
  const float* lnw   = (const float*)d_in[22];

  char* ws = (char*)d_ws;
  float* out = (float*)d_out;
  const size_t WS_NEEDED = 130482688ull;
  if (ws_size < WS_NEEDED){
    fill_k<<<(out_size+255)/256,256,0,stream>>>(out, out_size, 1.0e9f);
    return;
  }

  unsigned short* qw_qkv = (unsigned short*)(ws + 0);
  unsigned short* qw_wo  = (unsigned short*)(ws + 12582912);
  unsigned short* qw_gu  = (unsigned short*)(ws + 16777216);
  unsigned short* qw_wd  = (unsigned short*)(ws + 50331648);
  unsigned short* qw_bw  = (unsigned short*)(ws + 67108864);
  unsigned short* qw_ld  = (unsigned short*)(ws + 69206016);
  unsigned short* qw_lu  = (unsigned short*)(ws + 69271552);
  unsigned short* qw_act = (unsigned short*)(ws + 69337088);
  float* scales = (float*)(ws + 69339136);
  float* part   = (float*)(ws + 69339648);
  float* delta  = (float*)(ws + 69358080);
  float* hbuf   = (float*)(ws + 69362176);
  float* Bebuf  = (float*)(ws + 73556480);
  float* bufX   = (float*)(ws + 77750784);
  float* bufY   = (float*)(ws + 81945088);
  float* qkvb   = (float*)(ws + 86139392);            // aliases gub (splitK z=0)
  float* obuf   = (float*)(ws + 86139392 + 12582912);
  float* gub    = (float*)(ws + 86139392);            // 32MB scratch: gu out / splitK partials
  unsigned short* xq1k = (unsigned short*)(ws + 119693824);
  float* rs1k   = (float*)(ws + 121790976);
  unsigned short* xqm  = (unsigned short*)(ws + 121795072);
  float* rsm    = (float*)(ws + 130183680);
  float* ropetab= (float*)(ws + 130351616);           // 128KB

  // ---- setup: scales + ternary weights ----
  WSetup wsu;
  wsu.src[0]=Bw;
  wsu.src[1]=bwq; wsu.src[2]=bwq+1048576;
  wsu.src[3]=bwk; wsu.src[4]=bwk+1048576;
  wsu.src[5]=bwv; wsu.src[6]=bwv+1048576;
  wsu.src[7]=bwo; wsu.src[8]=bwo+1048576;
  wsu.src[9]=bwg; wsu.src[10]=bwg+4194304;
  wsu.src[11]=bwu; wsu.src[12]=bwu+4194304;
  wsu.src[13]=bwd; wsu.src[14]=bwd+4194304;
  wsu.src[15]=ldw; wsu.src[16]=luw; wsu.src[17]=actw;
  wsu.dst[0]=qw_bw;
  wsu.dst[1]=qw_qkv;             wsu.dst[2]=qw_qkv+3145728;
  wsu.dst[3]=qw_qkv+1048576;     wsu.dst[4]=qw_qkv+3145728+1048576;
  wsu.dst[5]=qw_qkv+2097152;     wsu.dst[6]=qw_qkv+3145728+2097152;
  wsu.dst[7]=qw_wo;              wsu.dst[8]=qw_wo+1048576;
  wsu.dst[9]=qw_gu;              wsu.dst[10]=qw_gu+8388608;
  wsu.dst[11]=qw_gu+4194304;     wsu.dst[12]=qw_gu+8388608+4194304;
  wsu.dst[13]=qw_wd;             wsu.dst[14]=qw_wd+4194304;
  wsu.dst[15]=qw_ld; wsu.dst[16]=qw_lu; wsu.dst[17]=qw_act;

  absmean_all_k<<<4608,256,0,stream>>>(wsu, part);
  finalize_scales_k<<<1,256,0,stream>>>(part, scales);
  quantw_all_k<<<8465,256,0,stream>>>(wsu, scales);

  // ---- misc setup ----
  delta2_k<<<128,256,0,stream>>>(temb, lpw, lp2w, lp2b, delta);
  ropetab_k<<<64,256,0,stream>>>(ropetab);
  copy_init_k<<<1024,256,0,stream>>>(x, hbuf, out);

  // Be = bitlinear(e, B_w)  (splitK x4)
  rowquant1k_k<false><<<1024,256,0,stream>>>(e, nullptr, xq1k, rs1k);
  { dim3 g(8,8,4); gemm_bt<0,true><<<g,256,0,stream>>>(xq1k, qw_bw, nullptr, nullptr, nullptr, gub, 1024, 1024, 256); }
  reduce4_k<<<1024,256,0,stream>>>(gub, rs1k, scales+0, nullptr, Bebuf);

  // ---- main recurrent loop (n_loops = 8) ----
  for (int it=0; it<8; ++it){
    loopnorm_quant_k<<<1024,256,0,stream>>>(hbuf, delta + it*128, lnw, bn1, bufX, xq1k, rs1k);
    for (int l=0;l<2;l++){
      // qkv (splitK x2) + fused rope/scale reduce
      { dim3 g(24,8,2); gemm_bt<0,true><<<g,256,0,stream>>>(xq1k, qw_qkv + (size_t)l*3145728, nullptr, nullptr, nullptr, gub, 3072, 1024, 512); }
      rope_reduce_k<<<1024,256,0,stream>>>(gub, rs1k, scales+18+l*3, ropetab, qkvb);
      attn_mfma_k<<<256,256,0,stream>>>(qkvb, obuf);
      rowquant1k_k<false><<<1024,256,0,stream>>>(obuf, nullptr, xq1k, rs1k);
      // wo (splitK x4) + fused reduce+residual+rmsnorm(bn2)+quant
      { dim3 g(8,8,4); gemm_bt<0,true><<<g,256,0,stream>>>(xq1k, qw_wo + (size_t)l*1048576, nullptr, nullptr, nullptr, gub, 1024, 1024, 256); }
      redq_norm_k<<<1024,256,0,stream>>>(gub, rs1k, scales+7+l, bufX, bn2 + (size_t)l*1024, bufY, xq1k, rs1k);
      // gu
      { dim3 g(64,8); gemm_bt<12,false><<<g,256,0,stream>>>(xq1k, qw_gu + (size_t)l*8388608, rs1k, scales+24+l*2, nullptr, gub, 8192, 1024, 1024); }
      silu_mul_quant_k<<<1024,256,0,stream>>>(gub, xqm, rsm);
      // wd (splitK x4)
      { dim3 g(8,8,4); gemm_bt<0,true><<<g,256,0,stream>>>(xqm, qw_wd + (size_t)l*4194304, nullptr, nullptr, nullptr, gub, 1024, 4096, 1024); }
      if (l==0){
        // reduce + residual -> bufX (block-l0 out), + rmsnorm(bn1[1]) quant for l=1 qkv
        redq_norm_k<<<1024,256,0,stream>>>(gub, rsm, scales+13, bufY, bn1 + 1024, bufX, xq1k, rs1k);
      } else {
        // fused tail: reduce + recurrence + lora + gate + h_out + ponder
        redfin_k<<<1024,256,0,stream>>>(gub, rsm, scales+14, bufY, hbuf, Bebuf, Araw, alph, it,
                                        qw_ld, scales+15, qw_lu, scales+16, qw_act, scales+17,
                                        ig, out, out + 1048576);
      }
    }
  }
}

// Round 5
// 2110.839 us; speedup vs baseline: 2.3559x; 1.2189x over previous
//
#include <hip/hip_runtime.h>
#include <stdint.h>

#define DEV static __device__ __forceinline__

typedef float f32x4 __attribute__((ext_vector_type(4)));
typedef int   i32x4 __attribute__((ext_vector_type(4)));
typedef unsigned short u16x8 __attribute__((ext_vector_type(8)));

DEV float bf2f(unsigned short u){ return __uint_as_float(((unsigned int)u)<<16); }
DEV unsigned short f2bfr(float f){ // round-to-nearest-even bf16
  unsigned int u = __float_as_uint(f);
  return (unsigned short)((u + 0x7FFF + ((u>>16)&1)) >> 16);
}
DEV signed char f2i8(float f){ return (signed char)(int)f; } // f already rint+clamped

// ---------------- block reductions (256-thread blocks, 4 waves) ----------------
DEV float wredsum(float v){
#pragma unroll
  for (int o=32;o;o>>=1) v += __shfl_xor(v,o);
  return v;
}
DEV float wredmax(float v){
#pragma unroll
  for (int o=32;o;o>>=1) v = fmaxf(v,__shfl_xor(v,o));
  return v;
}
DEV float bredsum(float v, float* red){
  v = wredsum(v);
  if ((threadIdx.x&63)==0) red[threadIdx.x>>6] = v;
  __syncthreads();
  float r = red[0]+red[1]+red[2]+red[3];
  __syncthreads();
  return r;
}
DEV float bredmax(float v, float* red){
  v = wredmax(v);
  if ((threadIdx.x&63)==0) red[threadIdx.x>>6] = v;
  __syncthreads();
  float r = fmaxf(fmaxf(red[0],red[1]),fmaxf(red[2],red[3]));
  __syncthreads();
  return r;
}

// ---------------- misc ----------------
__global__ void fill_k(float* p, int n, float v){
  int i = blockIdx.x*256 + threadIdx.x;
  if (i < n) p[i] = v;
}

__global__ __launch_bounds__(256) void copy_init_k(const float* __restrict__ x,
                                                   float* __restrict__ h, float* __restrict__ ho){
  int i = blockIdx.x*256 + threadIdx.x;
  float4 v = *(const float4*)(x + (size_t)i*4);
  *(float4*)(h  + (size_t)i*4) = v;
  *(float4*)(ho + (size_t)i*4) = v;
  if (blockIdx.x==0 && threadIdx.x==0) ho[1048576] = 0.f;   // ponder accumulator
}

// ---------------- fused setup: 18 weight matrices ----------------
// order: 0:Bw 1:wq0 2:wq1 3:wk0 4:wk1 5:wv0 6:wv1 7:wo0 8:wo1
//        9:wg0 10:wg1 11:wu0 12:wu1 13:wd0 14:wd1 15:ld 16:lu 17:act
struct WSetup {
  const float* src[18];
  signed char* dst[18];
};
DEV long n4of(int mat){ return mat<9 ? 262144 : (mat<15 ? 1048576 : (mat<17 ? 8192 : 256)); }

__global__ __launch_bounds__(256) void absmean_all_k(WSetup wsu, float* __restrict__ part){
  __shared__ float red[4];
  int mat = blockIdx.x >> 8;
  int seg = blockIdx.x & 255;
  long n4 = n4of(mat);
  const float4* p = (const float4*)wsu.src[mat];
  float s0=0.f, s1=0.f, s2=0.f, s3=0.f;
  long i = (long)seg*256 + threadIdx.x;
  for (; i + 196608 < n4; i += 262144){
    float4 a = p[i], b = p[i+65536], c = p[i+131072], d = p[i+196608];
    s0 += fabsf(a.x)+fabsf(a.y)+fabsf(a.z)+fabsf(a.w);
    s1 += fabsf(b.x)+fabsf(b.y)+fabsf(b.z)+fabsf(b.w);
    s2 += fabsf(c.x)+fabsf(c.y)+fabsf(c.z)+fabsf(c.w);
    s3 += fabsf(d.x)+fabsf(d.y)+fabsf(d.z)+fabsf(d.w);
  }
  for (; i < n4; i += 65536){
    float4 a = p[i];
    s0 += fabsf(a.x)+fabsf(a.y)+fabsf(a.z)+fabsf(a.w);
  }
  float s = bredsum(s0+s1+s2+s3, red);
  if (threadIdx.x==0) part[(long)mat*256 + seg] = s;
}

__global__ __launch_bounds__(256) void finalize_scales_k(const float* __restrict__ part,
                                                         float* __restrict__ scales){
  __shared__ float red[4];
  const long numel[18] = {1048576, 1048576,1048576, 1048576,1048576, 1048576,1048576,
                          1048576,1048576, 4194304,4194304, 4194304,4194304, 4194304,4194304,
                          32768, 32768, 1024};
  for (int m=0;m<18;m++){
    float v = part[(long)m*256 + threadIdx.x];
    v = bredsum(v, red);
    if (threadIdx.x==0) scales[m] = v/(float)numel[m] + 1e-8f;
  }
  if (threadIdx.x==0){
    for (int l=0;l<2;l++){
      scales[18+l*3+0] = scales[1+l];   // wq
      scales[18+l*3+1] = scales[3+l];   // wk
      scales[18+l*3+2] = scales[5+l];   // wv
      scales[24+l*2+0] = scales[9+l];   // wg
      scales[24+l*2+1] = scales[11+l];  // wu
    }
  }
}

// one kernel quantizes all 18 matrices -> ternary i8; block -> (mat, seg of 1024 float4s)
__global__ __launch_bounds__(256) void quantw_all_k(WSetup wsu, const float* __restrict__ scales){
  int bid = blockIdx.x;
  int mat = 0, c = 0;
  for (;;){
    int nb = mat<9 ? 256 : (mat<15 ? 1024 : (mat<17 ? 8 : 1));
    if (bid < c + nb) break;
    c += nb; mat++;
  }
  long seg = bid - c;
  long n4 = n4of(mat);
  float s = scales[mat];
  const float4* src = (const float4*)wsu.src[mat];
  char4* dst = (char4*)wsu.dst[mat];
  long base = seg*1024;
#pragma unroll
  for (int k=0;k<4;k++){
    long i = base + k*256 + threadIdx.x;
    if (i < n4){
      float4 v = src[i];
      char4 q;
      q.x = f2i8(fminf(fmaxf(rintf(v.x/s), -1.f), 1.f));
      q.y = f2i8(fminf(fmaxf(rintf(v.y/s), -1.f), 1.f));
      q.z = f2i8(fminf(fmaxf(rintf(v.z/s), -1.f), 1.f));
      q.w = f2i8(fminf(fmaxf(rintf(v.w/s), -1.f), 1.f));
      dst[i] = q;
    }
  }
}

// ---------------- loop_delta: parallel dots, all 8 iterations ----------------
__global__ __launch_bounds__(256) void delta2_k(const float* __restrict__ temb,
                                                const float* __restrict__ lpw,
                                                const float* __restrict__ lp2w,
                                                const float* __restrict__ lp2b,
                                                float* __restrict__ delta){
  __shared__ float red[4];
  int blk = blockIdx.x;            // 128 = 2 b * 64 j
  int b = blk >> 6, j = blk & 63;
  int t = threadIdx.x;
  float te = temb[b*256 + t];
  float p1 = bredsum(te * lpw[j*256 + t], red);
  float p2 = bredsum(te * lp2w[j*256 + t], red);
  if (t < 8){
    int i = t;
    float frac = (float)i / 7.f;
    int jj = j & 31;
    float fr = expf(-logf(10000.f) * (float)jj * (1.f/32.f));
    float ang = frac * fr;
    float sig = (j < 32) ? sinf(ang) : cosf(ang);
    delta[i*128 + b*64 + j] = sig*p1 + p2 + lp2b[j];
  }
}

// ---------------- RoPE cos/sin table ----------------
__global__ __launch_bounds__(256) void ropetab_k(float* __restrict__ tab){
  int i = blockIdx.x*256 + threadIdx.x;   // 512*32 = 16384
  int tpos = i >> 5, d = i & 31;
  float inv = powf(10000.f, -(float)d * (1.f/32.f));
  float sv, cv; sincosf((float)tpos * inv, &sv, &cv);
  tab[i*2]   = cv;
  tab[i*2+1] = sv;
}

// ---------------- row quant (1024 wide) -> i8 ----------------
__global__ __launch_bounds__(256) void rowquant1k_k(const float* __restrict__ x,
                                                    signed char* __restrict__ xq,
                                                    float* __restrict__ rs){
  __shared__ float red[4];
  int m = blockIdx.x, t = threadIdx.x;
  float v[4];
  float4 f = *(const float4*)(x + (size_t)m*1024 + t*4);
  v[0]=f.x; v[1]=f.y; v[2]=f.z; v[3]=f.w;
  float am = fmaxf(fmaxf(fabsf(v[0]),fabsf(v[1])),fmaxf(fabsf(v[2]),fabsf(v[3])));
  am = bredmax(am, red);
  float a = fmaxf(am, 1e-8f), inv = 127.f/a;
  char4 q;
  q.x = f2i8(fminf(fmaxf(rintf(v[0]*inv),-128.f),127.f));
  q.y = f2i8(fminf(fmaxf(rintf(v[1]*inv),-128.f),127.f));
  q.z = f2i8(fminf(fmaxf(rintf(v[2]*inv),-128.f),127.f));
  q.w = f2i8(fminf(fmaxf(rintf(v[3]*inv),-128.f),127.f));
  *(char4*)(xq + (size_t)m*1024 + t*4) = q;
  if (t==0) rs[m] = a/127.f;
}

// ---------------- fused: h_in = rmsnorm(h+delta, lnw); a_in quant with n1 ----------------
__global__ __launch_bounds__(256) void loopnorm_quant_k(const float* __restrict__ h,
                                                        const float* __restrict__ delta,
                                                        const float* __restrict__ lnw,
                                                        const float* __restrict__ n1,
                                                        float* __restrict__ hin,
                                                        signed char* __restrict__ xq,
                                                        float* __restrict__ rs){
  __shared__ float red[4];
  int m = blockIdx.x, t = threadIdx.x;
  int b = m >> 9;
  float v[4];
  float4 f = *(const float4*)(h + (size_t)m*1024 + t*4);
  v[0]=f.x; v[1]=f.y; v[2]=f.z; v[3]=f.w;
  if (t < 16){
#pragma unroll
    for (int j=0;j<4;j++) v[j] += delta[b*64 + t*4 + j];
  }
  float ss = v[0]*v[0]+v[1]*v[1]+v[2]*v[2]+v[3]*v[3];
  ss = bredsum(ss, red);
  float r1 = rsqrtf(ss*(1.f/1024.f) + 1e-6f);
  float w4[4];
#pragma unroll
  for (int j=0;j<4;j++) w4[j] = v[j]*r1*lnw[t*4+j];
  float4 of; of.x=w4[0]; of.y=w4[1]; of.z=w4[2]; of.w=w4[3];
  *(float4*)(hin + (size_t)m*1024 + t*4) = of;
  float s2 = w4[0]*w4[0]+w4[1]*w4[1]+w4[2]*w4[2]+w4[3]*w4[3];
  s2 = bredsum(s2, red);
  float r2 = rsqrtf(s2*(1.f/1024.f) + 1e-6f);
  float y[4];
#pragma unroll
  for (int j=0;j<4;j++) y[j] = w4[j]*r2*n1[t*4+j];
  float am = fmaxf(fmaxf(fabsf(y[0]),fabsf(y[1])),fmaxf(fabsf(y[2]),fabsf(y[3])));
  am = bredmax(am, red);
  float a = fmaxf(am, 1e-8f), inv = 127.f/a;
  char4 q;
  q.x = f2i8(fminf(fmaxf(rintf(y[0]*inv),-128.f),127.f));
  q.y = f2i8(fminf(fmaxf(rintf(y[1]*inv),-128.f),127.f));
  q.z = f2i8(fminf(fmaxf(rintf(y[2]*inv),-128.f),127.f));
  q.w = f2i8(fminf(fmaxf(rintf(y[3]*inv),-128.f),127.f));
  *(char4*)(xq + (size_t)m*1024 + t*4) = q;
  if (t==0) rs[m] = a/127.f;
}

// ---------------- silu(g)*u over F=4096, then row quant -> i8 ----------------
__global__ __launch_bounds__(256) void silu_mul_quant_k(const float* __restrict__ gu,
                                                        signed char* __restrict__ xq,
                                                        float* __restrict__ rs){
  __shared__ float red[4];
  int m = blockIdx.x, t = threadIdx.x;
  const float* g = gu + (size_t)m*8192;
  const float* u = g + 4096;
  float v[16];
#pragma unroll
  for (int j=0;j<16;j+=4){
    float4 gg = *(const float4*)(g + t*16 + j);
    float4 uu = *(const float4*)(u + t*16 + j);
    v[j+0] = gg.x/(1.f+expf(-gg.x))*uu.x;
    v[j+1] = gg.y/(1.f+expf(-gg.y))*uu.y;
    v[j+2] = gg.z/(1.f+expf(-gg.z))*uu.z;
    v[j+3] = gg.w/(1.f+expf(-gg.w))*uu.w;
  }
  float am = 0.f;
#pragma unroll
  for (int j=0;j<16;j++) am = fmaxf(am, fabsf(v[j]));
  am = bredmax(am, red);
  float a = fmaxf(am, 1e-8f), inv = 127.f/a;
#pragma unroll
  for (int j=0;j<16;j+=4){
    char4 q;
    q.x = f2i8(fminf(fmaxf(rintf(v[j+0]*inv),-128.f),127.f));
    q.y = f2i8(fminf(fmaxf(rintf(v[j+1]*inv),-128.f),127.f));
    q.z = f2i8(fminf(fmaxf(rintf(v[j+2]*inv),-128.f),127.f));
    q.w = f2i8(fminf(fmaxf(rintf(v[j+3]*inv),-128.f),127.f));
    *(char4*)(xq + (size_t)m*4096 + t*16 + j) = q;
  }
  if (t==0) rs[m] = a/127.f;
}

// ---------------- i8 MFMA GEMM (pipelined, double-buffered, swizzled) ----------------
// Byte layout identical to the bf16 BK=32 version: 64 B per tile-row, 16 B fragments.
// Kf/Kc/kstart are in BYTES (= elements for i8).
DEV f32x4 accfence(f32x4 c){ asm volatile("s_nop 7\n\ts_nop 7" : "+v"(c)); return c; }
DEV i32x4 accfencei(i32x4 c){ asm volatile("s_nop 7\n\ts_nop 7" : "+v"(c)); return c; }

template<int SSHIFT, bool SPLITK>
__global__ __launch_bounds__(256)
void gemm_i8(const signed char* __restrict__ A, const signed char* __restrict__ W,
             const float* __restrict__ rowsc, const float* __restrict__ wscv,
             const float* __restrict__ res, float* __restrict__ C, int N, int Kf, int Kc)
{
  __shared__ __align__(16) signed char As[2][8192];
  __shared__ __align__(16) signed char Bs[2][8192];
  const int tid = threadIdx.x;
  const int lane = tid & 63, wvid = tid >> 6;
  const int wr = wvid >> 1, wc = wvid & 1;
  const int bm = blockIdx.y, bn = blockIdx.x;

  const int r0 = (wvid<<4) + (lane>>2);
  const int sw = (((lane&3) ^ ((r0>>1)&3)) << 4);        // byte offset of 16B chunk
  const long kstart = SPLITK ? (long)blockIdx.z * Kc : 0;
  const signed char* gA = A + (size_t)(bm*128 + r0)*Kf + kstart + sw;
  const signed char* gB = W + (size_t)(bn*128 + r0)*Kf + kstart + sw;
  const size_t row64 = (size_t)64*Kf;

#define STAGE(buf, koff) do { \
    __builtin_amdgcn_global_load_lds(gA + (koff),         &As[buf][(wvid<<10)],      16, 0, 0); \
    __builtin_amdgcn_global_load_lds(gA + (koff) + row64, &As[buf][(wvid<<10)+4096], 16, 0, 0); \
    __builtin_amdgcn_global_load_lds(gB + (koff),         &Bs[buf][(wvid<<10)],      16, 0, 0); \
    __builtin_amdgcn_global_load_lds(gB + (koff) + row64, &Bs[buf][(wvid<<10)+4096], 16, 0, 0); \
  } while(0)

  i32x4 acc[4][4] = {};
  const int rA = (wr<<6) + (lane&15);
  const int rB = (wc<<6) + (lane&15);
  const int psA = (((lane>>4) ^ (((lane&15)>>1)&3)) << 4);  // byte offset

  STAGE(0, 0);
  const int NT = Kc >> 6;
  int cur = 0;
  for (int kt = 0; kt < NT; ++kt){
    const int knext = (kt+1 < NT) ? ((kt+1)<<6) : 0;
    STAGE(cur^1, knext);
    asm volatile("s_waitcnt vmcnt(4)" ::: "memory");
    __builtin_amdgcn_s_barrier();
    asm volatile("" ::: "memory");
    i32x4 a[4], b[4];
    const signed char* Ab = As[cur];
    const signed char* Bb = Bs[cur];
#pragma unroll
    for (int mi=0;mi<4;mi++) a[mi] = *(const i32x4*)(Ab + (rA + mi*16)*64 + psA);
#pragma unroll
    for (int ni=0;ni<4;ni++) b[ni] = *(const i32x4*)(Bb + (rB + ni*16)*64 + psA);
#pragma unroll
    for (int mi=0;mi<4;mi++)
#pragma unroll
      for (int ni=0;ni<4;ni++)
        asm("v_mfma_i32_16x16x64_i8 %0, %1, %2, %0" : "+v"(acc[mi][ni]) : "v"(a[mi]), "v"(b[ni]));
    asm volatile("s_waitcnt lgkmcnt(0)" ::: "memory");
    __builtin_amdgcn_s_barrier();
    cur ^= 1;
  }
#undef STAGE

#pragma unroll
  for (int mi=0;mi<4;mi++)
#pragma unroll
    for (int ni=0;ni<4;ni++)
      acc[mi][ni] = accfencei(acc[mi][ni]);

  const int rif = (lane>>4)<<2;
  const int cif = lane&15;
  const int gcol0 = bn*128 + (wc<<6);

  if constexpr (SPLITK){
    float* P = C + (size_t)blockIdx.z * ((size_t)N << 10);
#pragma unroll
    for (int mi=0;mi<4;mi++)
#pragma unroll
      for (int r=0;r<4;r++){
        const int grow = bm*128 + (wr<<6) + mi*16 + rif + r;
#pragma unroll
        for (int ni=0;ni<4;ni++)
          P[(size_t)grow*N + gcol0 + ni*16 + cif] = (float)acc[mi][ni][r];
      }
    return;
  }

#pragma unroll
  for (int mi=0;mi<4;mi++){
#pragma unroll
    for (int r=0;r<4;r++){
      const int grow = bm*128 + (wr<<6) + mi*16 + rif + r;
      const float rsc = rowsc[grow];
#pragma unroll
      for (int ni=0;ni<4;ni++){
        const int gcol = gcol0 + ni*16 + cif;
        float vvv = (float)acc[mi][ni][r] * rsc * wscv[gcol>>SSHIFT];
        const size_t off = (size_t)grow*N + gcol;
        if (res) vvv += res[off];
        C[off] = vvv;
      }
    }
  }
}

// ---------------- split-K(2) reduce + scales + RoPE -> qkvb (in-place alias of P z=0 ok) ----------------
__global__ __launch_bounds__(256) void rope_reduce_k(const float* P,
                                                     const float* __restrict__ rowsc,
                                                     const float* __restrict__ wscv,
                                                     const float* __restrict__ tab,
                                                     float* C){
  int m = blockIdx.x, t = threadIdx.x;
  const float rsc = rowsc[m];
  const int tpos = m & 511;
  const size_t base = (size_t)m*3072;
  const float* P1 = P + 3145728;
  int p0 = t*4;
  int hh = p0 >> 5, d = p0 & 31;
  int c1 = hh*64 + d;
  float wsc = wscv[c1>>10] * rsc;
  float4 xa0 = *(const float4*)(P  + base + c1);
  float4 xa1 = *(const float4*)(P1 + base + c1);
  float4 xb0 = *(const float4*)(P  + base + c1 + 32);
  float4 xb1 = *(const float4*)(P1 + base + c1 + 32);
  float4 cs01 = *(const float4*)(tab + ((size_t)tpos*32 + d)*2);
  float4 cs23 = *(const float4*)(tab + ((size_t)tpos*32 + d)*2 + 4);
  int cv = 2048 + t*4;
  float4 va = *(const float4*)(P  + base + cv);
  float4 vb = *(const float4*)(P1 + base + cv);
  float wv2 = wscv[2] * rsc;

  float x1[4] = {(xa0.x+xa1.x)*wsc, (xa0.y+xa1.y)*wsc, (xa0.z+xa1.z)*wsc, (xa0.w+xa1.w)*wsc};
  float x2[4] = {(xb0.x+xb1.x)*wsc, (xb0.y+xb1.y)*wsc, (xb0.z+xb1.z)*wsc, (xb0.w+xb1.w)*wsc};
  float cc[4] = {cs01.x, cs01.z, cs23.x, cs23.z};
  float ss[4] = {cs01.y, cs01.w, cs23.y, cs23.w};
  float4 o1, o2, ov;
  o1.x = x1[0]*cc[0] - x2[0]*ss[0];  o2.x = x1[0]*ss[0] + x2[0]*cc[0];
  o1.y = x1[1]*cc[1] - x2[1]*ss[1];  o2.y = x1[1]*ss[1] + x2[1]*cc[1];
  o1.z = x1[2]*cc[2] - x2[2]*ss[2];  o2.z = x1[2]*ss[2] + x2[2]*cc[2];
  o1.w = x1[3]*cc[3] - x2[3]*ss[3];  o2.w = x1[3]*ss[3] + x2[3]*cc[3];
  ov.x = (va.x+vb.x)*wv2; ov.y = (va.y+vb.y)*wv2; ov.z = (va.z+vb.z)*wv2; ov.w = (va.w+vb.w)*wv2;
  *(float4*)(C + base + c1)      = o1;
  *(float4*)(C + base + c1 + 32) = o2;
  *(float4*)(C + base + cv)      = ov;
}

// ---------------- split-K(4) reduce: C = (res?) + (sum P)*rowsc*wsc ----------------
__global__ __launch_bounds__(256) void reduce4_k(const float* __restrict__ P,
                                                 const float* __restrict__ rowsc,
                                                 const float* __restrict__ wsc,
                                                 const float* __restrict__ res,
                                                 float* __restrict__ C){
  int m = blockIdx.x, t = threadIdx.x;
  float s0 = rowsc[m] * wsc[0];
  size_t off = (size_t)m*1024 + t*4;
  float4 a = *(const float4*)(P + off);
  float4 b = *(const float4*)(P + 1048576 + off);
  float4 c = *(const float4*)(P + 2097152 + off);
  float4 d = *(const float4*)(P + 3145728 + off);
  float4 o;
  o.x = (a.x+b.x+c.x+d.x)*s0;
  o.y = (a.y+b.y+c.y+d.y)*s0;
  o.z = (a.z+b.z+c.z+d.z)*s0;
  o.w = (a.w+b.w+c.w+d.w)*s0;
  if (res){
    float4 r = *(const float4*)(res + off);
    o.x += r.x; o.y += r.y; o.z += r.z; o.w += r.w;
  }
  *(float4*)(C + off) = o;
}

// ---------------- fused: split-K(4) reduce + residual + rmsnorm + quant ----------------
__global__ __launch_bounds__(256) void redq_norm_k(const float* __restrict__ P,
                                                   const float* rowsc,
                                                   const float* __restrict__ wsc,
                                                   const float* __restrict__ res,
                                                   const float* __restrict__ gamma,
                                                   float* __restrict__ Cout,
                                                   signed char* __restrict__ xq,
                                                   float* rs){
  __shared__ float red[4];
  int m = blockIdx.x, t = threadIdx.x;
  float s0 = rowsc[m] * wsc[0];
  size_t off = (size_t)m*1024 + t*4;
  float4 a = *(const float4*)(P + off);
  float4 b = *(const float4*)(P + 1048576 + off);
  float4 c = *(const float4*)(P + 2097152 + off);
  float4 d = *(const float4*)(P + 3145728 + off);
  float4 r4 = *(const float4*)(res + off);
  float v[4];
  v[0] = r4.x + (a.x+b.x+c.x+d.x)*s0;
  v[1] = r4.y + (a.y+b.y+c.y+d.y)*s0;
  v[2] = r4.z + (a.z+b.z+c.z+d.z)*s0;
  v[3] = r4.w + (a.w+b.w+c.w+d.w)*s0;
  float4 of; of.x=v[0]; of.y=v[1]; of.z=v[2]; of.w=v[3];
  *(float4*)(Cout + off) = of;
  float ss = v[0]*v[0]+v[1]*v[1]+v[2]*v[2]+v[3]*v[3];
  ss = bredsum(ss, red);
  float r1 = rsqrtf(ss*(1.f/1024.f) + 1e-6f);
  float y[4];
#pragma unroll
  for (int j=0;j<4;j++) y[j] = v[j]*r1*gamma[t*4+j];
  float am = fmaxf(fmaxf(fabsf(y[0]),fabsf(y[1])),fmaxf(fabsf(y[2]),fabsf(y[3])));
  am = bredmax(am, red);
  float aq = fmaxf(am, 1e-8f), inv = 127.f/aq;
  char4 q;
  q.x = f2i8(fminf(fmaxf(rintf(y[0]*inv),-128.f),127.f));
  q.y = f2i8(fminf(fmaxf(rintf(y[1]*inv),-128.f),127.f));
  q.z = f2i8(fminf(fmaxf(rintf(y[2]*inv),-128.f),127.f));
  q.w = f2i8(fminf(fmaxf(rintf(y[3]*inv),-128.f),127.f));
  *(char4*)(xq + (size_t)m*1024 + t*4) = q;
  if (t==0) rs[m] = aq/127.f;
}

// ---------------- fused tail (l=1 wd): reduce + recurrence + quant + loraDown
//                  + topk + loraUp + act-sigmoid + h_out blend + ponder ----------------
__global__ __launch_bounds__(256) void redfin_k(const float* __restrict__ P,
                                                const float* __restrict__ rowsc,
                                                const float* __restrict__ wsc,
                                                const float* __restrict__ res,
                                                float* __restrict__ h,
                                                const float* __restrict__ Be,
                                                const float* __restrict__ Araw,
                                                const float* __restrict__ alpha, int it,
                                                const signed char* __restrict__ ldq,
                                                const float* __restrict__ sld,
                                                const signed char* __restrict__ luq,
                                                const float* __restrict__ slu,
                                                const signed char* __restrict__ actq,
                                                const float* __restrict__ sact,
                                                const float* __restrict__ ig,
                                                float* __restrict__ hout,
                                                float* __restrict__ ponder){
  __shared__ float red[4];
  __shared__ float xrow[1024];
  __shared__ float part[256];
  __shared__ float xs[32];
  __shared__ float sh_thr, sh_gs;
  int m = blockIdx.x, t = threadIdx.x;
  float al = alpha[it];
  float s0 = rowsc[m] * wsc[0];
  size_t off = (size_t)m*1024 + t*4;
  float4 a = *(const float4*)(P + off);
  float4 b = *(const float4*)(P + 1048576 + off);
  float4 c = *(const float4*)(P + 2097152 + off);
  float4 d = *(const float4*)(P + 3145728 + off);
  float4 r4 = *(const float4*)(res + off);
  float4 hh = *(const float4*)(h + off);
  float4 be = *(const float4*)(Be + off);
  float4 ar = *(const float4*)(Araw + t*4);
  float v[4];
  v[0] = 0.99f*tanhf(ar.x)*hh.x + be.x + al*(r4.x + (a.x+b.x+c.x+d.x)*s0);
  v[1] = 0.99f*tanhf(ar.y)*hh.y + be.y + al*(r4.y + (a.y+b.y+c.y+d.y)*s0);
  v[2] = 0.99f*tanhf(ar.z)*hh.z + be.z + al*(r4.z + (a.z+b.z+c.z+d.z)*s0);
  v[3] = 0.99f*tanhf(ar.w)*hh.w + be.w + al*(r4.w + (a.w+b.w+c.w+d.w)*s0);
  float am = fmaxf(fmaxf(fabsf(v[0]),fabsf(v[1])),fmaxf(fabsf(v[2]),fabsf(v[3])));
  am = bredmax(am, red);
  float aq = fmaxf(am, 1e-8f), inv = 127.f/aq;
#pragma unroll
  for (int j=0;j<4;j++) xrow[t*4+j] = fminf(fmaxf(rintf(v[j]*inv),-128.f),127.f);
  float rsv = aq/127.f;
  __syncthreads();
  {
    int r = t & 31, seg = t >> 5;
    const signed char* wrow = ldq + (size_t)r*1024 + seg*128;
    const float* xr = xrow + seg*128;
    float acc = 0.f;
    for (int k=0;k<128;k+=4){
      char4 w4 = *(const char4*)(wrow + k);
      acc += xr[k]*(float)w4.x + xr[k+1]*(float)w4.y + xr[k+2]*(float)w4.z + xr[k+3]*(float)w4.w;
    }
    part[t] = acc;
  }
  __syncthreads();
  if (t < 32){
    float s = 0.f;
    for (int sg=0; sg<8; sg++) s += part[sg*32 + t];
    xs[t] = s * rsv * (*sld);
  }
  __syncthreads();
  float val = 0.f, av = 0.f, amax = 0.f;
  if (t < 32){
    val = xs[t]; av = fabsf(val);
    int rank = 0;
    for (int j=0;j<32;j++){
      float aj = fabsf(xs[j]);
      amax = fmaxf(amax, aj);
      if (aj > av || (aj == av && j < t)) rank++;
    }
    if (rank == 17) sh_thr = av;
  }
  __syncthreads();
  if (t < 32){
    float a2 = fmaxf(amax, 1e-8f);
    float q = 0.f;
    if (av >= sh_thr) q = fminf(fmaxf(rintf(val*(127.f/a2)), -128.f), 127.f);
    xs[t] = q;
    if (t == 0) sh_gs = ig[it] * (*slu) * (a2/127.f);
  }
  __syncthreads();
  float gs = sh_gs;
  float hn[4];
  int n0 = t*4;
#pragma unroll
  for (int ni=0;ni<4;ni++){
    const signed char* lr = luq + (size_t)(n0+ni)*32;
    float dd = 0.f;
    for (int k=0;k<32;k+=4){
      char4 w4 = *(const char4*)(lr + k);
      dd += xs[k]*(float)w4.x + xs[k+1]*(float)w4.y + xs[k+2]*(float)w4.z + xs[k+3]*(float)w4.w;
    }
    hn[ni] = v[ni] + gs*dd;
  }
  float am2 = fmaxf(fmaxf(fabsf(hn[0]),fabsf(hn[1])),fmaxf(fabsf(hn[2]),fabsf(hn[3])));
  am2 = bredmax(am2, red);
  float a2 = fmaxf(am2, 1e-8f), inv2 = 127.f/a2;
  float zp = 0.f;
#pragma unroll
  for (int ni=0;ni<4;ni++){
    float q = fminf(fmaxf(rintf(hn[ni]*inv2),-128.f),127.f);
    zp += q * (float)actq[n0+ni];
  }
  zp = bredsum(zp, red);
  float z = zp * (a2/127.f) * (*sact);
  float wv = 1.f/(1.f+expf(-z));
#pragma unroll
  for (int ni=0;ni<4;ni++){
    size_t o2 = (size_t)m*1024 + n0+ni;
    float ho = hout[o2];
    hout[o2] = ho + wv*(hn[ni]-ho);
    h[o2] = hn[ni];
  }
  if (t==0) atomicAdd(ponder, wv * (1.f/8192.f));
}

// ---------------- MFMA flash attention (bf16) ----------------
DEV int swz64(int r, int c){ return r*64 + (c ^ ((r&7)<<3)); }
DEV u16x8 cvt8(float4 a, float4 b, float sc){
  u16x8 q;
  q[0]=f2bfr(a.x*sc); q[1]=f2bfr(a.y*sc); q[2]=f2bfr(a.z*sc); q[3]=f2bfr(a.w*sc);
  q[4]=f2bfr(b.x*sc); q[5]=f2bfr(b.y*sc); q[6]=f2bfr(b.z*sc); q[7]=f2bfr(b.w*sc);
  return q;
}

__global__ __launch_bounds__(256) void attn_mfma_k(const float* __restrict__ qkv,
                                                   float* __restrict__ o){
  __shared__ __align__(16) unsigned short Qs[4096];
  __shared__ __align__(16) unsigned short Ks[4096];
  __shared__ __align__(16) unsigned short Vt[4096];   // [d][k], swizzled on d
  __shared__ __align__(16) unsigned short Ps[4][1024];
  const int tid = threadIdx.x;
  const int lane = tid & 63, wv = tid >> 6;
  const int qt = blockIdx.x & 7, bh = blockIdx.x >> 3;
  const int b = bh >> 4, h = bh & 15;
  const size_t tokbase = (size_t)(b*512);
  const int l15 = lane & 15, lh = lane >> 4;

  { // stage Q (scaled by 1/sqrt(64))
    int r = tid >> 2, c0 = (tid & 3) << 4;
    const float* s = qkv + (tokbase + qt*64 + r)*3072 + h*64 + c0;
    float4 f0 = *(const float4*)s,     f1 = *(const float4*)(s+4);
    float4 f2 = *(const float4*)(s+8), f3 = *(const float4*)(s+12);
    *(u16x8*)(Qs + swz64(r, c0))   = cvt8(f0, f1, 0.125f);
    *(u16x8*)(Qs + swz64(r, c0+8)) = cvt8(f2, f3, 0.125f);
  }

  float m_run[4] = {-1e30f,-1e30f,-1e30f,-1e30f};
  float l_run[4] = {0.f,0.f,0.f,0.f};
  f32x4 accO[4] = {};

  for (int kt = 0; kt <= qt; ++kt){
    __syncthreads();
    { // stage K
      int r = tid >> 2, c0 = (tid & 3) << 4;
      const float* s = qkv + (tokbase + kt*64 + r)*3072 + 1024 + h*64 + c0;
      float4 f0 = *(const float4*)s,     f1 = *(const float4*)(s+4);
      float4 f2 = *(const float4*)(s+8), f3 = *(const float4*)(s+12);
      *(u16x8*)(Ks + swz64(r, c0))   = cvt8(f0, f1, 1.f);
      *(u16x8*)(Ks + swz64(r, c0+8)) = cvt8(f2, f3, 1.f);
    }
    { // stage V transposed
      int r0 = (tid >> 3) << 1, cv = (tid & 7) << 3;
      const float* s0 = qkv + (tokbase + kt*64 + r0)*3072 + 2048 + h*64 + cv;
      const float* s1 = s0 + 3072;
      float4 a0 = *(const float4*)s0, a1 = *(const float4*)(s0+4);
      float4 b0 = *(const float4*)s1, b1 = *(const float4*)(s1+4);
      float va[8] = {a0.x,a0.y,a0.z,a0.w,a1.x,a1.y,a1.z,a1.w};
      float vb[8] = {b0.x,b0.y,b0.z,b0.w,b1.x,b1.y,b1.z,b1.w};
#pragma unroll
      for (int j=0;j<8;j++){
        int d = cv + j;
        unsigned int pk = (unsigned int)f2bfr(va[j]) | ((unsigned int)f2bfr(vb[j])<<16);
        *(unsigned int*)(Vt + swz64(d, r0)) = pk;
      }
    }
    __syncthreads();

    f32x4 s4[4] = {};
#pragma unroll
    for (int kc=0; kc<2; ++kc){
      i32x4 aq = *(const i32x4*)(Qs + swz64(wv*16 + l15, kc*32 + lh*8));
#pragma unroll
      for (int nt=0; nt<4; ++nt){
        i32x4 bk = *(const i32x4*)(Ks + swz64(nt*16 + l15, kc*32 + lh*8));
        asm("v_mfma_f32_16x16x32_bf16 %0, %1, %2, %0" : "+v"(s4[nt]) : "v"(aq), "v"(bk));
      }
    }
#pragma unroll
    for (int nt=0; nt<4; ++nt) s4[nt] = accfence(s4[nt]);

    const bool diag = (kt == qt);
    float sf[4];
#pragma unroll
    for (int r=0;r<4;r++){
      int rl = lh*4 + r;
      float mx = -1e30f;
#pragma unroll
      for (int nt=0; nt<4; ++nt){
        float v = s4[nt][r];
        if (diag && (nt*16 + l15) > (wv*16 + rl)) v = -1e30f;
        s4[nt][r] = v;
        mx = fmaxf(mx, v);
      }
      mx = fmaxf(mx, __shfl_xor(mx,1));
      mx = fmaxf(mx, __shfl_xor(mx,2));
      mx = fmaxf(mx, __shfl_xor(mx,4));
      mx = fmaxf(mx, __shfl_xor(mx,8));
      float mn = fmaxf(m_run[r], mx);
      sf[r] = __expf(m_run[r] - mn);
      m_run[r] = mn;
      float ps = 0.f;
#pragma unroll
      for (int nt=0; nt<4; ++nt){
        float p = __expf(s4[nt][r] - mn);
        ps += p;
        Ps[wv][swz64(rl, nt*16 + l15)] = f2bfr(p);
      }
      ps += __shfl_xor(ps,1); ps += __shfl_xor(ps,2);
      ps += __shfl_xor(ps,4); ps += __shfl_xor(ps,8);
      l_run[r] = l_run[r]*sf[r] + ps;
    }
#pragma unroll
    for (int dt=0; dt<4; ++dt){
#pragma unroll
      for (int r=0;r<4;r++) accO[dt][r] *= sf[r];
      accO[dt] = accfence(accO[dt]);
    }
#pragma unroll
    for (int kc=0; kc<2; ++kc){
      i32x4 pa = *(const i32x4*)(Ps[wv] + swz64(l15, kc*32 + lh*8));
#pragma unroll
      for (int dt=0; dt<4; ++dt){
        i32x4 vb2 = *(const i32x4*)(Vt + swz64(dt*16 + l15, kc*32 + lh*8));
        asm("v_mfma_f32_16x16x32_bf16 %0, %1, %2, %0" : "+v"(accO[dt]) : "v"(pa), "v"(vb2));
      }
    }
  }
#pragma unroll
  for (int dt=0; dt<4; ++dt) accO[dt] = accfence(accO[dt]);
#pragma unroll
  for (int r=0;r<4;r++){
    float invl = 1.f / l_run[r];
    int row = qt*64 + wv*16 + lh*4 + r;
    float* op = o + (tokbase + row)*1024 + h*64 + l15;
#pragma unroll
    for (int dt=0; dt<4; ++dt)
      op[dt*16] = accO[dt][r] * invl;
  }
}

// ================= host =================
extern "C" void kernel_launch(void* const* d_in, const int* in_sizes, int n_in,
                              void* d_out, int out_size, void* d_ws, size_t ws_size,
                              hipStream_t stream)
{
  (void)in_sizes; (void)n_in;
  const float* x     = (const float*)d_in[0];
  const float* e     = (const float*)d_in[1];
  const float* temb  = (const float*)d_in[2];
  const float* bn1   = (const float*)d_in[3];
  const float* bwq   = (const float*)d_in[4];
  const float* bwk   = (const float*)d_in[5];
  const float* bwv   = (const float*)d_in[6];
  const float* bwo   = (const float*)d_in[7];
  const float* bn2   = (const float*)d_in[8];
  const float* bwg   = (const float*)d_in[9];
  const float* bwu   = (const float*)d_in[10];
  const float* bwd   = (const float*)d_in[11];
  const float* Araw  = (const float*)d_in[12];
  const float* Bw    = (const float*)d_in[13];
  const float* ldw   = (const float*)d_in[14];
  const float* luw   = (const float*)d_in[15];
  const float* ig    = (const float*)d_in[16];
  const float* actw  = (const float*)d_in[17];
  const float* alph  = (const float*)d_in[18];
  const float* lpw   = (const float*)d_in[19];
  const float* lp2w  = (const float*)d_in[20];
  const float* lp2b  = (const float*)d_in[21];
  const float* lnw   = (const float*)d_in[22];

  char* ws = (char*)d_ws;
  float* out = (float*)d_out;
  const size_t WS_NEEDED = 94600704ull;
  if (ws_size < WS_NEEDED){
    fill_k<<<(out_size+255)/256,256,0,stream>>>(out, out_size, 1.0e9f);
    return;
  }

  signed char* qw_qkv = (signed char*)(ws + 0);          // 6 MB
  signed char* qw_wo  = (signed char*)(ws + 6291456);    // 2 MB
  signed char* qw_gu  = (signed char*)(ws + 8388608);    // 16 MB
  signed char* qw_wd  = (signed char*)(ws + 25165824);   // 8 MB
  signed char* qw_bw  = (signed char*)(ws + 33554432);   // 1 MB
  signed char* qw_ld  = (signed char*)(ws + 34603008);
  signed char* qw_lu  = (signed char*)(ws + 34635776);
  signed char* qw_act = (signed char*)(ws + 34668544);
  float* scales = (float*)(ws + 34669568);
  float* part   = (float*)(ws + 34670080);
  float* delta  = (float*)(ws + 34688512);
  float* hbuf   = (float*)(ws + 34692608);
  float* Bebuf  = (float*)(ws + 38886912);
  float* bufX   = (float*)(ws + 43081216);
  float* bufY   = (float*)(ws + 47275520);
  float* gub    = (float*)(ws + 51469824);               // 32 MB scratch / splitK partials
  float* qkvb   = gub;                                   // alias (splitK z=0)
  float* obuf   = (float*)(ws + 85024256);
  signed char* xq1k = (signed char*)(ws + 89218560);
  float* rs1k   = (float*)(ws + 90267136);
  signed char* xqm  = (signed char*)(ws + 90271232);
  float* rsm    = (float*)(ws + 94465536);
  float* ropetab= (float*)(ws + 94469632);               // 128 KB

  // ---- setup: scales + ternary weights ----
  WSetup wsu;
  wsu.src[0]=Bw;
  wsu.src[1]=bwq; wsu.src[2]=bwq+1048576;
  wsu.src[3]=bwk; wsu.src[4]=bwk+1048576;
  wsu.src[5]=bwv; wsu.src[6]=bwv+1048576;
  wsu.src[7]=bwo; wsu.src[8]=bwo+1048576;
  wsu.src[9]=bwg; wsu.src[10]=bwg+4194304;
  wsu.src[11]=bwu; wsu.src[12]=bwu+4194304;
  wsu.src[13]=bwd; wsu.src[14]=bwd+4194304;
  wsu.src[15]=ldw; wsu.src[16]=luw; wsu.src[17]=actw;
  wsu.dst[0]=qw_bw;
  wsu.dst[1]=qw_qkv;             wsu.dst[2]=qw_qkv+3145728;
  wsu.dst[3]=qw_qkv+1048576;     wsu.dst[4]=qw_qkv+3145728+1048576;
  wsu.dst[5]=qw_qkv+2097152;     wsu.dst[6]=qw_qkv+3145728+2097152;
  wsu.dst[7]=qw_wo;              wsu.dst[8]=qw_wo+1048576;
  wsu.dst[9]=qw_gu;              wsu.dst[10]=qw_gu+8388608;
  wsu.dst[11]=qw_gu+4194304;     wsu.dst[12]=qw_gu+8388608+4194304;
  wsu.dst[13]=qw_wd;             wsu.dst[14]=qw_wd+4194304;
  wsu.dst[15]=qw_ld; wsu.dst[16]=qw_lu; wsu.dst[17]=qw_act;

  absmean_all_k<<<4608,256,0,stream>>>(wsu, part);
  finalize_scales_k<<<1,256,0,stream>>>(part, scales);
  quantw_all_k<<<8465,256,0,stream>>>(wsu, scales);

  // ---- misc setup ----
  delta2_k<<<128,256,0,stream>>>(temb, lpw, lp2w, lp2b, delta);
  ropetab_k<<<64,256,0,stream>>>(ropetab);
  copy_init_k<<<1024,256,0,stream>>>(x, hbuf, out);

  // Be = bitlinear(e, B_w)  (splitK x4)
  rowquant1k_k<<<1024,256,0,stream>>>(e, xq1k, rs1k);
  { dim3 g(8,8,4); gemm_i8<0,true><<<g,256,0,stream>>>(xq1k, qw_bw, nullptr, nullptr, nullptr, gub, 1024, 1024, 256); }
  reduce4_k<<<1024,256,0,stream>>>(gub, rs1k, scales+0, nullptr, Bebuf);

  // ---- main recurrent loop (n_loops = 8) ----
  for (int it=0; it<8; ++it){
    loopnorm_quant_k<<<1024,256,0,stream>>>(hbuf, delta + it*128, lnw, bn1, bufX, xq1k, rs1k);
    for (int l=0;l<2;l++){
      // qkv (splitK x2) + fused rope/scale reduce
      { dim3 g(24,8,2); gemm_i8<0,true><<<g,256,0,stream>>>(xq1k, qw_qkv + (size_t)l*3145728, nullptr, nullptr, nullptr, gub, 3072, 1024, 512); }
      rope_reduce_k<<<1024,256,0,stream>>>(gub, rs1k, scales+18+l*3, ropetab, qkvb);
      attn_mfma_k<<<256,256,0,stream>>>(qkvb, obuf);
      rowquant1k_k<<<1024,256,0,stream>>>(obuf, xq1k, rs1k);
      // wo (splitK x4) + fused reduce+residual+rmsnorm(bn2)+quant
      { dim3 g(8,8,4); gemm_i8<0,true><<<g,256,0,stream>>>(xq1k, qw_wo + (size_t)l*1048576, nullptr, nullptr, nullptr, gub, 1024, 1024, 256); }
      redq_norm_k<<<1024,256,0,stream>>>(gub, rs1k, scales+7+l, bufX, bn2 + (size_t)l*1024, bufY, xq1k, rs1k);
      // gu
      { dim3 g(64,8); gemm_i8<12,false><<<g,256,0,stream>>>(xq1k, qw_gu + (size_t)l*8388608, rs1k, scales+24+l*2, nullptr, gub, 8192, 1024, 1024); }
      silu_mul_quant_k<<<1024,256,0,stream>>>(gub, xqm, rsm);
      // wd (splitK x4)
      { dim3 g(8,8,4); gemm_i8<0,true><<<g,256,0,stream>>>(xqm, qw_wd + (size_t)l*4194304, nullptr, nullptr, nullptr, gub, 1024, 4096, 1024); }
      if (l==0){
        redq_norm_k<<<1024,256,0,stream>>>(gub, rsm, scales+13, bufY, bn1 + 1024, bufX, xq1k, rs1k);
      } else {
        redfin_k<<<1024,256,0,stream>>>(gub, rsm, scales+14, bufY, hbuf, Bebuf, Araw, alph, it,
                                        qw_ld, scales+15, qw_lu, scales+16, qw_act, scales+17,
                                        ig, out, out + 1048576);
      }
    }
  }
}